// Round 1
// baseline (1473.463 us; speedup 1.0000x reference)
//
#include <hip/hip_runtime.h>

// FluxUNet fused block — fp32 baseline (round 1).
// B=8, C=512, H=W=32 (HW=1024), S=77, E=768, NH=8, HD=64, HID=2048, T=1101.
constexpr int BATCH = 8, CH = 512, HWN = 1024, SEQ = 77, EMB = 768;
constexpr int NHEAD = 8, HDIM = 64, HIDDEN = 2048, TTOT = 1101;

__device__ __forceinline__ float gelu_tanh(float v) {
    float c = v * v * v;
    float t = tanhf(0.7978845608028654f * (v + 0.044715f * c));
    return 0.5f * v * (1.0f + t);
}

// ---------------- K1: mod = silu(final_emb) @ mod_w + mod_b ----------------
__global__ void k_modulation(const float* __restrict__ emb, const float* __restrict__ w,
                             const float* __restrict__ bias, float* __restrict__ mod) {
    __shared__ float se[EMB];
    int b = blockIdx.y;
    int tid = threadIdx.x;
    for (int i = tid; i < EMB; i += 256) {
        float v = emb[b * EMB + i];
        se[i] = v / (1.0f + expf(-v));
    }
    __syncthreads();
    int j = blockIdx.x * 256 + tid;
    float acc = 0.0f;
    #pragma unroll 8
    for (int e = 0; e < EMB; ++e) acc = fmaf(se[e], w[e * (6 * CH) + j], acc);
    mod[b * (6 * CH) + j] = acc + bias[j];
}

// ------------- K2/K6: RMSNorm over channel dim + adaLN modulate -------------
// out[b,c,n] = x*rsqrt(mean_c(x^2)+1e-6)*sw[c]*(1+mod[sc+c]) + mod[sh+c]
__global__ void k_rms2d_mod(const float* __restrict__ xin, const float* __restrict__ sw,
                            const float* __restrict__ mod, int shoff, int scoff,
                            float* __restrict__ outp) {
    int b = blockIdx.y;
    int n = blockIdx.x * 256 + threadIdx.x;
    const float* xb = xin + (size_t)b * CH * HWN + n;
    float ss = 0.0f;
    #pragma unroll 8
    for (int c = 0; c < CH; ++c) { float v = xb[(size_t)c * HWN]; ss = fmaf(v, v, ss); }
    float r = rsqrtf(ss * (1.0f / CH) + 1e-6f);
    const float* mb = mod + b * (6 * CH);
    float* ob = outp + (size_t)b * CH * HWN + n;
    #pragma unroll 4
    for (int c = 0; c < CH; ++c) {
        float v = xb[(size_t)c * HWN];
        ob[(size_t)c * HWN] = v * r * sw[c] * (1.0f + mb[scoff + c]) + mb[shoff + c];
    }
}

// ---------------- generic 128x128x16 fp32 tiled GEMM ----------------
// TA=0: A[m,k] row-major (stride K). TA=1: A[k,m] row-major (stride M; requires M%128==0).
// TB=0: B[k,n] row-major (stride N; requires N%128==0). TB=1: B[n,k] row-major (stride K).
// EPI=0: Out = acc
// EPI=1: Out = res + gate[m] * (acc + bias[m])      (out-proj & MLP2)
// EPI=2: Out = gelu_tanh(acc + bias[m])             (MLP1)
template <int TA, int TB, int EPI>
__global__ __launch_bounds__(256) void k_gemm(
    const float* __restrict__ Ap, const float* __restrict__ Bp, float* __restrict__ Out,
    int M, int N, int K, long sAb, long sBb, long sOb,
    const float* __restrict__ bias, const float* __restrict__ gate, int gateStride,
    const float* __restrict__ res, long sResb) {
    __shared__ float As[16][132];
    __shared__ float Bs[16][132];
    int bz = blockIdx.z;
    Ap += (long)bz * sAb;
    Bp += (long)bz * sBb;
    Out += (long)bz * sOb;
    if (EPI == 1) res += (long)bz * sResb;
    int tid = threadIdx.x;
    int tx = tid & 15, ty = tid >> 4;
    int m0 = blockIdx.y * 128, n0 = blockIdx.x * 128;
    float acc[2][2][4][4] = {};
    for (int k0 = 0; k0 < K; k0 += 16) {
        if (TA == 1) {
            int col = (tid & 31) * 4, row = tid >> 5;
            #pragma unroll
            for (int r = 0; r < 2; ++r) {
                int kk = row + r * 8;
                float4 v = *(const float4*)&Ap[(long)(k0 + kk) * M + m0 + col];
                *(float4*)&As[kk][col] = v;
            }
        } else {
            int mloc = tid >> 2, kc = (tid & 3) * 4;
            #pragma unroll
            for (int r = 0; r < 2; ++r) {
                int m = mloc + r * 64;
                int gm = m0 + m;
                float4 v = make_float4(0.f, 0.f, 0.f, 0.f);
                if (gm < M) v = *(const float4*)&Ap[(long)gm * K + k0 + kc];
                As[kc + 0][m] = v.x; As[kc + 1][m] = v.y;
                As[kc + 2][m] = v.z; As[kc + 3][m] = v.w;
            }
        }
        if (TB == 0) {
            int col = (tid & 31) * 4, row = tid >> 5;
            #pragma unroll
            for (int r = 0; r < 2; ++r) {
                int kk = row + r * 8;
                float4 v = *(const float4*)&Bp[(long)(k0 + kk) * N + n0 + col];
                *(float4*)&Bs[kk][col] = v;
            }
        } else {
            int nloc = tid >> 2, kc = (tid & 3) * 4;
            #pragma unroll
            for (int r = 0; r < 2; ++r) {
                int n = nloc + r * 64;
                int gn = n0 + n;
                float4 v = make_float4(0.f, 0.f, 0.f, 0.f);
                if (gn < N) v = *(const float4*)&Bp[(long)gn * K + k0 + kc];
                Bs[kc + 0][n] = v.x; Bs[kc + 1][n] = v.y;
                Bs[kc + 2][n] = v.z; Bs[kc + 3][n] = v.w;
            }
        }
        __syncthreads();
        #pragma unroll
        for (int k = 0; k < 16; ++k) {
            float4 a0 = *(const float4*)&As[k][ty * 4];
            float4 a1 = *(const float4*)&As[k][64 + ty * 4];
            float4 b0 = *(const float4*)&Bs[k][tx * 4];
            float4 b1 = *(const float4*)&Bs[k][64 + tx * 4];
            float am[2][4] = {{a0.x, a0.y, a0.z, a0.w}, {a1.x, a1.y, a1.z, a1.w}};
            float bn[2][4] = {{b0.x, b0.y, b0.z, b0.w}, {b1.x, b1.y, b1.z, b1.w}};
            #pragma unroll
            for (int mh = 0; mh < 2; ++mh)
                #pragma unroll
                for (int nh = 0; nh < 2; ++nh)
                    #pragma unroll
                    for (int i = 0; i < 4; ++i)
                        #pragma unroll
                        for (int j = 0; j < 4; ++j)
                            acc[mh][nh][i][j] = fmaf(am[mh][i], bn[nh][j], acc[mh][nh][i][j]);
        }
        __syncthreads();
    }
    #pragma unroll
    for (int mh = 0; mh < 2; ++mh)
        #pragma unroll
        for (int i = 0; i < 4; ++i) {
            int m = m0 + mh * 64 + ty * 4 + i;
            if (m >= M) continue;
            float bv = (EPI != 0) ? bias[m] : 0.f;
            float gv = (EPI == 1) ? gate[bz * gateStride + m] : 0.f;
            #pragma unroll
            for (int nh = 0; nh < 2; ++nh) {
                int n = n0 + nh * 64 + tx * 4;
                float4 o;
                if (EPI == 0) {
                    o = make_float4(acc[mh][nh][i][0], acc[mh][nh][i][1],
                                    acc[mh][nh][i][2], acc[mh][nh][i][3]);
                } else if (EPI == 1) {
                    const float* rp = &res[(long)m * N + n];
                    o.x = rp[0] + gv * (acc[mh][nh][i][0] + bv);
                    o.y = rp[1] + gv * (acc[mh][nh][i][1] + bv);
                    o.z = rp[2] + gv * (acc[mh][nh][i][2] + bv);
                    o.w = rp[3] + gv * (acc[mh][nh][i][3] + bv);
                } else {
                    o.x = gelu_tanh(acc[mh][nh][i][0] + bv);
                    o.y = gelu_tanh(acc[mh][nh][i][1] + bv);
                    o.z = gelu_tanh(acc[mh][nh][i][2] + bv);
                    o.w = gelu_tanh(acc[mh][nh][i][3] + bv);
                }
                *(float4*)&Out[(long)m * N + n] = o;
            }
        }
}

// -------- K5: build q/k/v heads with RoPE (2D spatial / 1D cond) + RMSNorm --------
// qkvs: [B, HW, 3C] token-major; qkvc: [B, S, 3C]. One wave per (b,h,token), lane = d.
// q gets the 1/sqrt(HD)=0.125 attention scale baked in. q written only for spatial tokens.
__global__ void k_qkv_build(const float* __restrict__ qkvs, const float* __restrict__ qkvc,
                            const float* __restrict__ freqs, const float* __restrict__ qn,
                            const float* __restrict__ kn,
                            float* __restrict__ qb, float* __restrict__ kb,
                            float* __restrict__ vb) {
    int wid = threadIdx.x >> 6, lane = threadIdx.x & 63;
    int gid = blockIdx.x * 4 + wid;
    if (gid >= BATCH * NHEAD * TTOT) return;
    int bh = gid / TTOT, tok = gid - bh * TTOT;
    int b = bh >> 3;
    int j = lane >> 1;
    float qv = 0.f, kv, vv, ang;
    if (tok < HWN) {
        size_t base = ((size_t)(b * HWN + tok)) * 1536 + (bh & 7) * 64 + lane;
        qv = qkvs[base];
        kv = qkvs[base + 512];
        vv = qkvs[base + 1024];
        ang = (float)(tok >> 5) * freqs[2 * j] + (float)(tok & 31) * freqs[2 * j + 1];
    } else {
        int s = tok - HWN;
        size_t base = ((size_t)(b * SEQ + s)) * 1536 + (bh & 7) * 64 + lane;
        kv = qkvc[base + 512];
        vv = qkvc[base + 1024];
        // inv_freq = 10000^(-j/32)
        float inv = expf(-(float)j * (9.210340371976184f / 32.0f));
        ang = (float)s * inv;
    }
    float co = cosf(ang), si = sinf(ang);
    float kp = __shfl_xor(kv, 1);
    float kr = (lane & 1) ? fmaf(kv, co, kp * si) : fmaf(kv, co, -kp * si);
    float qp = __shfl_xor(qv, 1);
    float qr = (lane & 1) ? fmaf(qv, co, qp * si) : fmaf(qv, co, -qp * si);
    float ssk = kr * kr, ssq = qr * qr;
    #pragma unroll
    for (int o = 1; o < 64; o <<= 1) {
        ssk += __shfl_xor(ssk, o);
        ssq += __shfl_xor(ssq, o);
    }
    float kout = kr * rsqrtf(ssk * (1.0f / 64.f) + 1.1920929e-07f) * kn[lane];
    size_t kbase = ((size_t)bh * TTOT + tok) * 64 + lane;
    kb[kbase] = kout;
    vb[kbase] = vv;
    if (tok < HWN) {
        float qout = qr * rsqrtf(ssq * (1.0f / 64.f) + 1.1920929e-07f) * qn[lane] * 0.125f;
        qb[((size_t)bh * HWN + tok) * 64 + lane] = qout;
    }
}

// -------- K7: flash attention, spatial queries only. 64-row Q tile per block. --------
// K and V share one LDS buffer (staged sequentially) to stay under the 64 KiB static limit.
__global__ __launch_bounds__(256) void k_attn(const float* __restrict__ qb,
                                              const float* __restrict__ kb,
                                              const float* __restrict__ vb,
                                              float* __restrict__ ob) {
    __shared__ float Qs[64][68];   // [d][row]  (Q^T)
    __shared__ float KVs[64][68];  // K phase: [d][key]; V phase: [key][d]
    __shared__ float Ps[64][68];   // [row][key]
    int bh = blockIdx.y;
    int q0 = blockIdx.x * 64;
    int tid = threadIdx.x;
    int wid = tid >> 6, lane = tid & 63;
    int tx = tid & 15, ty = tid >> 4;
    int rw = lane >> 4;
    int d4 = (lane & 15) * 4;
    {
        const float* qbase = qb + ((size_t)bh * HWN + q0) * 64;
        #pragma unroll
        for (int it = 0; it < 4; ++it) {
            int r = wid * 16 + it * 4 + rw;
            float4 v = *(const float4*)&qbase[r * 64 + d4];
            Qs[d4 + 0][r] = v.x; Qs[d4 + 1][r] = v.y;
            Qs[d4 + 2][r] = v.z; Qs[d4 + 3][r] = v.w;
        }
    }
    float O[4][4] = {};
    float Mr[4] = {-1e30f, -1e30f, -1e30f, -1e30f};
    float Lr[4] = {};
    const float* kbase = kb + (size_t)bh * TTOT * 64;
    const float* vbase = vb + (size_t)bh * TTOT * 64;
    for (int kt = 0; kt < 18; ++kt) {
        __syncthreads();  // previous PV done; KVs free
        #pragma unroll
        for (int it = 0; it < 4; ++it) {
            int r = wid * 16 + it * 4 + rw;
            int t = kt * 64 + r;
            float4 v = make_float4(0.f, 0.f, 0.f, 0.f);
            if (t < TTOT) v = *(const float4*)&kbase[(size_t)t * 64 + d4];
            KVs[d4 + 0][r] = v.x; KVs[d4 + 1][r] = v.y;
            KVs[d4 + 2][r] = v.z; KVs[d4 + 3][r] = v.w;
        }
        __syncthreads();
        float Sv[4][4] = {};
        #pragma unroll 16
        for (int d = 0; d < 64; ++d) {
            float4 a = *(const float4*)&Qs[d][ty * 4];
            float4 bq = *(const float4*)&KVs[d][tx * 4];
            float av[4] = {a.x, a.y, a.z, a.w};
            float bv[4] = {bq.x, bq.y, bq.z, bq.w};
            #pragma unroll
            for (int i = 0; i < 4; ++i)
                #pragma unroll
                for (int jj = 0; jj < 4; ++jj)
                    Sv[i][jj] = fmaf(av[i], bv[jj], Sv[i][jj]);
        }
        __syncthreads();  // K consumed; stage V into same buffer
        #pragma unroll
        for (int it = 0; it < 4; ++it) {
            int r = wid * 16 + it * 4 + rw;
            int t = kt * 64 + r;
            float4 v = make_float4(0.f, 0.f, 0.f, 0.f);
            if (t < TTOT) v = *(const float4*)&vbase[(size_t)t * 64 + d4];
            *(float4*)&KVs[r][d4] = v;
        }
        // mask tail keys, then online softmax
        #pragma unroll
        for (int jj = 0; jj < 4; ++jj) {
            if (kt * 64 + tx * 4 + jj >= TTOT) {
                #pragma unroll
                for (int i = 0; i < 4; ++i) Sv[i][jj] = -1e30f;
            }
        }
        #pragma unroll
        for (int i = 0; i < 4; ++i) {
            float rm = fmaxf(fmaxf(Sv[i][0], Sv[i][1]), fmaxf(Sv[i][2], Sv[i][3]));
            #pragma unroll
            for (int o = 1; o < 16; o <<= 1) rm = fmaxf(rm, __shfl_xor(rm, o));
            float mnew = fmaxf(Mr[i], rm);
            float alpha = __expf(Mr[i] - mnew);
            float ps = 0.f;
            #pragma unroll
            for (int jj = 0; jj < 4; ++jj) {
                float p = __expf(Sv[i][jj] - mnew);
                Ps[ty * 4 + i][tx * 4 + jj] = p;
                ps += p;
            }
            #pragma unroll
            for (int o = 1; o < 16; o <<= 1) ps += __shfl_xor(ps, o);
            Lr[i] = Lr[i] * alpha + ps;
            Mr[i] = mnew;
            #pragma unroll
            for (int jj = 0; jj < 4; ++jj) O[i][jj] *= alpha;
        }
        __syncthreads();  // Ps + V ready
        #pragma unroll 16
        for (int kk = 0; kk < 64; ++kk) {
            float4 v4 = *(const float4*)&KVs[kk][tx * 4];
            float vv[4] = {v4.x, v4.y, v4.z, v4.w};
            float p0 = Ps[ty * 4 + 0][kk], p1 = Ps[ty * 4 + 1][kk];
            float p2 = Ps[ty * 4 + 2][kk], p3 = Ps[ty * 4 + 3][kk];
            #pragma unroll
            for (int jj = 0; jj < 4; ++jj) {
                O[0][jj] = fmaf(p0, vv[jj], O[0][jj]);
                O[1][jj] = fmaf(p1, vv[jj], O[1][jj]);
                O[2][jj] = fmaf(p2, vv[jj], O[2][jj]);
                O[3][jj] = fmaf(p3, vv[jj], O[3][jj]);
            }
        }
    }
    int b = bh >> 3, h = bh & 7;
    #pragma unroll
    for (int i = 0; i < 4; ++i) {
        float inv = 1.0f / Lr[i];
        size_t row = (size_t)(b * HWN + q0 + ty * 4 + i);
        float4 o4 = make_float4(O[i][0] * inv, O[i][1] * inv, O[i][2] * inv, O[i][3] * inv);
        *(float4*)&ob[row * 512 + h * 64 + tx * 4] = o4;
    }
}

extern "C" void kernel_launch(void* const* d_in, const int* in_sizes, int n_in,
                              void* d_out, int out_size, void* d_ws, size_t ws_size,
                              hipStream_t stream) {
    const float* x     = (const float*)d_in[0];
    const float* cond  = (const float*)d_in[1];
    const float* femb  = (const float*)d_in[2];
    const float* mod_w = (const float*)d_in[3];
    const float* mod_b = (const float*)d_in[4];
    const float* n1s   = (const float*)d_in[5];
    const float* n2s   = (const float*)d_in[6];
    const float* qkvsw = (const float*)d_in[7];
    const float* qkvcw = (const float*)d_in[8];
    const float* ropef = (const float*)d_in[9];
    const float* qn    = (const float*)d_in[10];
    const float* kn    = (const float*)d_in[11];
    const float* outw  = (const float*)d_in[12];
    const float* outb  = (const float*)d_in[13];
    const float* w1    = (const float*)d_in[14];
    const float* b1    = (const float*)d_in[15];
    const float* w2    = (const float*)d_in[16];
    const float* b2    = (const float*)d_in[17];
    float* out = (float*)d_out;
    float* ws  = (float*)d_ws;

    // workspace layout in floats; peak = 35,155,968 floats = 134.1 MiB.
    const size_t OFF_MOD  = 0;                          //    24,576
    const size_t OFF_HMOD = 24576;                      // 4,194,304
    const size_t OFF_QKVS = OFF_HMOD + 4194304;         // 12,582,912
    const size_t OFF_QKVC = OFF_QKVS + 12582912;        //   946,176
    const size_t OFF_Q    = OFF_QKVC + 946176;          // 4,194,304
    const size_t OFF_K    = OFF_Q + 4194304;            // 4,509,696
    const size_t OFF_V    = OFF_K + 4509696;            // 4,509,696
    const size_t OFF_O    = OFF_V + 4509696;            // 4,194,304
    const size_t OFF_M    = OFF_HMOD;  // overlays HMOD+QKVS (dead by MLP1)
    const size_t OFF_X1   = OFF_K;     // overlays K (dead after attention)
    const size_t OFF_H2   = OFF_V;     // overlays V (dead after attention)

    float* mod  = ws + OFF_MOD;
    float* hmod = ws + OFF_HMOD;
    float* qkvs = ws + OFF_QKVS;
    float* qkvc = ws + OFF_QKVC;
    float* qbuf = ws + OFF_Q;
    float* kbuf = ws + OFF_K;
    float* vbuf = ws + OFF_V;
    float* obuf = ws + OFF_O;
    float* mbuf = ws + OFF_M;
    float* x1   = ws + OFF_X1;
    float* h2   = ws + OFF_H2;

    // 1. adaLN modulation
    k_modulation<<<dim3(12, BATCH), 256, 0, stream>>>(femb, mod_w, mod_b, mod);
    // 2. rmsnorm2d(x) + modulate(sh1, sc1)
    k_rms2d_mod<<<dim3(4, BATCH), 256, 0, stream>>>(x, n1s, mod, 0, 512, hmod);
    // 3. qkv_s, token-major [B,HW,3C]: C[n,o] = sum_c hmod[c,n] * Ws[o,c]
    k_gemm<1, 1, 0><<<dim3(12, 8, BATCH), 256, 0, stream>>>(
        hmod, qkvsw, qkvs, 1024, 1536, 512,
        (long)512 * 1024, 0, (long)1024 * 1536, nullptr, nullptr, 0, nullptr, 0);
    // 4. qkv_c [B,S,3C]: C[s,o] = sum_e cond[s,e] * Wc[o,e]
    k_gemm<0, 1, 0><<<dim3(12, 1, BATCH), 256, 0, stream>>>(
        cond, qkvcw, qkvc, 77, 1536, 768,
        (long)77 * 768, 0, (long)77 * 1536, nullptr, nullptr, 0, nullptr, 0);
    // 5. heads + RoPE + qk-RMSNorm (+0.125 scale on q)
    k_qkv_build<<<dim3((BATCH * NHEAD * TTOT) / 4), 256, 0, stream>>>(
        qkvs, qkvc, ropef, qn, kn, qbuf, kbuf, vbuf);
    // 6. flash attention (spatial queries) -> obuf [B,HW,C]
    k_attn<<<dim3(16, BATCH * NHEAD), 256, 0, stream>>>(qbuf, kbuf, vbuf, obuf);
    // 7. out-proj + gate + residual: x1[c,n] = x + g1[c]*(sum_c' Wo[c,c']*obuf[n,c'] + ob[c])
    k_gemm<0, 1, 1><<<dim3(8, 4, BATCH), 256, 0, stream>>>(
        outw, obuf, x1, 512, 1024, 512,
        0, (long)1024 * 512, (long)512 * 1024, outb, mod + 2 * 512, 3072,
        x, (long)512 * 1024);
    // 8. rmsnorm2d(x1) + modulate(sh2, sc2)
    k_rms2d_mod<<<dim3(4, BATCH), 256, 0, stream>>>(x1, n2s, mod, 3 * 512, 4 * 512, h2);
    // 9. MLP1 + gelu: m[o,n] = gelu(sum_c W1[o,c]*h2[c,n] + b1[o])
    k_gemm<0, 0, 2><<<dim3(8, 16, BATCH), 256, 0, stream>>>(
        w1, h2, mbuf, 2048, 1024, 512,
        0, (long)512 * 1024, (long)2048 * 1024, b1, nullptr, 0, nullptr, 0);
    // 10. MLP2 + gate + residual -> d_out
    k_gemm<0, 0, 1><<<dim3(8, 4, BATCH), 256, 0, stream>>>(
        w2, mbuf, out, 512, 1024, 2048,
        0, (long)2048 * 1024, (long)512 * 1024, b2, mod + 5 * 512, 3072,
        x1, (long)512 * 1024);
}

// Round 2
// 355.800 us; speedup vs baseline: 4.1413x; 4.1413x over previous
//
#include <hip/hip_runtime.h>

// FluxUNet fused block — bf16 MFMA round 2.
// B=8, C=512, HW=1024, S=77, E=768, NH=8, HD=64, HID=2048, T=1101.
constexpr int BATCH = 8, CH = 512, HWN = 1024, SEQ = 77, EMB = 768;
constexpr int NHEAD = 8, HDIM = 64, HIDDEN = 2048, TTOT = 1101;

typedef short bhalf8 __attribute__((ext_vector_type(8)));
typedef float f32x4 __attribute__((ext_vector_type(4)));

__device__ __forceinline__ unsigned short f2bf(float f) {
    unsigned u = __builtin_bit_cast(unsigned, f);
    unsigned r = (u + 0x7fffu + ((u >> 16) & 1u)) >> 16;
    return (unsigned short)r;
}
__device__ __forceinline__ float gelu_tanh(float v) {
    float c = v * v * v;
    float t = tanhf(0.7978845608028654f * (v + 0.044715f * c));
    return 0.5f * v * (1.0f + t);
}
// XOR-swizzle for LDS tiles with 128B row stride: spreads 8 rows across banks.
__device__ __forceinline__ int swz(int byte) { return byte ^ ((byte >> 3) & 0x70); }

// ---------------- f32 -> bf16 cast ----------------
__global__ void k_cvt(const float* __restrict__ src, unsigned short* __restrict__ dst, int n) {
    int i = (blockIdx.x * 256 + threadIdx.x) * 4;
    if (i >= n) return;
    float4 v = *(const float4*)&src[i];
    ushort4 o = {f2bf(v.x), f2bf(v.y), f2bf(v.z), f2bf(v.w)};
    *(ushort4*)&dst[i] = o;
}

// ---------------- mod = silu(final_emb) @ mod_w + mod_b ----------------
__global__ void k_modulation(const float* __restrict__ emb, const float* __restrict__ w,
                             const float* __restrict__ bias, float* __restrict__ mod) {
    __shared__ float se[EMB];
    int b = blockIdx.y;
    int tid = threadIdx.x;
    for (int i = tid; i < EMB; i += 256) {
        float v = emb[b * EMB + i];
        se[i] = v / (1.0f + expf(-v));
    }
    __syncthreads();
    int j = blockIdx.x * 256 + tid;
    float acc = 0.0f;
    #pragma unroll 8
    for (int e = 0; e < EMB; ++e) acc = fmaf(se[e], w[e * (6 * CH) + j], acc);
    mod[b * (6 * CH) + j] = acc + bias[j];
}

// ------- RMSNorm(channel) + adaLN modulate + transpose -> bf16 token-major -------
// in:  x [B][512][1024] f32 (channel-major).  out: [B*1024][512] bf16 (token-major)
__global__ __launch_bounds__(256) void k_rms2d_mod_t(const float* __restrict__ xin,
        const float* __restrict__ sw, const float* __restrict__ mod, int shoff, int scoff,
        unsigned short* __restrict__ outp) {
    __shared__ float part[4][64];
    __shared__ float rinv[64];
    int b = blockIdx.y;
    int n0 = blockIdx.x * 64;
    int tid = threadIdx.x;
    const float* xb = xin + (size_t)b * CH * HWN;
    {
        int n = n0 + (tid & 63);
        int cg = tid >> 6;
        float ss = 0.f;
        #pragma unroll 8
        for (int c = cg * 128; c < cg * 128 + 128; ++c) {
            float v = xb[(size_t)c * HWN + n];
            ss = fmaf(v, v, ss);
        }
        part[cg][tid & 63] = ss;
    }
    __syncthreads();
    if (tid < 64) {
        float s = part[0][tid] + part[1][tid] + part[2][tid] + part[3][tid];
        rinv[tid] = rsqrtf(s * (1.0f / CH) + 1e-6f);
    }
    __syncthreads();
    int n = n0 + (tid >> 2);
    int cq = tid & 3;
    float r = rinv[tid >> 2];
    const float* mb = mod + b * (6 * CH);
    unsigned short* orow = outp + ((size_t)(b * HWN + n)) * CH;
    for (int jc = 0; jc < 16; ++jc) {
        int c = cq * 128 + jc * 8;
        bhalf8 o;
        #pragma unroll
        for (int u = 0; u < 8; ++u) {
            int cc = c + u;
            float v = xb[(size_t)cc * HWN + n];
            float y = v * r * sw[cc] * (1.0f + mb[scoff + cc]) + mb[shoff + cc];
            o[u] = (short)f2bf(y);
        }
        *(bhalf8*)&orow[c] = o;
    }
}

// ---------------- bf16 MFMA GEMM: 128x128 tile, BK=64, 4 waves ----------------
// A [M][K] bf16 row-major; Bt [N][K] bf16 row-major (i.e. B transposed). K%64==0, N%128==0.
// EPI=0: f32 out [M][N] (row-guarded).
// EPI=1: f32 out [B][N][1024] = res + gate[b][n]*(acc + bias[n])   (channel-major, M=b*1024+hw)
// EPI=2: bf16 out [M][N] = gelu_tanh(acc + bias[n])
template <int EPI>
__global__ __launch_bounds__(256) void k_gemm_mfma(
        const unsigned short* __restrict__ A, const unsigned short* __restrict__ Bt,
        void* __restrict__ OutV, int M, int N, int K,
        const float* __restrict__ bias, const float* __restrict__ gate,
        const float* __restrict__ res) {
    __shared__ unsigned short Al[128 * 64];
    __shared__ unsigned short Bl[128 * 64];
    int tid = threadIdx.x;
    int w = tid >> 6, l = tid & 63;
    int lg = l >> 4, ll = l & 15;
    int wr = w >> 1, wc = w & 1;
    int m0 = blockIdx.y * 128, n0 = blockIdx.x * 128;
    f32x4 acc[4][4] = {};
    for (int k0 = 0; k0 < K; k0 += 64) {
        bhalf8 ra[4], rb[4];
        #pragma unroll
        for (int i = 0; i < 4; ++i) {
            int id = tid + i * 256;
            int row = id >> 3, k8 = id & 7;
            int ar = m0 + row;
            if (ar > M - 1) ar = M - 1;
            ra[i] = *(const bhalf8*)&A[(size_t)ar * K + k0 + k8 * 8];
            rb[i] = *(const bhalf8*)&Bt[(size_t)(n0 + row) * K + k0 + k8 * 8];
        }
        __syncthreads();
        #pragma unroll
        for (int i = 0; i < 4; ++i) {
            int id = tid + i * 256;
            int row = id >> 3, k8 = id & 7;
            *(bhalf8*)((char*)Al + swz(row * 128 + k8 * 16)) = ra[i];
            *(bhalf8*)((char*)Bl + swz(row * 128 + k8 * 16)) = rb[i];
        }
        __syncthreads();
        #pragma unroll
        for (int ks = 0; ks < 2; ++ks) {
            bhalf8 af[4], bfr[4];
            #pragma unroll
            for (int mi = 0; mi < 4; ++mi)
                af[mi] = *(const bhalf8*)((char*)Al + swz((wr * 64 + mi * 16 + ll) * 128 + ks * 64 + lg * 16));
            #pragma unroll
            for (int ni = 0; ni < 4; ++ni)
                bfr[ni] = *(const bhalf8*)((char*)Bl + swz((wc * 64 + ni * 16 + ll) * 128 + ks * 64 + lg * 16));
            #pragma unroll
            for (int mi = 0; mi < 4; ++mi)
                #pragma unroll
                for (int ni = 0; ni < 4; ++ni)
                    acc[mi][ni] = __builtin_amdgcn_mfma_f32_16x16x32_bf16(af[mi], bfr[ni], acc[mi][ni], 0, 0, 0);
        }
        __syncthreads();
    }
    if (EPI == 0) {
        float* Out = (float*)OutV;
        #pragma unroll
        for (int mi = 0; mi < 4; ++mi)
            #pragma unroll
            for (int ni = 0; ni < 4; ++ni) {
                int col = n0 + wc * 64 + ni * 16 + ll;
                #pragma unroll
                for (int r = 0; r < 4; ++r) {
                    int mrow = m0 + wr * 64 + mi * 16 + 4 * lg + r;
                    if (mrow < M) Out[(size_t)mrow * N + col] = acc[mi][ni][r];
                }
            }
    } else if (EPI == 2) {
        unsigned short* Out = (unsigned short*)OutV;
        #pragma unroll
        for (int mi = 0; mi < 4; ++mi)
            #pragma unroll
            for (int ni = 0; ni < 4; ++ni) {
                int col = n0 + wc * 64 + ni * 16 + ll;
                float bv = bias[col];
                #pragma unroll
                for (int r = 0; r < 4; ++r) {
                    int mrow = m0 + wr * 64 + mi * 16 + 4 * lg + r;
                    Out[(size_t)mrow * N + col] = f2bf(gelu_tanh(acc[mi][ni][r] + bv));
                }
            }
    } else {
        float* Out = (float*)OutV;
        int bidx = m0 >> 10;
        int hw0 = m0 & 1023;
        const float* resb = res + (size_t)bidx * N * HWN;
        float* outb_ = Out + (size_t)bidx * N * HWN;
        #pragma unroll
        for (int ni = 0; ni < 4; ++ni) {
            int ch = n0 + wc * 64 + ni * 16 + ll;
            float g = gate[bidx * (6 * CH) + ch];
            float bv = bias[ch];
            #pragma unroll
            for (int mi = 0; mi < 4; ++mi) {
                int t = hw0 + wr * 64 + mi * 16 + 4 * lg;
                float4 r4 = *(const float4*)&resb[(size_t)ch * HWN + t];
                f32x4 a = acc[mi][ni];
                float4 o;
                o.x = r4.x + g * (a[0] + bv);
                o.y = r4.y + g * (a[1] + bv);
                o.z = r4.z + g * (a[2] + bv);
                o.w = r4.w + g * (a[3] + bv);
                *(float4*)&outb_[(size_t)ch * HWN + t] = o;
            }
        }
    }
}

// -------- heads + RoPE (2D spatial / 1D cond) + qk-RMSNorm -> bf16 q/k/v --------
__global__ void k_qkv_build(const float* __restrict__ qkvs, const float* __restrict__ qkvc,
                            const float* __restrict__ freqs, const float* __restrict__ qn,
                            const float* __restrict__ kn,
                            unsigned short* __restrict__ qb, unsigned short* __restrict__ kb,
                            unsigned short* __restrict__ vb) {
    int wid = threadIdx.x >> 6, lane = threadIdx.x & 63;
    int gid = blockIdx.x * 4 + wid;
    int bh = gid / TTOT, tok = gid - bh * TTOT;
    int b = bh >> 3;
    int j = lane >> 1;
    float qv = 0.f, kv, vv, ang;
    if (tok < HWN) {
        size_t base = ((size_t)(b * HWN + tok)) * 1536 + (bh & 7) * 64 + lane;
        qv = qkvs[base];
        kv = qkvs[base + 512];
        vv = qkvs[base + 1024];
        ang = (float)(tok >> 5) * freqs[2 * j] + (float)(tok & 31) * freqs[2 * j + 1];
    } else {
        int s = tok - HWN;
        size_t base = ((size_t)(b * SEQ + s)) * 1536 + (bh & 7) * 64 + lane;
        kv = qkvc[base + 512];
        vv = qkvc[base + 1024];
        float inv = expf(-(float)j * (9.210340371976184f / 32.0f));
        ang = (float)s * inv;
    }
    float co = cosf(ang), si = sinf(ang);
    float kp = __shfl_xor(kv, 1);
    float kr = (lane & 1) ? fmaf(kv, co, kp * si) : fmaf(kv, co, -kp * si);
    float qp = __shfl_xor(qv, 1);
    float qr = (lane & 1) ? fmaf(qv, co, qp * si) : fmaf(qv, co, -qp * si);
    float ssk = kr * kr, ssq = qr * qr;
    #pragma unroll
    for (int o = 1; o < 64; o <<= 1) {
        ssk += __shfl_xor(ssk, o);
        ssq += __shfl_xor(ssq, o);
    }
    float kout = kr * rsqrtf(ssk * (1.0f / 64.f) + 1.1920929e-07f) * kn[lane];
    size_t kbase = ((size_t)bh * TTOT + tok) * 64 + lane;
    kb[kbase] = f2bf(kout);
    vb[kbase] = f2bf(vv);
    if (tok < HWN) {
        float qout = qr * rsqrtf(ssq * (1.0f / 64.f) + 1.1920929e-07f) * qn[lane] * 0.125f;
        qb[((size_t)bh * HWN + tok) * 64 + lane] = f2bf(qout);
    }
}

// -------- MFMA flash attention: Qtile=128 (32 rows/wave), KVtile=64 --------
__global__ __launch_bounds__(256) void k_attn_mfma(const unsigned short* __restrict__ qb,
        const unsigned short* __restrict__ kb, const unsigned short* __restrict__ vb,
        unsigned short* __restrict__ ob) {
    __shared__ unsigned short Kl[64 * 64];   // [key][d], swizzled
    __shared__ unsigned short Vt[64 * 64];   // [d][key], swizzled
    __shared__ unsigned short Pl[128 * 64];  // [qrow][key], swizzled
    int bh = blockIdx.y;
    int q0 = blockIdx.x * 128;
    int tid = threadIdx.x;
    int w = tid >> 6, l = tid & 63;
    int lg = l >> 4, ll = l & 15;
    // Q fragments (A operand): rows w*32+mi*16+ll, k = ks*32 + lg*8
    bhalf8 qf[2][2];
    {
        const unsigned short* qbase = qb + ((size_t)bh * HWN + q0 + w * 32) * 64;
        #pragma unroll
        for (int mi = 0; mi < 2; ++mi)
            #pragma unroll
            for (int ks = 0; ks < 2; ++ks)
                qf[mi][ks] = *(const bhalf8*)&qbase[(mi * 16 + ll) * 64 + ks * 32 + lg * 8];
    }
    f32x4 O[2][4] = {};
    float M2[2][4], L2[2][4];
    #pragma unroll
    for (int mi = 0; mi < 2; ++mi)
        #pragma unroll
        for (int r = 0; r < 4; ++r) { M2[mi][r] = -1e30f; L2[mi][r] = 0.f; }
    const size_t kvbase = (size_t)bh * TTOT * 64;
    for (int kt = 0; kt < 18; ++kt) {
        // stage K and V^T (zero-fill tail rows)
        bhalf8 krg[2], vrg[2];
        #pragma unroll
        for (int i = 0; i < 2; ++i) {
            int id = tid + i * 256;
            int r = id >> 3, c8 = id & 7;
            int t = kt * 64 + r;
            bhalf8 kz = {}, vz = {};
            if (t < TTOT) {
                kz = *(const bhalf8*)&kb[kvbase + (size_t)t * 64 + c8 * 8];
                vz = *(const bhalf8*)&vb[kvbase + (size_t)t * 64 + c8 * 8];
            }
            krg[i] = kz; vrg[i] = vz;
        }
        __syncthreads();  // previous iteration's LDS reads complete
        #pragma unroll
        for (int i = 0; i < 2; ++i) {
            int id = tid + i * 256;
            int r = id >> 3, c8 = id & 7;
            *(bhalf8*)((char*)Kl + swz(r * 128 + c8 * 16)) = krg[i];
            #pragma unroll
            for (int u = 0; u < 8; ++u)
                *((unsigned short*)((char*)Vt + swz((c8 * 8 + u) * 128 + r * 2))) =
                    (unsigned short)vrg[i][u];
        }
        __syncthreads();
        // QK^T
        bhalf8 kf[4][2];
        #pragma unroll
        for (int ni = 0; ni < 4; ++ni)
            #pragma unroll
            for (int ks = 0; ks < 2; ++ks)
                kf[ni][ks] = *(const bhalf8*)((char*)Kl + swz((ni * 16 + ll) * 128 + ks * 64 + lg * 16));
        #pragma unroll
        for (int mi = 0; mi < 2; ++mi) {
            float sv[4][4];
            #pragma unroll
            for (int ni = 0; ni < 4; ++ni) {
                f32x4 s = {};
                #pragma unroll
                for (int ks = 0; ks < 2; ++ks)
                    s = __builtin_amdgcn_mfma_f32_16x16x32_bf16(qf[mi][ks], kf[ni][ks], s, 0, 0, 0);
                #pragma unroll
                for (int r = 0; r < 4; ++r) sv[ni][r] = s[r];
            }
            // mask tail keys
            #pragma unroll
            for (int ni = 0; ni < 4; ++ni)
                if (kt * 64 + ni * 16 + ll >= TTOT) {
                    #pragma unroll
                    for (int r = 0; r < 4; ++r) sv[ni][r] = -1e30f;
                }
            // online softmax (per row = 4*lg + r, reduce across 16 lanes)
            #pragma unroll
            for (int r = 0; r < 4; ++r) {
                float mn = fmaxf(fmaxf(sv[0][r], sv[1][r]), fmaxf(sv[2][r], sv[3][r]));
                #pragma unroll
                for (int msk = 1; msk < 16; msk <<= 1) mn = fmaxf(mn, __shfl_xor(mn, msk));
                float mnew = fmaxf(M2[mi][r], mn);
                float alpha = __expf(M2[mi][r] - mnew);
                M2[mi][r] = mnew;
                float rs = 0.f;
                #pragma unroll
                for (int ni = 0; ni < 4; ++ni) {
                    float p = __expf(sv[ni][r] - mnew);
                    sv[ni][r] = p;
                    rs += p;
                }
                #pragma unroll
                for (int msk = 1; msk < 16; msk <<= 1) rs += __shfl_xor(rs, msk);
                L2[mi][r] = L2[mi][r] * alpha + rs;
                #pragma unroll
                for (int nd = 0; nd < 4; ++nd) O[mi][nd][r] *= alpha;
            }
            // write P (bf16) — only this wave reads these rows back
            #pragma unroll
            for (int ni = 0; ni < 4; ++ni)
                #pragma unroll
                for (int r = 0; r < 4; ++r)
                    *((unsigned short*)((char*)Pl +
                        swz((w * 32 + mi * 16 + 4 * lg + r) * 128 + (ni * 16 + ll) * 2))) =
                        f2bf(sv[ni][r]);
        }
        // PV (no barrier needed: P rows are wave-private, V guarded by stage barrier)
        bhalf8 vf[4][2];
        #pragma unroll
        for (int nd = 0; nd < 4; ++nd)
            #pragma unroll
            for (int ks = 0; ks < 2; ++ks)
                vf[nd][ks] = *(const bhalf8*)((char*)Vt + swz((nd * 16 + ll) * 128 + ks * 64 + lg * 16));
        #pragma unroll
        for (int mi = 0; mi < 2; ++mi) {
            bhalf8 pf[2];
            #pragma unroll
            for (int ks = 0; ks < 2; ++ks)
                pf[ks] = *(const bhalf8*)((char*)Pl + swz((w * 32 + mi * 16 + ll) * 128 + ks * 64 + lg * 16));
            #pragma unroll
            for (int nd = 0; nd < 4; ++nd)
                #pragma unroll
                for (int ks = 0; ks < 2; ++ks)
                    O[mi][nd] = __builtin_amdgcn_mfma_f32_16x16x32_bf16(pf[ks], vf[nd][ks], O[mi][nd], 0, 0, 0);
        }
    }
    // epilogue: divide by L, store bf16 token-major [B*HW][512]
    int b = bh >> 3, h = bh & 7;
    #pragma unroll
    for (int mi = 0; mi < 2; ++mi)
        #pragma unroll
        for (int r = 0; r < 4; ++r) {
            float inv = 1.0f / L2[mi][r];
            size_t row = (size_t)(b * HWN + q0 + w * 32 + mi * 16 + 4 * lg + r);
            #pragma unroll
            for (int nd = 0; nd < 4; ++nd)
                ob[row * CH + h * 64 + nd * 16 + ll] = f2bf(O[mi][nd][r] * inv);
        }
}

extern "C" void kernel_launch(void* const* d_in, const int* in_sizes, int n_in,
                              void* d_out, int out_size, void* d_ws, size_t ws_size,
                              hipStream_t stream) {
    const float* x     = (const float*)d_in[0];
    const float* cond  = (const float*)d_in[1];
    const float* femb  = (const float*)d_in[2];
    const float* mod_w = (const float*)d_in[3];
    const float* mod_b = (const float*)d_in[4];
    const float* n1s   = (const float*)d_in[5];
    const float* n2s   = (const float*)d_in[6];
    const float* qkvsw = (const float*)d_in[7];
    const float* qkvcw = (const float*)d_in[8];
    const float* ropef = (const float*)d_in[9];
    const float* qn    = (const float*)d_in[10];
    const float* kn    = (const float*)d_in[11];
    const float* outw  = (const float*)d_in[12];
    const float* outb  = (const float*)d_in[13];
    const float* w1    = (const float*)d_in[14];
    const float* b1    = (const float*)d_in[15];
    const float* w2    = (const float*)d_in[16];
    const float* b2    = (const float*)d_in[17];
    float* out = (float*)d_out;
    char* W = (char*)d_ws;

    // byte layout (total ~90.3 MB, overlays respect liveness)
    unsigned short* wqs_b = (unsigned short*)(W + 0);         // 1536x512
    unsigned short* wqc_b = (unsigned short*)(W + 1572864);   // 1536x768
    unsigned short* wo_b  = (unsigned short*)(W + 3932160);   // 512x512
    unsigned short* w1_b  = (unsigned short*)(W + 4456448);   // 2048x512
    unsigned short* w2_b  = (unsigned short*)(W + 6553600);   // 512x2048
    unsigned short* condb = (unsigned short*)(W + 8650752);   // 616x768
    float* mod            = (float*)(W + 9596928);            // 8x3072
    unsigned short* hmod  = (unsigned short*)(W + 9695232);   // 8192x512 bf16; later reused as q
    unsigned short* qbuf  = hmod;
    float* qkvs           = (float*)(W + 18083840);           // 8192x1536 f32
    unsigned short* obuf  = (unsigned short*)(W + 18083840);            // overlays qkvs[0:8.4M]
    unsigned short* mbuf  = (unsigned short*)(W + 18083840 + 8388608);  // 8192x2048 bf16
    unsigned short* h2    = (unsigned short*)(W + 18083840 + 41943040); // 8192x512 bf16
    float* qkvc           = (float*)(W + 68415488);           // 616x1536 f32
    unsigned short* kbuf  = (unsigned short*)(W + 72200192);  // 64x1101x64 bf16
    float* x1             = (float*)(W + 72200192);           // overlays k(+v head) after attn
    unsigned short* vbuf  = (unsigned short*)(W + 81219584);  // 64x1101x64 bf16

    auto cvt = [&](const float* s, unsigned short* d, int n) {
        k_cvt<<<dim3((n / 4 + 255) / 256), 256, 0, stream>>>(s, d, n);
    };
    cvt(qkvsw, wqs_b, 1536 * 512);
    cvt(qkvcw, wqc_b, 1536 * 768);
    cvt(outw, wo_b, 512 * 512);
    cvt(w1, w1_b, 2048 * 512);
    cvt(w2, w2_b, 512 * 2048);
    cvt(cond, condb, 616 * 768);

    k_modulation<<<dim3(12, BATCH), 256, 0, stream>>>(femb, mod_w, mod_b, mod);
    k_rms2d_mod_t<<<dim3(16, BATCH), 256, 0, stream>>>(x, n1s, mod, 0, 512, hmod);
    // qkv_s: [8192,512] @ [1536,512]^T -> f32 [8192,1536]
    k_gemm_mfma<0><<<dim3(12, 64), 256, 0, stream>>>(hmod, wqs_b, qkvs, 8192, 1536, 512,
                                                     nullptr, nullptr, nullptr);
    // qkv_c: [616,768] @ [1536,768]^T -> f32 [616,1536]
    k_gemm_mfma<0><<<dim3(12, 5), 256, 0, stream>>>(condb, wqc_b, qkvc, 616, 1536, 768,
                                                    nullptr, nullptr, nullptr);
    k_qkv_build<<<dim3((BATCH * NHEAD * TTOT) / 4), 256, 0, stream>>>(
        qkvs, qkvc, ropef, qn, kn, qbuf, kbuf, vbuf);
    k_attn_mfma<<<dim3(8, 64), 256, 0, stream>>>(qbuf, kbuf, vbuf, obuf);
    // out-proj: [8192,512] @ [512,512]^T ; x1 = x + g1*(acc+outb)  (channel-major)
    k_gemm_mfma<1><<<dim3(4, 64), 256, 0, stream>>>(obuf, wo_b, x1, 8192, 512, 512,
                                                    outb, mod + 2 * 512, x);
    k_rms2d_mod_t<<<dim3(16, BATCH), 256, 0, stream>>>(x1, n2s, mod, 3 * 512, 4 * 512, h2);
    // MLP1: [8192,512] @ [2048,512]^T -> gelu -> bf16 [8192,2048]
    k_gemm_mfma<2><<<dim3(16, 64), 256, 0, stream>>>(h2, w1_b, mbuf, 8192, 2048, 512,
                                                     b1, nullptr, nullptr);
    // MLP2: [8192,2048] @ [512,2048]^T ; out = x1 + g2*(acc+b2)  (channel-major)
    k_gemm_mfma<1><<<dim3(4, 64), 256, 0, stream>>>(mbuf, w2_b, out, 8192, 512, 2048,
                                                    b2, mod + 5 * 512, x1);
}

// Round 3
// 338.147 us; speedup vs baseline: 4.3575x; 1.0522x over previous
//
#include <hip/hip_runtime.h>

// FluxUNet fused block — round 3: gload_lds GEMM + swapped-QK MFMA attention.
// B=8, C=512, HW=1024, S=77, E=768, NH=8, HD=64, HID=2048, T=1101.
constexpr int BATCH = 8, CH = 512, HWN = 1024, SEQ = 77, EMB = 768;
constexpr int NHEAD = 8, HDIM = 64, HIDDEN = 2048, TTOT = 1101;
constexpr int VSTRIDE = 1152;  // padded t-stride for transposed V

typedef short bhalf8 __attribute__((ext_vector_type(8)));
typedef float f32x4 __attribute__((ext_vector_type(4)));

__device__ __forceinline__ unsigned short f2bf(float f) {
    unsigned u = __builtin_bit_cast(unsigned, f);
    unsigned r = (u + 0x7fffu + ((u >> 16) & 1u)) >> 16;
    return (unsigned short)r;
}
__device__ __forceinline__ float gelu_tanh(float v) {
    float c = v * v * v;
    float t = tanhf(0.7978845608028654f * (v + 0.044715f * c));
    return 0.5f * v * (1.0f + t);
}
// XOR-swizzle on a 128B-row-stride LDS tile (XORs 16B-block index with row&7).
__device__ __forceinline__ int swz(int b) { return b ^ ((b >> 3) & 0x70); }

// async global->LDS 16B: LDS dest = wave-uniform base + lane*16.
__device__ __forceinline__ void gload16(const void* g, void* l) {
#if __has_builtin(__builtin_amdgcn_global_load_lds)
    __builtin_amdgcn_global_load_lds(
        (const __attribute__((address_space(1))) unsigned int*)g,
        (__attribute__((address_space(3))) unsigned int*)l, 16, 0, 0);
#else
    // fallback: per-lane copy (lane offset applied by caller-visible contract)
    ((bhalf8*)l)[threadIdx.x & 63] = ((const bhalf8*)g)[0];
#endif
}

// ---------------- merged f32 -> bf16 weight/activation casts ----------------
struct CvtArgs {
    const float* src[6];
    unsigned short* dst[6];
    int n[6];
};
__global__ void k_cvt_all(CvtArgs a) {
    int t = blockIdx.y;
    int i = (blockIdx.x * 256 + threadIdx.x) * 4;
    if (i >= a.n[t]) return;
    float4 v = *(const float4*)&a.src[t][i];
    ushort4 o = {f2bf(v.x), f2bf(v.y), f2bf(v.z), f2bf(v.w)};
    *(ushort4*)&a.dst[t][i] = o;
}

// ---------------- mod = silu(final_emb) @ mod_w + mod_b ----------------
__global__ void k_modulation(const float* __restrict__ emb, const float* __restrict__ w,
                             const float* __restrict__ bias, float* __restrict__ mod) {
    __shared__ float se[EMB];
    int b = blockIdx.y;
    int tid = threadIdx.x;
    for (int i = tid; i < EMB; i += 256) {
        float v = emb[b * EMB + i];
        se[i] = v / (1.0f + expf(-v));
    }
    __syncthreads();
    int j = blockIdx.x * 256 + tid;
    float acc = 0.0f;
    #pragma unroll 8
    for (int e = 0; e < EMB; ++e) acc = fmaf(se[e], w[e * (6 * CH) + j], acc);
    mod[b * (6 * CH) + j] = acc + bias[j];
}

// ------- RMSNorm(channel) + adaLN modulate + transpose -> bf16 token-major -------
__global__ __launch_bounds__(256) void k_rms2d_mod_t(const float* __restrict__ xin,
        const float* __restrict__ sw, const float* __restrict__ mod, int shoff, int scoff,
        unsigned short* __restrict__ outp) {
    __shared__ float part[4][64];
    __shared__ float rinv[64];
    int b = blockIdx.y;
    int n0 = blockIdx.x * 64;
    int tid = threadIdx.x;
    const float* xb = xin + (size_t)b * CH * HWN;
    {
        int n = n0 + (tid & 63);
        int cg = tid >> 6;
        float ss = 0.f;
        #pragma unroll 8
        for (int c = cg * 128; c < cg * 128 + 128; ++c) {
            float v = xb[(size_t)c * HWN + n];
            ss = fmaf(v, v, ss);
        }
        part[cg][tid & 63] = ss;
    }
    __syncthreads();
    if (tid < 64) {
        float s = part[0][tid] + part[1][tid] + part[2][tid] + part[3][tid];
        rinv[tid] = rsqrtf(s * (1.0f / CH) + 1e-6f);
    }
    __syncthreads();
    int n = n0 + (tid >> 2);
    int cq = tid & 3;
    float r = rinv[tid >> 2];
    const float* mb = mod + b * (6 * CH);
    unsigned short* orow = outp + ((size_t)(b * HWN + n)) * CH;
    for (int jc = 0; jc < 16; ++jc) {
        int c = cq * 128 + jc * 8;
        bhalf8 o;
        #pragma unroll
        for (int u = 0; u < 8; ++u) {
            int cc = c + u;
            float v = xb[(size_t)cc * HWN + n];
            float y = v * r * sw[cc] * (1.0f + mb[scoff + cc]) + mb[shoff + cc];
            o[u] = (short)f2bf(y);
        }
        *(bhalf8*)&orow[c] = o;
    }
}

// ---------------- bf16 MFMA GEMM (m97 structure): 128x128, BK=64, gload_lds ----------------
// A [M][K], Bt [N][K] bf16 row-major. K%64==0, N%128==0, M row-clamped.
template <int EPI>
__global__ __launch_bounds__(256) void k_gemm_mfma(
        const unsigned short* __restrict__ A, const unsigned short* __restrict__ Bt,
        void* __restrict__ OutV, int M, int N, int K,
        const float* __restrict__ bias, const float* __restrict__ gate,
        const float* __restrict__ res) {
    __shared__ unsigned short As[8192];
    __shared__ unsigned short Bs[8192];
    int tid = threadIdx.x;
    int w = tid >> 6, l = tid & 63, lg = l >> 4, ll = l & 15;
    int wr = w >> 1, wc = w & 1;
    int m0 = blockIdx.y * 128, n0 = blockIdx.x * 128;
    int r8 = l >> 3, c16 = (l & 7) * 16;
    f32x4 acc[4][4] = {};
    const char* Ac = (const char*)A;
    const char* Bc = (const char*)Bt;
    size_t rowBytes = (size_t)K * 2;
    for (int k0 = 0; k0 < K; k0 += 64) {
        __syncthreads();
        #pragma unroll
        for (int i = 0; i < 4; ++i) {
            int c = w * 4 + i;
            int row = c * 8 + r8;
            int off = c16 ^ ((row & 7) << 4);   // inverse-swizzled source
            int ar = m0 + row;
            if (ar > M - 1) ar = M - 1;
            gload16(Ac + (size_t)ar * rowBytes + k0 * 2 + off, (char*)As + c * 1024);
            gload16(Bc + (size_t)(n0 + row) * rowBytes + k0 * 2 + off, (char*)Bs + c * 1024);
        }
        __syncthreads();
        #pragma unroll
        for (int ks = 0; ks < 2; ++ks) {
            bhalf8 af[4], bf[4];
            #pragma unroll
            for (int mi = 0; mi < 4; ++mi)
                af[mi] = *(const bhalf8*)((char*)As + swz((wr * 64 + mi * 16 + ll) * 128 + ks * 64 + lg * 16));
            #pragma unroll
            for (int ni = 0; ni < 4; ++ni)
                bf[ni] = *(const bhalf8*)((char*)Bs + swz((wc * 64 + ni * 16 + ll) * 128 + ks * 64 + lg * 16));
            #pragma unroll
            for (int mi = 0; mi < 4; ++mi)
                #pragma unroll
                for (int ni = 0; ni < 4; ++ni)
                    acc[mi][ni] = __builtin_amdgcn_mfma_f32_16x16x32_bf16(af[mi], bf[ni], acc[mi][ni], 0, 0, 0);
        }
    }
    if (EPI == 0) {
        float* Out = (float*)OutV;
        #pragma unroll
        for (int mi = 0; mi < 4; ++mi)
            #pragma unroll
            for (int ni = 0; ni < 4; ++ni) {
                int col = n0 + wc * 64 + ni * 16 + ll;
                #pragma unroll
                for (int r = 0; r < 4; ++r) {
                    int mrow = m0 + wr * 64 + mi * 16 + 4 * lg + r;
                    if (mrow < M) Out[(size_t)mrow * N + col] = acc[mi][ni][r];
                }
            }
    } else if (EPI == 2) {
        unsigned short* Out = (unsigned short*)OutV;
        #pragma unroll
        for (int mi = 0; mi < 4; ++mi)
            #pragma unroll
            for (int ni = 0; ni < 4; ++ni) {
                int col = n0 + wc * 64 + ni * 16 + ll;
                float bv = bias[col];
                #pragma unroll
                for (int r = 0; r < 4; ++r) {
                    int mrow = m0 + wr * 64 + mi * 16 + 4 * lg + r;
                    Out[(size_t)mrow * N + col] = f2bf(gelu_tanh(acc[mi][ni][r] + bv));
                }
            }
    } else {
        float* Out = (float*)OutV;
        int bidx = m0 >> 10;
        int hw0 = m0 & 1023;
        const float* resb = res + (size_t)bidx * N * HWN;
        float* outb_ = Out + (size_t)bidx * N * HWN;
        #pragma unroll
        for (int ni = 0; ni < 4; ++ni) {
            int ch = n0 + wc * 64 + ni * 16 + ll;
            float g = gate[bidx * (6 * CH) + ch];
            float bv = bias[ch];
            #pragma unroll
            for (int mi = 0; mi < 4; ++mi) {
                int t = hw0 + wr * 64 + mi * 16 + 4 * lg;
                float4 r4 = *(const float4*)&resb[(size_t)ch * HWN + t];
                f32x4 a = acc[mi][ni];
                float4 o;
                o.x = r4.x + g * (a[0] + bv);
                o.y = r4.y + g * (a[1] + bv);
                o.z = r4.z + g * (a[2] + bv);
                o.w = r4.w + g * (a[3] + bv);
                *(float4*)&outb_[(size_t)ch * HWN + t] = o;
            }
        }
    }
}

// -------- V transpose: qkv f32 v-slice -> vT[bh][d][t] bf16 (t padded to 1152) --------
__global__ __launch_bounds__(256) void k_transpose_v(const float* __restrict__ qkvs,
        const float* __restrict__ qkvc, unsigned short* __restrict__ vT) {
    __shared__ unsigned short T[64][72];
    int bh = blockIdx.y, tk = blockIdx.x;
    int b = bh >> 3, h = bh & 7;
    int tid = threadIdx.x;
    {
        int tq = tid >> 2, dg = tid & 3;
        int t = tk * 64 + tq;
        const float* src = nullptr;
        if (t < HWN) src = qkvs + ((size_t)(b * HWN + t)) * 1536 + 1024 + h * 64 + dg * 16;
        else if (t < TTOT) src = qkvc + ((size_t)(b * SEQ + t - HWN)) * 1536 + 1024 + h * 64 + dg * 16;
        #pragma unroll
        for (int i = 0; i < 4; ++i) {
            float4 v = src ? *(const float4*)&src[i * 4] : make_float4(0.f, 0.f, 0.f, 0.f);
            ushort4 o = {f2bf(v.x), f2bf(v.y), f2bf(v.z), f2bf(v.w)};
            *(ushort4*)&T[tq][dg * 16 + i * 4] = o;
        }
    }
    __syncthreads();
    {
        int d = tid >> 2, tg = tid & 3;
        bhalf8 o0, o1;
        #pragma unroll
        for (int i = 0; i < 8; ++i) {
            o0[i] = (short)T[tg * 16 + i][d];
            o1[i] = (short)T[tg * 16 + 8 + i][d];
        }
        size_t base = ((size_t)(bh * 64 + d)) * VSTRIDE + tk * 64 + tg * 16;
        *(bhalf8*)&vT[base] = o0;
        *(bhalf8*)&vT[base + 8] = o1;
    }
}

// -------- heads + RoPE + qk-RMSNorm -> bf16 q (x0.125*log2e) and k --------
__global__ void k_qkv_build(const float* __restrict__ qkvs, const float* __restrict__ qkvc,
                            const float* __restrict__ freqs, const float* __restrict__ qn,
                            const float* __restrict__ kn,
                            unsigned short* __restrict__ qb, unsigned short* __restrict__ kb) {
    int wid = threadIdx.x >> 6, lane = threadIdx.x & 63;
    int gid = blockIdx.x * 4 + wid;
    int bh = gid / TTOT, tok = gid - bh * TTOT;
    int b = bh >> 3;
    int j = lane >> 1;
    float qv = 0.f, kv, ang;
    if (tok < HWN) {
        size_t base = ((size_t)(b * HWN + tok)) * 1536 + (bh & 7) * 64 + lane;
        qv = qkvs[base];
        kv = qkvs[base + 512];
        ang = (float)(tok >> 5) * freqs[2 * j] + (float)(tok & 31) * freqs[2 * j + 1];
    } else {
        int s = tok - HWN;
        size_t base = ((size_t)(b * SEQ + s)) * 1536 + (bh & 7) * 64 + lane;
        kv = qkvc[base + 512];
        float inv = expf(-(float)j * (9.210340371976184f / 32.0f));
        ang = (float)s * inv;
    }
    float co = cosf(ang), si = sinf(ang);
    float kp = __shfl_xor(kv, 1);
    float kr = (lane & 1) ? fmaf(kv, co, kp * si) : fmaf(kv, co, -kp * si);
    float qp = __shfl_xor(qv, 1);
    float qr = (lane & 1) ? fmaf(qv, co, qp * si) : fmaf(qv, co, -qp * si);
    float ssk = kr * kr, ssq = qr * qr;
    #pragma unroll
    for (int o = 1; o < 64; o <<= 1) {
        ssk += __shfl_xor(ssk, o);
        ssq += __shfl_xor(ssq, o);
    }
    float kout = kr * rsqrtf(ssk * (1.0f / 64.f) + 1.1920929e-07f) * kn[lane];
    kb[((size_t)bh * TTOT + tok) * 64 + lane] = f2bf(kout);
    if (tok < HWN) {
        // 0.125 attn scale * log2(e): softmax runs in exp2 domain
        float qout = qr * rsqrtf(ssq * (1.0f / 64.f) + 1.1920929e-07f) * qn[lane] * 0.18033688011112042f;
        qb[((size_t)bh * HWN + tok) * 64 + lane] = f2bf(qout);
    }
}

// -------- swapped-QK flash attention: S^T = K·Q, O^T = V^T·P; Qtile=128, KVtile=64 --------
__global__ __launch_bounds__(256) void k_attn_v3(const unsigned short* __restrict__ qb,
        const unsigned short* __restrict__ kbuf, const unsigned short* __restrict__ vT,
        unsigned short* __restrict__ ob) {
    __shared__ unsigned short SM[16384];  // [0,8KB) K tile, [8,16KB) V^T tile, [16,32KB) per-wave P
    char* smc = (char*)SM;
    int bh = blockIdx.y;
    int q0 = blockIdx.x * 128;
    int tid = threadIdx.x;
    int w = tid >> 6, l = tid & 63, lg = l >> 4, ll = l & 15;
    int r8 = l >> 3, c16 = (l & 7) * 16;
    // Q fragments (B operand): lane holds Q[q=qblk*16+ll][d=ks*32+lg*8 ..+7]
    bhalf8 qf[2][2];
    {
        const unsigned short* qbase = qb + ((size_t)bh * HWN + q0 + w * 32) * 64;
        #pragma unroll
        for (int q_ = 0; q_ < 2; ++q_)
            #pragma unroll
            for (int ks = 0; ks < 2; ++ks)
                qf[q_][ks] = *(const bhalf8*)&qbase[(q_ * 16 + ll) * 64 + ks * 32 + lg * 8];
    }
    f32x4 accO[4][2] = {};  // O^T[d=d4*16+4lg+r][q=q_*16+ll]
    float Mx[2] = {-1e30f, -1e30f}, Lx[2] = {0.f, 0.f};
    const char* kgl = (const char*)kbuf + (size_t)bh * TTOT * 128;
    const char* vgl = (const char*)vT + (size_t)bh * 64 * (VSTRIDE * 2);
    for (int kt = 0; kt < 18; ++kt) {
        __syncthreads();  // previous tile fully consumed
        #pragma unroll
        for (int i = 0; i < 2; ++i) {
            int c = w * 2 + i;
            int row = c * 8 + r8;
            int off = c16 ^ ((row & 7) << 4);  // inverse-swizzled source
            int t = kt * 64 + row;
            if (t > TTOT - 1) t = TTOT - 1;    // clamped rows are softmax-masked
            gload16(kgl + (size_t)t * 128 + off, smc + c * 1024);
            gload16(vgl + (size_t)row * (VSTRIDE * 2) + kt * 128 + off, smc + 8192 + c * 1024);
        }
        __syncthreads();
        // S^T = K x Q : A=K rows=key, B=Q cols=q
        f32x4 s[4][2] = {};
        #pragma unroll
        for (int ks = 0; ks < 2; ++ks) {
            bhalf8 kf[4];
            #pragma unroll
            for (int k4 = 0; k4 < 4; ++k4)
                kf[k4] = *(const bhalf8*)(smc + swz((k4 * 16 + ll) * 128 + ks * 64 + lg * 16));
            #pragma unroll
            for (int k4 = 0; k4 < 4; ++k4)
                #pragma unroll
                for (int q_ = 0; q_ < 2; ++q_)
                    s[k4][q_] = __builtin_amdgcn_mfma_f32_16x16x32_bf16(kf[k4], qf[q_][ks], s[k4][q_], 0, 0, 0);
        }
        // mask tail keys (key index is lane-local: k4*16 + 4lg + r)
        int kb0 = kt * 64 + 4 * lg;
        #pragma unroll
        for (int k4 = 0; k4 < 4; ++k4)
            #pragma unroll
            for (int r = 0; r < 4; ++r)
                if (kb0 + k4 * 16 + r >= TTOT) { s[k4][0][r] = -1e30f; s[k4][1][r] = -1e30f; }
        // online softmax per qblk (q = ll lane-local; reduce 16 local + 2 shfl)
        #pragma unroll
        for (int q_ = 0; q_ < 2; ++q_) {
            float ml = s[0][q_][0];
            #pragma unroll
            for (int k4 = 0; k4 < 4; ++k4)
                #pragma unroll
                for (int r = 0; r < 4; ++r) ml = fmaxf(ml, s[k4][q_][r]);
            ml = fmaxf(ml, __shfl_xor(ml, 16));
            ml = fmaxf(ml, __shfl_xor(ml, 32));
            float mnew = fmaxf(Mx[q_], ml);
            float alpha = exp2f(Mx[q_] - mnew);
            Mx[q_] = mnew;
            float sum = 0.f;
            #pragma unroll
            for (int k4 = 0; k4 < 4; ++k4)
                #pragma unroll
                for (int r = 0; r < 4; ++r) {
                    float p = exp2f(s[k4][q_][r] - mnew);
                    s[k4][q_][r] = p;
                    sum += p;
                }
            sum += __shfl_xor(sum, 16);
            sum += __shfl_xor(sum, 32);
            Lx[q_] = Lx[q_] * alpha + sum;
            #pragma unroll
            for (int d4 = 0; d4 < 4; ++d4)
                #pragma unroll
                for (int r = 0; r < 4; ++r) accO[d4][q_][r] *= alpha;
            // P -> wave-private LDS [q 32][key 64], packed b64 runs (keys k4*16+4lg+{0..3})
            int prow = q_ * 16 + ll;
            char* pw = smc + 16384 + w * 4096 + prow * 128;
            int pswz = (prow & 7) << 4;
            #pragma unroll
            for (int k4 = 0; k4 < 4; ++k4) {
                ushort4 pk = {f2bf(s[k4][q_][0]), f2bf(s[k4][q_][1]),
                              f2bf(s[k4][q_][2]), f2bf(s[k4][q_][3])};
                *(ushort4*)(pw + ((k4 * 32 + lg * 8) ^ pswz)) = pk;
            }
        }
        // O^T += V^T x P : A=V^T rows=d, B=P cols=q (wave-private, no barrier needed)
        #pragma unroll
        for (int ks = 0; ks < 2; ++ks) {
            bhalf8 vf[4], pf[2];
            #pragma unroll
            for (int d4 = 0; d4 < 4; ++d4)
                vf[d4] = *(const bhalf8*)(smc + 8192 + swz((d4 * 16 + ll) * 128 + ks * 64 + lg * 16));
            #pragma unroll
            for (int q_ = 0; q_ < 2; ++q_)
                pf[q_] = *(const bhalf8*)(smc + 16384 + w * 4096 + swz((q_ * 16 + ll) * 128 + ks * 64 + lg * 16));
            #pragma unroll
            for (int d4 = 0; d4 < 4; ++d4)
                #pragma unroll
                for (int q_ = 0; q_ < 2; ++q_)
                    accO[d4][q_] = __builtin_amdgcn_mfma_f32_16x16x32_bf16(vf[d4], pf[q_], accO[d4][q_], 0, 0, 0);
        }
    }
    // epilogue: /L (lane-local), transpose O^T -> [q][d] via LDS, coalesced bf16 stores
    __syncthreads();
    #pragma unroll
    for (int q_ = 0; q_ < 2; ++q_) {
        float inv = 1.0f / Lx[q_];
        int orow = w * 32 + q_ * 16 + ll;
        char* po = smc + orow * 128;
        int oswz = (orow & 7) << 4;
        #pragma unroll
        for (int d4 = 0; d4 < 4; ++d4) {
            ushort4 pk = {f2bf(accO[d4][q_][0] * inv), f2bf(accO[d4][q_][1] * inv),
                          f2bf(accO[d4][q_][2] * inv), f2bf(accO[d4][q_][3] * inv)};
            *(ushort4*)(po + ((d4 * 32 + lg * 8) ^ oswz)) = pk;
        }
    }
    __syncthreads();
    int b = bh >> 3, h = bh & 7;
    int qr = tid >> 1, half = tid & 1;
    unsigned short* dst = ob + ((size_t)(b * HWN + q0 + qr)) * CH + h * 64 + half * 32;
    #pragma unroll
    for (int i = 0; i < 4; ++i) {
        bhalf8 v = *(const bhalf8*)(smc + swz(qr * 128 + half * 64 + i * 16));
        *(bhalf8*)&dst[i * 8] = v;
    }
}

extern "C" void kernel_launch(void* const* d_in, const int* in_sizes, int n_in,
                              void* d_out, int out_size, void* d_ws, size_t ws_size,
                              hipStream_t stream) {
    const float* x     = (const float*)d_in[0];
    const float* cond  = (const float*)d_in[1];
    const float* femb  = (const float*)d_in[2];
    const float* mod_w = (const float*)d_in[3];
    const float* mod_b = (const float*)d_in[4];
    const float* n1s   = (const float*)d_in[5];
    const float* n2s   = (const float*)d_in[6];
    const float* qkvsw = (const float*)d_in[7];
    const float* qkvcw = (const float*)d_in[8];
    const float* ropef = (const float*)d_in[9];
    const float* qn    = (const float*)d_in[10];
    const float* kn    = (const float*)d_in[11];
    const float* outw  = (const float*)d_in[12];
    const float* outb  = (const float*)d_in[13];
    const float* w1    = (const float*)d_in[14];
    const float* b1    = (const float*)d_in[15];
    const float* w2    = (const float*)d_in[16];
    const float* b2    = (const float*)d_in[17];
    float* out = (float*)d_out;
    char* W = (char*)d_ws;

    // byte layout (~90.7 MB peak, overlays respect liveness)
    unsigned short* wqs_b = (unsigned short*)(W + 0);         // 1536x512
    unsigned short* wqc_b = (unsigned short*)(W + 1572864);   // 1536x768
    unsigned short* wo_b  = (unsigned short*)(W + 3932160);   // 512x512
    unsigned short* w1_b  = (unsigned short*)(W + 4456448);   // 2048x512
    unsigned short* w2_b  = (unsigned short*)(W + 6553600);   // 512x2048
    unsigned short* condb = (unsigned short*)(W + 8650752);   // 616x768
    float* mod            = (float*)(W + 9596928);            // 8x3072
    unsigned short* hmod  = (unsigned short*)(W + 9695232);   // 8192x512 bf16 (later: q)
    unsigned short* qbuf  = hmod;
    float* qkvs           = (float*)(W + 18083840);           // 8192x1536 f32
    unsigned short* obuf  = (unsigned short*)(W + 18083840);            // overlays qkvs head
    unsigned short* mbuf  = (unsigned short*)(W + 18083840 + 8388608);  // 8192x2048 bf16
    unsigned short* h2    = (unsigned short*)(W + 60026880);  // 8192x512 bf16
    float* qkvc           = (float*)(W + 68415488);           // 616x1536 f32
    unsigned short* kbuf  = (unsigned short*)(W + 72200192);  // 64x1101x64 bf16
    float* x1             = (float*)(W + 72200192);           // overlays kbuf+vT after attn
    unsigned short* vTb   = (unsigned short*)(W + 81218560);  // 64x64x1152 bf16

    CvtArgs ca;
    ca.src[0] = qkvsw; ca.dst[0] = wqs_b; ca.n[0] = 1536 * 512;
    ca.src[1] = qkvcw; ca.dst[1] = wqc_b; ca.n[1] = 1536 * 768;
    ca.src[2] = outw;  ca.dst[2] = wo_b;  ca.n[2] = 512 * 512;
    ca.src[3] = w1;    ca.dst[3] = w1_b;  ca.n[3] = 2048 * 512;
    ca.src[4] = w2;    ca.dst[4] = w2_b;  ca.n[4] = 512 * 2048;
    ca.src[5] = cond;  ca.dst[5] = condb; ca.n[5] = 616 * 768;
    k_cvt_all<<<dim3(1152, 6), 256, 0, stream>>>(ca);

    k_modulation<<<dim3(12, BATCH), 256, 0, stream>>>(femb, mod_w, mod_b, mod);
    k_rms2d_mod_t<<<dim3(16, BATCH), 256, 0, stream>>>(x, n1s, mod, 0, 512, hmod);
    // qkv_s: [8192,512] @ [1536,512]^T -> f32 [8192,1536]
    k_gemm_mfma<0><<<dim3(12, 64), 256, 0, stream>>>(hmod, wqs_b, qkvs, 8192, 1536, 512,
                                                     nullptr, nullptr, nullptr);
    // qkv_c: [616,768] @ [1536,768]^T -> f32 [616,1536]
    k_gemm_mfma<0><<<dim3(12, 5), 256, 0, stream>>>(condb, wqc_b, qkvc, 616, 1536, 768,
                                                    nullptr, nullptr, nullptr);
    k_transpose_v<<<dim3(18, 64), 256, 0, stream>>>(qkvs, qkvc, vTb);
    k_qkv_build<<<dim3((BATCH * NHEAD * TTOT) / 4), 256, 0, stream>>>(
        qkvs, qkvc, ropef, qn, kn, qbuf, kbuf);
    k_attn_v3<<<dim3(8, 64), 256, 0, stream>>>(qbuf, kbuf, vTb, obuf);
    // out-proj: x1 = x + g1*(obuf @ Wo^T + outb)  (channel-major f32)
    k_gemm_mfma<1><<<dim3(4, 64), 256, 0, stream>>>(obuf, wo_b, x1, 8192, 512, 512,
                                                    outb, mod + 2 * 512, x);
    k_rms2d_mod_t<<<dim3(16, BATCH), 256, 0, stream>>>(x1, n2s, mod, 3 * 512, 4 * 512, h2);
    // MLP1 + gelu -> bf16 [8192,2048]
    k_gemm_mfma<2><<<dim3(16, 64), 256, 0, stream>>>(h2, w1_b, mbuf, 8192, 2048, 512,
                                                     b1, nullptr, nullptr);
    // MLP2 + gate + residual -> d_out (channel-major f32)
    k_gemm_mfma<1><<<dim3(4, 64), 256, 0, stream>>>(mbuf, w2_b, out, 8192, 512, 2048,
                                                    b2, mod + 5 * 512, x1);
}

// Round 4
// 314.955 us; speedup vs baseline: 4.6783x; 1.0736x over previous
//
#include <hip/hip_runtime.h>

// FluxUNet fused block — round 4: occupancy (attn Qtile=64, small-N GEMM tiles 64x64).
// B=8, C=512, HW=1024, S=77, E=768, NH=8, HD=64, HID=2048, T=1101.
constexpr int BATCH = 8, CH = 512, HWN = 1024, SEQ = 77, EMB = 768;
constexpr int NHEAD = 8, HDIM = 64, HIDDEN = 2048, TTOT = 1101;
constexpr int VSTRIDE = 1152;  // padded t-stride for transposed V

typedef short bhalf8 __attribute__((ext_vector_type(8)));
typedef float f32x4 __attribute__((ext_vector_type(4)));

__device__ __forceinline__ unsigned short f2bf(float f) {
    unsigned u = __builtin_bit_cast(unsigned, f);
    unsigned r = (u + 0x7fffu + ((u >> 16) & 1u)) >> 16;
    return (unsigned short)r;
}
// packed f32x2 -> bf16x2 (RTNE), single VALU inst
__device__ __forceinline__ unsigned cvtpk(float a, float b) {
    unsigned r;
    asm("v_cvt_pk_bf16_f32 %0, %1, %2" : "=v"(r) : "v"(a), "v"(b));
    return r;
}
__device__ __forceinline__ float gelu_tanh(float v) {
    float c = v * v * v;
    float t = tanhf(0.7978845608028654f * (v + 0.044715f * c));
    return 0.5f * v * (1.0f + t);
}
// XOR-swizzle on a 128B-row-stride LDS tile (region base must be 1024B-aligned).
__device__ __forceinline__ int swz(int b) { return b ^ ((b >> 3) & 0x70); }

// async global->LDS 16B: LDS dest = wave-uniform base + lane*16.
__device__ __forceinline__ void gload16(const void* g, void* l) {
    __builtin_amdgcn_global_load_lds(
        (const __attribute__((address_space(1))) unsigned int*)g,
        (__attribute__((address_space(3))) unsigned int*)l, 16, 0, 0);
}

// ---------------- merged f32 -> bf16 weight/activation casts ----------------
struct CvtArgs {
    const float* src[6];
    unsigned short* dst[6];
    int n[6];
};
__global__ void k_cvt_all(CvtArgs a) {
    int t = blockIdx.y;
    int i = (blockIdx.x * 256 + threadIdx.x) * 4;
    if (i >= a.n[t]) return;
    float4 v = *(const float4*)&a.src[t][i];
    ushort4 o = {f2bf(v.x), f2bf(v.y), f2bf(v.z), f2bf(v.w)};
    *(ushort4*)&a.dst[t][i] = o;
}

// ---------------- mod = silu(final_emb) @ mod_w + mod_b ----------------
__global__ void k_modulation(const float* __restrict__ emb, const float* __restrict__ w,
                             const float* __restrict__ bias, float* __restrict__ mod) {
    __shared__ float se[EMB];
    int b = blockIdx.y;
    int tid = threadIdx.x;
    for (int i = tid; i < EMB; i += 256) {
        float v = emb[b * EMB + i];
        se[i] = v / (1.0f + expf(-v));
    }
    __syncthreads();
    int j = blockIdx.x * 256 + tid;
    float acc = 0.0f;
    #pragma unroll 8
    for (int e = 0; e < EMB; ++e) acc = fmaf(se[e], w[e * (6 * CH) + j], acc);
    mod[b * (6 * CH) + j] = acc + bias[j];
}

// ------- RMSNorm(channel) + adaLN modulate + transpose -> bf16 token-major -------
__global__ __launch_bounds__(256) void k_rms2d_mod_t(const float* __restrict__ xin,
        const float* __restrict__ sw, const float* __restrict__ mod, int shoff, int scoff,
        unsigned short* __restrict__ outp) {
    __shared__ float part[4][64];
    __shared__ float rinv[64];
    int b = blockIdx.y;
    int n0 = blockIdx.x * 64;
    int tid = threadIdx.x;
    const float* xb = xin + (size_t)b * CH * HWN;
    {
        int n = n0 + (tid & 63);
        int cg = tid >> 6;
        float ss = 0.f;
        #pragma unroll 8
        for (int c = cg * 128; c < cg * 128 + 128; ++c) {
            float v = xb[(size_t)c * HWN + n];
            ss = fmaf(v, v, ss);
        }
        part[cg][tid & 63] = ss;
    }
    __syncthreads();
    if (tid < 64) {
        float s = part[0][tid] + part[1][tid] + part[2][tid] + part[3][tid];
        rinv[tid] = rsqrtf(s * (1.0f / CH) + 1e-6f);
    }
    __syncthreads();
    int n = n0 + (tid >> 2);
    int cq = tid & 3;
    float r = rinv[tid >> 2];
    const float* mb = mod + b * (6 * CH);
    unsigned short* orow = outp + ((size_t)(b * HWN + n)) * CH;
    for (int jc = 0; jc < 16; ++jc) {
        int c = cq * 128 + jc * 8;
        bhalf8 o;
        #pragma unroll
        for (int u = 0; u < 8; ++u) {
            int cc = c + u;
            float v = xb[(size_t)cc * HWN + n];
            float y = v * r * sw[cc] * (1.0f + mb[scoff + cc]) + mb[shoff + cc];
            o[u] = (short)f2bf(y);
        }
        *(bhalf8*)&orow[c] = o;
    }
}

// ---------------- bf16 MFMA GEMM: BMxBN tile, BK=64, 4 waves, gload_lds ----------------
// A [M][K], Bt [N][K] bf16 row-major. K%64==0, N%BN==0, M row-clamped.
// EPI=0: f32 [M][N].  EPI=1: f32 channel-major residual+gate.  EPI=2: bf16 gelu.
template <int EPI, int BM, int BN>
__global__ __launch_bounds__(256) void k_gemm_mfma(
        const unsigned short* __restrict__ A, const unsigned short* __restrict__ Bt,
        void* __restrict__ OutV, int M, int N, int K,
        const float* __restrict__ bias, const float* __restrict__ gate,
        const float* __restrict__ res) {
    constexpr int WM = BM / 2, WN = BN / 2;
    constexpr int MI = WM / 16, NI = WN / 16;
    constexpr int CA = BM / 8, CB = BN / 8, CW = (CA + CB) / 4;
    __shared__ __align__(1024) unsigned short As[BM * 64];
    __shared__ __align__(1024) unsigned short Bs[BN * 64];
    int tid = threadIdx.x;
    int w = tid >> 6, l = tid & 63, lg = l >> 4, ll = l & 15;
    int wr = w >> 1, wc = w & 1;
    int m0 = blockIdx.y * BM, n0 = blockIdx.x * BN;
    int r8 = l >> 3, c16 = (l & 7) * 16;
    f32x4 acc[MI][NI] = {};
    const char* Ac = (const char*)A;
    const char* Bc = (const char*)Bt;
    size_t rowBytes = (size_t)K * 2;
    for (int k0 = 0; k0 < K; k0 += 64) {
        __syncthreads();
        #pragma unroll
        for (int i = 0; i < CW; ++i) {
            int c = w * CW + i;
            if (c < CA) {
                int row = c * 8 + r8;
                int off = c16 ^ ((row & 7) << 4);
                int ar = m0 + row;
                if (ar > M - 1) ar = M - 1;
                gload16(Ac + (size_t)ar * rowBytes + k0 * 2 + off, (char*)As + c * 1024);
            } else {
                int cc = c - CA;
                int row = cc * 8 + r8;
                int off = c16 ^ ((row & 7) << 4);
                gload16(Bc + (size_t)(n0 + row) * rowBytes + k0 * 2 + off, (char*)Bs + cc * 1024);
            }
        }
        __syncthreads();
        #pragma unroll
        for (int ks = 0; ks < 2; ++ks) {
            bhalf8 af[MI], bf[NI];
            #pragma unroll
            for (int mi = 0; mi < MI; ++mi)
                af[mi] = *(const bhalf8*)((char*)As + swz((wr * WM + mi * 16 + ll) * 128 + ks * 64 + lg * 16));
            #pragma unroll
            for (int ni = 0; ni < NI; ++ni)
                bf[ni] = *(const bhalf8*)((char*)Bs + swz((wc * WN + ni * 16 + ll) * 128 + ks * 64 + lg * 16));
            #pragma unroll
            for (int mi = 0; mi < MI; ++mi)
                #pragma unroll
                for (int ni = 0; ni < NI; ++ni)
                    acc[mi][ni] = __builtin_amdgcn_mfma_f32_16x16x32_bf16(af[mi], bf[ni], acc[mi][ni], 0, 0, 0);
        }
    }
    if (EPI == 0) {
        float* Out = (float*)OutV;
        #pragma unroll
        for (int mi = 0; mi < MI; ++mi)
            #pragma unroll
            for (int ni = 0; ni < NI; ++ni) {
                int col = n0 + wc * WN + ni * 16 + ll;
                #pragma unroll
                for (int r = 0; r < 4; ++r) {
                    int mrow = m0 + wr * WM + mi * 16 + 4 * lg + r;
                    if (mrow < M) Out[(size_t)mrow * N + col] = acc[mi][ni][r];
                }
            }
    } else if (EPI == 2) {
        unsigned short* Out = (unsigned short*)OutV;
        #pragma unroll
        for (int mi = 0; mi < MI; ++mi)
            #pragma unroll
            for (int ni = 0; ni < NI; ++ni) {
                int col = n0 + wc * WN + ni * 16 + ll;
                float bv = bias[col];
                #pragma unroll
                for (int r = 0; r < 4; ++r) {
                    int mrow = m0 + wr * WM + mi * 16 + 4 * lg + r;
                    Out[(size_t)mrow * N + col] = f2bf(gelu_tanh(acc[mi][ni][r] + bv));
                }
            }
    } else {
        float* Out = (float*)OutV;
        int bidx = m0 >> 10;
        int hw0 = m0 & 1023;
        const float* resb = res + (size_t)bidx * N * HWN;
        float* outb_ = Out + (size_t)bidx * N * HWN;
        #pragma unroll
        for (int ni = 0; ni < NI; ++ni) {
            int ch = n0 + wc * WN + ni * 16 + ll;
            float g = gate[bidx * (6 * CH) + ch];
            float bv = bias[ch];
            #pragma unroll
            for (int mi = 0; mi < MI; ++mi) {
                int t = hw0 + wr * WM + mi * 16 + 4 * lg;
                float4 r4 = *(const float4*)&resb[(size_t)ch * HWN + t];
                f32x4 a = acc[mi][ni];
                float4 o;
                o.x = r4.x + g * (a[0] + bv);
                o.y = r4.y + g * (a[1] + bv);
                o.z = r4.z + g * (a[2] + bv);
                o.w = r4.w + g * (a[3] + bv);
                *(float4*)&outb_[(size_t)ch * HWN + t] = o;
            }
        }
    }
}

// -------- V transpose: qkv f32 v-slice -> vT[bh][d][t] bf16 (t padded to 1152) --------
__global__ __launch_bounds__(256) void k_transpose_v(const float* __restrict__ qkvs,
        const float* __restrict__ qkvc, unsigned short* __restrict__ vT) {
    __shared__ unsigned short T[64][72];
    int bh = blockIdx.y, tk = blockIdx.x;
    int b = bh >> 3, h = bh & 7;
    int tid = threadIdx.x;
    {
        int tq = tid >> 2, dg = tid & 3;
        int t = tk * 64 + tq;
        const float* src = nullptr;
        if (t < HWN) src = qkvs + ((size_t)(b * HWN + t)) * 1536 + 1024 + h * 64 + dg * 16;
        else if (t < TTOT) src = qkvc + ((size_t)(b * SEQ + t - HWN)) * 1536 + 1024 + h * 64 + dg * 16;
        #pragma unroll
        for (int i = 0; i < 4; ++i) {
            float4 v = src ? *(const float4*)&src[i * 4] : make_float4(0.f, 0.f, 0.f, 0.f);
            ushort4 o = {f2bf(v.x), f2bf(v.y), f2bf(v.z), f2bf(v.w)};
            *(ushort4*)&T[tq][dg * 16 + i * 4] = o;
        }
    }
    __syncthreads();
    {
        int d = tid >> 2, tg = tid & 3;
        bhalf8 o0, o1;
        #pragma unroll
        for (int i = 0; i < 8; ++i) {
            o0[i] = (short)T[tg * 16 + i][d];
            o1[i] = (short)T[tg * 16 + 8 + i][d];
        }
        size_t base = ((size_t)(bh * 64 + d)) * VSTRIDE + tk * 64 + tg * 16;
        *(bhalf8*)&vT[base] = o0;
        *(bhalf8*)&vT[base + 8] = o1;
    }
}

// -------- heads + RoPE + qk-RMSNorm -> bf16 q (x0.125*log2e) and k --------
__global__ void k_qkv_build(const float* __restrict__ qkvs, const float* __restrict__ qkvc,
                            const float* __restrict__ freqs, const float* __restrict__ qn,
                            const float* __restrict__ kn,
                            unsigned short* __restrict__ qb, unsigned short* __restrict__ kb) {
    int wid = threadIdx.x >> 6, lane = threadIdx.x & 63;
    int gid = blockIdx.x * 4 + wid;
    int bh = gid / TTOT, tok = gid - bh * TTOT;
    int b = bh >> 3;
    int j = lane >> 1;
    float qv = 0.f, kv, ang;
    if (tok < HWN) {
        size_t base = ((size_t)(b * HWN + tok)) * 1536 + (bh & 7) * 64 + lane;
        qv = qkvs[base];
        kv = qkvs[base + 512];
        ang = (float)(tok >> 5) * freqs[2 * j] + (float)(tok & 31) * freqs[2 * j + 1];
    } else {
        int s = tok - HWN;
        size_t base = ((size_t)(b * SEQ + s)) * 1536 + (bh & 7) * 64 + lane;
        kv = qkvc[base + 512];
        float inv = expf(-(float)j * (9.210340371976184f / 32.0f));
        ang = (float)s * inv;
    }
    float co = cosf(ang), si = sinf(ang);
    float kp = __shfl_xor(kv, 1);
    float kr = (lane & 1) ? fmaf(kv, co, kp * si) : fmaf(kv, co, -kp * si);
    float qp = __shfl_xor(qv, 1);
    float qr = (lane & 1) ? fmaf(qv, co, qp * si) : fmaf(qv, co, -qp * si);
    float ssk = kr * kr, ssq = qr * qr;
    #pragma unroll
    for (int o = 1; o < 64; o <<= 1) {
        ssk += __shfl_xor(ssk, o);
        ssq += __shfl_xor(ssq, o);
    }
    float kout = kr * rsqrtf(ssk * (1.0f / 64.f) + 1.1920929e-07f) * kn[lane];
    kb[((size_t)bh * TTOT + tok) * 64 + lane] = f2bf(kout);
    if (tok < HWN) {
        // 0.125 attn scale * log2(e): softmax runs in exp2 domain
        float qout = qr * rsqrtf(ssq * (1.0f / 64.f) + 1.1920929e-07f) * qn[lane] * 0.18033688011112042f;
        qb[((size_t)bh * HWN + tok) * 64 + lane] = f2bf(qout);
    }
}

// -------- swapped-QK flash attention v4: Qtile=64 (16 q/wave), KVtile=64 --------
// LDS 24KB: [0,8K) K tile, [8K,16K) V^T tile, [16K,24K) per-wave P (2KB each).
__global__ __launch_bounds__(256) void k_attn_v4(const unsigned short* __restrict__ qb,
        const unsigned short* __restrict__ kbuf, const unsigned short* __restrict__ vT,
        unsigned short* __restrict__ ob) {
    __shared__ __align__(1024) unsigned short SM[12288];
    char* smc = (char*)SM;
    int bh = blockIdx.y;
    int q0 = blockIdx.x * 64;
    int tid = threadIdx.x;
    int w = tid >> 6, l = tid & 63, lg = l >> 4, ll = l & 15;
    int r8 = l >> 3, c16 = (l & 7) * 16;
    // Q fragments (B operand): lane holds Q[q=ll][d=ks*32+lg*8 ..+7] for wave's 16 rows
    bhalf8 qf[2];
    {
        const unsigned short* qbase = qb + ((size_t)bh * HWN + q0 + w * 16) * 64;
        #pragma unroll
        for (int ks = 0; ks < 2; ++ks)
            qf[ks] = *(const bhalf8*)&qbase[ll * 64 + ks * 32 + lg * 8];
    }
    f32x4 accO[4] = {};  // O^T[d=d4*16+4lg+r][q=ll]
    float Mx = -1e30f, Lx = 0.f;
    const char* kgl = (const char*)kbuf + (size_t)bh * TTOT * 128;
    const char* vgl = (const char*)vT + (size_t)bh * 64 * (VSTRIDE * 2);
    char* pw = smc + 16384 + w * 2048 + ll * 128;
    int pswz = (ll & 7) << 4;
    for (int kt = 0; kt < 18; ++kt) {
        __syncthreads();  // previous tile fully consumed
        #pragma unroll
        for (int i = 0; i < 4; ++i) {
            int c = w * 4 + i;
            if (c < 8) {  // K chunk: rows = keys
                int row = c * 8 + r8;
                int t = kt * 64 + row;
                if (t > TTOT - 1) t = TTOT - 1;  // clamped rows are softmax-masked
                gload16(kgl + (size_t)t * 128 + (c16 ^ ((row & 7) << 4)), smc + c * 1024);
            } else {      // V^T chunk: rows = d
                int row = (c - 8) * 8 + r8;
                gload16(vgl + (size_t)row * (VSTRIDE * 2) + kt * 128 + (c16 ^ ((row & 7) << 4)),
                        smc + 8192 + (c - 8) * 1024);
            }
        }
        __syncthreads();
        // S^T = K x Q : A=K rows=key, B=Q cols=q
        f32x4 s[4] = {};
        #pragma unroll
        for (int ks = 0; ks < 2; ++ks) {
            bhalf8 kf[4];
            #pragma unroll
            for (int k4 = 0; k4 < 4; ++k4)
                kf[k4] = *(const bhalf8*)(smc + swz((k4 * 16 + ll) * 128 + ks * 64 + lg * 16));
            #pragma unroll
            for (int k4 = 0; k4 < 4; ++k4)
                s[k4] = __builtin_amdgcn_mfma_f32_16x16x32_bf16(kf[k4], qf[ks], s[k4], 0, 0, 0);
        }
        if (kt == 17) {  // mask tail keys (key index lane-local: k4*16 + 4lg + r)
            int kb0 = kt * 64 + 4 * lg;
            #pragma unroll
            for (int k4 = 0; k4 < 4; ++k4)
                #pragma unroll
                for (int r = 0; r < 4; ++r)
                    if (kb0 + k4 * 16 + r >= TTOT) s[k4][r] = -1e30f;
        }
        // online softmax: q is lane-local (ll); reduce 16 local + 2 shfl across lg groups
        float ml = s[0][0];
        #pragma unroll
        for (int k4 = 0; k4 < 4; ++k4)
            #pragma unroll
            for (int r = 0; r < 4; ++r) ml = fmaxf(ml, s[k4][r]);
        ml = fmaxf(ml, __shfl_xor(ml, 16));
        ml = fmaxf(ml, __shfl_xor(ml, 32));
        if (__any(ml > Mx)) {  // exact defer: alpha==1 for all lanes when skipped
            float mnew = fmaxf(Mx, ml);
            float alpha = exp2f(Mx - mnew);
            Mx = mnew;
            Lx *= alpha;
            #pragma unroll
            for (int d4 = 0; d4 < 4; ++d4)
                #pragma unroll
                for (int r = 0; r < 4; ++r) accO[d4][r] *= alpha;
        }
        float sum = 0.f;
        #pragma unroll
        for (int k4 = 0; k4 < 4; ++k4) {
            float p0 = exp2f(s[k4][0] - Mx), p1 = exp2f(s[k4][1] - Mx);
            float p2 = exp2f(s[k4][2] - Mx), p3 = exp2f(s[k4][3] - Mx);
            sum += (p0 + p1) + (p2 + p3);
            uint2 pk = {cvtpk(p0, p1), cvtpk(p2, p3)};
            *(uint2*)(pw + ((k4 * 32 + lg * 8) ^ pswz)) = pk;
        }
        sum += __shfl_xor(sum, 16);
        sum += __shfl_xor(sum, 32);
        Lx += sum;
        // O^T += V^T x P (P wave-private: no barrier between write and read)
        #pragma unroll
        for (int ks = 0; ks < 2; ++ks) {
            bhalf8 vf[4];
            #pragma unroll
            for (int d4 = 0; d4 < 4; ++d4)
                vf[d4] = *(const bhalf8*)(smc + 8192 + swz((d4 * 16 + ll) * 128 + ks * 64 + lg * 16));
            bhalf8 pf = *(const bhalf8*)(smc + 16384 + w * 2048 + swz(ll * 128 + ks * 64 + lg * 16));
            #pragma unroll
            for (int d4 = 0; d4 < 4; ++d4)
                accO[d4] = __builtin_amdgcn_mfma_f32_16x16x32_bf16(vf[d4], pf, accO[d4], 0, 0, 0);
        }
    }
    // epilogue: /L (lane-local), transpose O^T -> [q][d] via LDS, coalesced stores
    __syncthreads();
    {
        float inv = 1.0f / Lx;
        int orow = w * 16 + ll;
        char* po = smc + orow * 128;
        int oswz = (orow & 7) << 4;
        #pragma unroll
        for (int d4 = 0; d4 < 4; ++d4) {
            uint2 pk = {cvtpk(accO[d4][0] * inv, accO[d4][1] * inv),
                        cvtpk(accO[d4][2] * inv, accO[d4][3] * inv)};
            *(uint2*)(po + ((d4 * 32 + lg * 8) ^ oswz)) = pk;
        }
    }
    __syncthreads();
    int b = bh >> 3, h = bh & 7;
    int row = tid >> 2, seg = tid & 3;
    bhalf8 v0 = *(const bhalf8*)(smc + swz(row * 128 + seg * 32));
    bhalf8 v1 = *(const bhalf8*)(smc + swz(row * 128 + seg * 32 + 16));
    unsigned short* dst = ob + ((size_t)(b * HWN + q0 + row)) * CH + h * 64 + seg * 16;
    *(bhalf8*)&dst[0] = v0;
    *(bhalf8*)&dst[8] = v1;
}

extern "C" void kernel_launch(void* const* d_in, const int* in_sizes, int n_in,
                              void* d_out, int out_size, void* d_ws, size_t ws_size,
                              hipStream_t stream) {
    const float* x     = (const float*)d_in[0];
    const float* cond  = (const float*)d_in[1];
    const float* femb  = (const float*)d_in[2];
    const float* mod_w = (const float*)d_in[3];
    const float* mod_b = (const float*)d_in[4];
    const float* n1s   = (const float*)d_in[5];
    const float* n2s   = (const float*)d_in[6];
    const float* qkvsw = (const float*)d_in[7];
    const float* qkvcw = (const float*)d_in[8];
    const float* ropef = (const float*)d_in[9];
    const float* qn    = (const float*)d_in[10];
    const float* kn    = (const float*)d_in[11];
    const float* outw  = (const float*)d_in[12];
    const float* outb  = (const float*)d_in[13];
    const float* w1    = (const float*)d_in[14];
    const float* b1    = (const float*)d_in[15];
    const float* w2    = (const float*)d_in[16];
    const float* b2    = (const float*)d_in[17];
    float* out = (float*)d_out;
    char* W = (char*)d_ws;

    // byte layout (~90.7 MB peak, overlays respect liveness)
    unsigned short* wqs_b = (unsigned short*)(W + 0);         // 1536x512
    unsigned short* wqc_b = (unsigned short*)(W + 1572864);   // 1536x768
    unsigned short* wo_b  = (unsigned short*)(W + 3932160);   // 512x512
    unsigned short* w1_b  = (unsigned short*)(W + 4456448);   // 2048x512
    unsigned short* w2_b  = (unsigned short*)(W + 6553600);   // 512x2048
    unsigned short* condb = (unsigned short*)(W + 8650752);   // 616x768
    float* mod            = (float*)(W + 9596928);            // 8x3072
    unsigned short* hmod  = (unsigned short*)(W + 9695232);   // 8192x512 bf16 (later: q)
    unsigned short* qbuf  = hmod;
    float* qkvs           = (float*)(W + 18083840);           // 8192x1536 f32
    unsigned short* obuf  = (unsigned short*)(W + 18083840);            // overlays qkvs head
    unsigned short* mbuf  = (unsigned short*)(W + 18083840 + 8388608);  // 8192x2048 bf16
    unsigned short* h2    = (unsigned short*)(W + 60026880);  // 8192x512 bf16
    float* qkvc           = (float*)(W + 68415488);           // 616x1536 f32
    unsigned short* kbuf  = (unsigned short*)(W + 72200192);  // 64x1101x64 bf16
    float* x1             = (float*)(W + 72200192);           // overlays kbuf+vT after attn
    unsigned short* vTb   = (unsigned short*)(W + 81218560);  // 64x64x1152 bf16

    CvtArgs ca;
    ca.src[0] = qkvsw; ca.dst[0] = wqs_b; ca.n[0] = 1536 * 512;
    ca.src[1] = qkvcw; ca.dst[1] = wqc_b; ca.n[1] = 1536 * 768;
    ca.src[2] = outw;  ca.dst[2] = wo_b;  ca.n[2] = 512 * 512;
    ca.src[3] = w1;    ca.dst[3] = w1_b;  ca.n[3] = 2048 * 512;
    ca.src[4] = w2;    ca.dst[4] = w2_b;  ca.n[4] = 512 * 2048;
    ca.src[5] = cond;  ca.dst[5] = condb; ca.n[5] = 616 * 768;
    k_cvt_all<<<dim3(1152, 6), 256, 0, stream>>>(ca);

    k_modulation<<<dim3(12, BATCH), 256, 0, stream>>>(femb, mod_w, mod_b, mod);
    k_rms2d_mod_t<<<dim3(16, BATCH), 256, 0, stream>>>(x, n1s, mod, 0, 512, hmod);
    // qkv_s: [8192,512] @ [1536,512]^T -> f32 [8192,1536]
    k_gemm_mfma<0, 128, 128><<<dim3(12, 64), 256, 0, stream>>>(
        hmod, wqs_b, qkvs, 8192, 1536, 512, nullptr, nullptr, nullptr);
    // qkv_c: [616,768] @ [1536,768]^T -> f32 [616,1536]
    k_gemm_mfma<0, 128, 128><<<dim3(12, 5), 256, 0, stream>>>(
        condb, wqc_b, qkvc, 616, 1536, 768, nullptr, nullptr, nullptr);
    k_transpose_v<<<dim3(18, 64), 256, 0, stream>>>(qkvs, qkvc, vTb);
    k_qkv_build<<<dim3((BATCH * NHEAD * TTOT) / 4), 256, 0, stream>>>(
        qkvs, qkvc, ropef, qn, kn, qbuf, kbuf);
    k_attn_v4<<<dim3(16, 64), 256, 0, stream>>>(qbuf, kbuf, vTb, obuf);
    // out-proj: x1 = x + g1*(obuf @ Wo^T + outb)  (channel-major f32), 64x64 tiles
    k_gemm_mfma<1, 64, 64><<<dim3(8, 128), 256, 0, stream>>>(
        obuf, wo_b, x1, 8192, 512, 512, outb, mod + 2 * 512, x);
    k_rms2d_mod_t<<<dim3(16, BATCH), 256, 0, stream>>>(x1, n2s, mod, 3 * 512, 4 * 512, h2);
    // MLP1 + gelu -> bf16 [8192,2048]
    k_gemm_mfma<2, 128, 128><<<dim3(16, 64), 256, 0, stream>>>(
        h2, w1_b, mbuf, 8192, 2048, 512, b1, nullptr, nullptr);
    // MLP2 + gate + residual -> d_out (channel-major f32), 64x64 tiles
    k_gemm_mfma<1, 64, 64><<<dim3(8, 128), 256, 0, stream>>>(
        mbuf, w2_b, out, 8192, 512, 2048, b2, mod + 5 * 512, x1);
}

// Round 5
// 308.507 us; speedup vs baseline: 4.7761x; 1.0209x over previous
//
#include <hip/hip_runtime.h>

// FluxUNet fused block — round 5: fused qkv epilogue (RoPE+RMS+V^T) + KVBLK=128 attn.
// B=8, C=512, HW=1024, S=77, E=768, NH=8, HD=64, HID=2048, T=1101.
constexpr int BATCH = 8, CH = 512, HWN = 1024, SEQ = 77, EMB = 768;
constexpr int NHEAD = 8, HDIM = 64, HIDDEN = 2048, TTOT = 1101;
constexpr int VSTRIDE = 1152;  // padded t-stride for transposed V

typedef short bhalf8 __attribute__((ext_vector_type(8)));
typedef float f32x4 __attribute__((ext_vector_type(4)));

__device__ __forceinline__ unsigned short f2bf(float f) {
    unsigned u = __builtin_bit_cast(unsigned, f);
    unsigned r = (u + 0x7fffu + ((u >> 16) & 1u)) >> 16;
    return (unsigned short)r;
}
__device__ __forceinline__ unsigned cvtpk(float a, float b) {
    unsigned r;
    asm("v_cvt_pk_bf16_f32 %0, %1, %2" : "=v"(r) : "v"(a), "v"(b));
    return r;
}
__device__ __forceinline__ float gelu_tanh(float v) {
    float c = v * v * v;
    float t = tanhf(0.7978845608028654f * (v + 0.044715f * c));
    return 0.5f * v * (1.0f + t);
}
// XOR-swizzle on a 128B-row-stride LDS tile (region base must be 1024B-aligned).
__device__ __forceinline__ int swz(int b) { return b ^ ((b >> 3) & 0x70); }

// async global->LDS 16B: LDS dest = wave-uniform base + lane*16.
__device__ __forceinline__ void gload16(const void* g, void* l) {
    __builtin_amdgcn_global_load_lds(
        (const __attribute__((address_space(1))) unsigned int*)g,
        (__attribute__((address_space(3))) unsigned int*)l, 16, 0, 0);
}

// ---------------- merged f32 -> bf16 casts ----------------
struct CvtArgs {
    const float* src[6];
    unsigned short* dst[6];
    int n[6];
};
__global__ void k_cvt_all(CvtArgs a) {
    int t = blockIdx.y;
    int i = (blockIdx.x * 256 + threadIdx.x) * 4;
    if (i >= a.n[t]) return;
    float4 v = *(const float4*)&a.src[t][i];
    ushort4 o = {f2bf(v.x), f2bf(v.y), f2bf(v.z), f2bf(v.w)};
    *(ushort4*)&a.dst[t][i] = o;
}

// ---------------- RoPE cos/sin table: ct[t][j] = (cos, sin), t<1024 2D, else 1D ----------------
__global__ void k_rope_table(const float* __restrict__ freqs, float* __restrict__ ct) {
    int i = blockIdx.x * 256 + threadIdx.x;
    if (i >= TTOT * 32) return;
    int t = i >> 5, j = i & 31;
    float ang;
    if (t < HWN) {
        ang = (float)(t >> 5) * freqs[2 * j] + (float)(t & 31) * freqs[2 * j + 1];
    } else {
        float inv = expf(-(float)j * (9.210340371976184f / 32.0f));
        ang = (float)(t - HWN) * inv;
    }
    ct[i * 2] = cosf(ang);
    ct[i * 2 + 1] = sinf(ang);
}

// ---------------- mod = silu(final_emb) @ mod_w + mod_b ----------------
__global__ void k_modulation(const float* __restrict__ emb, const float* __restrict__ w,
                             const float* __restrict__ bias, float* __restrict__ mod) {
    __shared__ float se[EMB];
    int b = blockIdx.y;
    int tid = threadIdx.x;
    for (int i = tid; i < EMB; i += 256) {
        float v = emb[b * EMB + i];
        se[i] = v / (1.0f + expf(-v));
    }
    __syncthreads();
    int j = blockIdx.x * 256 + tid;
    float acc = 0.0f;
    #pragma unroll 8
    for (int e = 0; e < EMB; ++e) acc = fmaf(se[e], w[e * (6 * CH) + j], acc);
    mod[b * (6 * CH) + j] = acc + bias[j];
}

// ------- RMSNorm(channel) + adaLN modulate + transpose -> bf16 token-major -------
__global__ __launch_bounds__(256) void k_rms2d_mod_t(const float* __restrict__ xin,
        const float* __restrict__ sw, const float* __restrict__ mod, int shoff, int scoff,
        unsigned short* __restrict__ outp) {
    __shared__ float part[4][64];
    __shared__ float rinv[64];
    int b = blockIdx.y;
    int n0 = blockIdx.x * 64;
    int tid = threadIdx.x;
    const float* xb = xin + (size_t)b * CH * HWN;
    {
        int n = n0 + (tid & 63);
        int cg = tid >> 6;
        float ss = 0.f;
        #pragma unroll 8
        for (int c = cg * 128; c < cg * 128 + 128; ++c) {
            float v = xb[(size_t)c * HWN + n];
            ss = fmaf(v, v, ss);
        }
        part[cg][tid & 63] = ss;
    }
    __syncthreads();
    if (tid < 64) {
        float s = part[0][tid] + part[1][tid] + part[2][tid] + part[3][tid];
        rinv[tid] = rsqrtf(s * (1.0f / CH) + 1e-6f);
    }
    __syncthreads();
    int n = n0 + (tid >> 2);
    int cq = tid & 3;
    float r = rinv[tid >> 2];
    const float* mb = mod + b * (6 * CH);
    unsigned short* orow = outp + ((size_t)(b * HWN + n)) * CH;
    for (int jc = 0; jc < 16; ++jc) {
        int c = cq * 128 + jc * 8;
        bhalf8 o;
        #pragma unroll
        for (int u = 0; u < 8; ++u) {
            int cc = c + u;
            float v = xb[(size_t)cc * HWN + n];
            float y = v * r * sw[cc] * (1.0f + mb[scoff + cc]) + mb[shoff + cc];
            o[u] = (short)f2bf(y);
        }
        *(bhalf8*)&orow[c] = o;
    }
}

// ---------------- generic bf16 MFMA GEMM (unchanged epilogues 1,2) ----------------
template <int EPI, int BM, int BN>
__global__ __launch_bounds__(256) void k_gemm_mfma(
        const unsigned short* __restrict__ A, const unsigned short* __restrict__ Bt,
        void* __restrict__ OutV, int M, int N, int K,
        const float* __restrict__ bias, const float* __restrict__ gate,
        const float* __restrict__ res) {
    constexpr int WM = BM / 2, WN = BN / 2;
    constexpr int MI = WM / 16, NI = WN / 16;
    constexpr int CA = BM / 8, CB = BN / 8, CW = (CA + CB) / 4;
    __shared__ __align__(1024) unsigned short As[BM * 64];
    __shared__ __align__(1024) unsigned short Bs[BN * 64];
    int tid = threadIdx.x;
    int w = tid >> 6, l = tid & 63, lg = l >> 4, ll = l & 15;
    int wr = w >> 1, wc = w & 1;
    int m0 = blockIdx.y * BM, n0 = blockIdx.x * BN;
    int r8 = l >> 3, c16 = (l & 7) * 16;
    f32x4 acc[MI][NI] = {};
    const char* Ac = (const char*)A;
    const char* Bc = (const char*)Bt;
    size_t rowBytes = (size_t)K * 2;
    for (int k0 = 0; k0 < K; k0 += 64) {
        __syncthreads();
        #pragma unroll
        for (int i = 0; i < CW; ++i) {
            int c = w * CW + i;
            if (c < CA) {
                int row = c * 8 + r8;
                int off = c16 ^ ((row & 7) << 4);
                int ar = m0 + row;
                if (ar > M - 1) ar = M - 1;
                gload16(Ac + (size_t)ar * rowBytes + k0 * 2 + off, (char*)As + c * 1024);
            } else {
                int cc = c - CA;
                int row = cc * 8 + r8;
                int off = c16 ^ ((row & 7) << 4);
                gload16(Bc + (size_t)(n0 + row) * rowBytes + k0 * 2 + off, (char*)Bs + cc * 1024);
            }
        }
        __syncthreads();
        #pragma unroll
        for (int ks = 0; ks < 2; ++ks) {
            bhalf8 af[MI], bf[NI];
            #pragma unroll
            for (int mi = 0; mi < MI; ++mi)
                af[mi] = *(const bhalf8*)((char*)As + swz((wr * WM + mi * 16 + ll) * 128 + ks * 64 + lg * 16));
            #pragma unroll
            for (int ni = 0; ni < NI; ++ni)
                bf[ni] = *(const bhalf8*)((char*)Bs + swz((wc * WN + ni * 16 + ll) * 128 + ks * 64 + lg * 16));
            #pragma unroll
            for (int mi = 0; mi < MI; ++mi)
                #pragma unroll
                for (int ni = 0; ni < NI; ++ni)
                    acc[mi][ni] = __builtin_amdgcn_mfma_f32_16x16x32_bf16(af[mi], bf[ni], acc[mi][ni], 0, 0, 0);
        }
    }
    if (EPI == 2) {
        unsigned short* Out = (unsigned short*)OutV;
        #pragma unroll
        for (int mi = 0; mi < MI; ++mi)
            #pragma unroll
            for (int ni = 0; ni < NI; ++ni) {
                int col = n0 + wc * WN + ni * 16 + ll;
                float bv = bias[col];
                #pragma unroll
                for (int r = 0; r < 4; ++r) {
                    int mrow = m0 + wr * WM + mi * 16 + 4 * lg + r;
                    Out[(size_t)mrow * N + col] = f2bf(gelu_tanh(acc[mi][ni][r] + bv));
                }
            }
    } else {
        float* Out = (float*)OutV;
        int bidx = m0 >> 10;
        int hw0 = m0 & 1023;
        const float* resb = res + (size_t)bidx * N * HWN;
        float* outb_ = Out + (size_t)bidx * N * HWN;
        #pragma unroll
        for (int ni = 0; ni < NI; ++ni) {
            int ch = n0 + wc * WN + ni * 16 + ll;
            float g = gate[bidx * (6 * CH) + ch];
            float bv = bias[ch];
            #pragma unroll
            for (int mi = 0; mi < MI; ++mi) {
                int t = hw0 + wr * WM + mi * 16 + 4 * lg;
                float4 r4 = *(const float4*)&resb[(size_t)ch * HWN + t];
                f32x4 a = acc[mi][ni];
                float4 o;
                o.x = r4.x + g * (a[0] + bv);
                o.y = r4.y + g * (a[1] + bv);
                o.z = r4.z + g * (a[2] + bv);
                o.w = r4.w + g * (a[3] + bv);
                *(float4*)&outb_[(size_t)ch * HWN + t] = o;
            }
        }
    }
}

// ------- qkv GEMM with fused RoPE + qk-RMSNorm + head-split + V-transpose -------
// A [M][K] bf16 (tokens), Bt [1536][K] bf16. 128x128 tiles, n0 = nOff + bx*128.
// Tile type by n0: <512 q, <1024 k, else v.
// COND=0: rows = b*1024 + hw (M=8192).  COND=1: rows = b*77 + s (M=616), t = 1024+s.
// Outputs: qb[bh][1024][64] (q * 0.125*log2e), kb[bh][1101][64], vT[bh][64][1152].
template <int COND>
__global__ __launch_bounds__(256) void k_gemm_qkv(
        const unsigned short* __restrict__ A, const unsigned short* __restrict__ Bt,
        int M, int K, int nOff, const float* __restrict__ ct,
        const float* __restrict__ qn, const float* __restrict__ kn,
        unsigned short* __restrict__ qb, unsigned short* __restrict__ kb,
        unsigned short* __restrict__ vT) {
    __shared__ __align__(1024) char SMEM[34816];  // loop: As/Bs 16K+16K; epi: stage[128][136]
    unsigned short* As = (unsigned short*)SMEM;
    unsigned short* Bs = (unsigned short*)(SMEM + 16384);
    int tid = threadIdx.x;
    int w = tid >> 6, l = tid & 63, lg = l >> 4, ll = l & 15;
    int wr = w >> 1, wc = w & 1;
    int m0 = blockIdx.y * 128, n0 = nOff + blockIdx.x * 128;
    int r8 = l >> 3, c16 = (l & 7) * 16;
    f32x4 acc[4][4] = {};
    const char* Ac = (const char*)A;
    const char* Bc = (const char*)Bt;
    size_t rowBytes = (size_t)K * 2;
    for (int k0 = 0; k0 < K; k0 += 64) {
        __syncthreads();
        #pragma unroll
        for (int i = 0; i < 8; ++i) {
            int c = w * 8 + i;
            if (c < 16) {
                int row = c * 8 + r8;
                int off = c16 ^ ((row & 7) << 4);
                int ar = m0 + row;
                if (ar > M - 1) ar = M - 1;
                gload16(Ac + (size_t)ar * rowBytes + k0 * 2 + off, (char*)As + c * 1024);
            } else {
                int cc = c - 16;
                int row = cc * 8 + r8;
                int off = c16 ^ ((row & 7) << 4);
                gload16(Bc + (size_t)(n0 + row) * rowBytes + k0 * 2 + off, (char*)Bs + cc * 1024);
            }
        }
        __syncthreads();
        #pragma unroll
        for (int ks = 0; ks < 2; ++ks) {
            bhalf8 af[4], bf[4];
            #pragma unroll
            for (int mi = 0; mi < 4; ++mi)
                af[mi] = *(const bhalf8*)((char*)As + swz((wr * 64 + mi * 16 + ll) * 128 + ks * 64 + lg * 16));
            #pragma unroll
            for (int ni = 0; ni < 4; ++ni)
                bf[ni] = *(const bhalf8*)((char*)Bs + swz((wc * 64 + ni * 16 + ll) * 128 + ks * 64 + lg * 16));
            #pragma unroll
            for (int mi = 0; mi < 4; ++mi)
                #pragma unroll
                for (int ni = 0; ni < 4; ++ni)
                    acc[mi][ni] = __builtin_amdgcn_mfma_f32_16x16x32_bf16(af[mi], bf[ni], acc[mi][ni], 0, 0, 0);
        }
    }
    int type = n0 >> 9;  // 0 q, 1 k, >=2 v
    const float2* ct2 = (const float2*)ct;

    if (type >= 2) {  // ---- V: direct transposed bf16 writes ----
        int hd = (n0 - 1024 + wc * 64) >> 6;
        #pragma unroll
        for (int ni = 0; ni < 4; ++ni) {
            int d = ni * 16 + ll;
            #pragma unroll
            for (int mi = 0; mi < 4; ++mi) {
                int rowL = m0 + wr * 64 + mi * 16 + 4 * lg;
                if (COND == 0) {
                    int b = rowL >> 10, t = rowL & 1023;
                    uint2 pk = {cvtpk(acc[mi][ni][0], acc[mi][ni][1]),
                                cvtpk(acc[mi][ni][2], acc[mi][ni][3])};
                    *(uint2*)&vT[((size_t)(b * 8 + hd) * 64 + d) * VSTRIDE + t] = pk;
                } else {
                    #pragma unroll
                    for (int r = 0; r < 4; ++r) {
                        int row = rowL + r;
                        if (row < M) {
                            int b = row / 77, s = row - b * 77;
                            vT[((size_t)(b * 8 + hd) * 64 + d) * VSTRIDE + 1024 + s] =
                                f2bf(acc[mi][ni][r]);
                        }
                    }
                }
            }
        }
        return;
    }
    // ---- Q/K: RoPE + RMSNorm + scale, then LDS-transpose for coalesced stores ----
    const float* wnt = (type == 0) ? qn : kn;
    float wn[4];
    int jj[4];
    #pragma unroll
    for (int ni = 0; ni < 4; ++ni) {
        wn[ni] = wnt[ni * 16 + ll];
        jj[ni] = (ni * 16 + ll) >> 1;
    }
    float sgn = (ll & 1) ? 1.f : -1.f;
    #pragma unroll
    for (int mi = 0; mi < 4; ++mi) {
        int rowL = m0 + wr * 64 + mi * 16 + 4 * lg;
        int tt[4];
        #pragma unroll
        for (int r = 0; r < 4; ++r) {
            if (COND == 0) tt[r] = (rowL + r) & 1023;
            else {
                int row = rowL + r;
                if (row > M - 1) row = M - 1;
                int b = row / 77;
                tt[r] = 1024 + (row - b * 77);
            }
        }
        // RoPE (partner lane = ll^1 holds d^1)
        #pragma unroll
        for (int ni = 0; ni < 4; ++ni) {
            f32x4 a = acc[mi][ni], p;
            #pragma unroll
            for (int r = 0; r < 4; ++r) p[r] = __shfl_xor(a[r], 1);
            #pragma unroll
            for (int r = 0; r < 4; ++r) {
                float2 cs = ct2[tt[r] * 32 + jj[ni]];
                a[r] = fmaf(sgn * p[r], cs.y, a[r] * cs.x);
            }
            acc[mi][ni] = a;
        }
        // RMSNorm over head dim (4 local + 4 shfl over ll)
        f32x4 ss = {};
        #pragma unroll
        for (int ni = 0; ni < 4; ++ni)
            #pragma unroll
            for (int r = 0; r < 4; ++r) ss[r] = fmaf(acc[mi][ni][r], acc[mi][ni][r], ss[r]);
        #pragma unroll
        for (int msk = 1; msk < 16; msk <<= 1)
            #pragma unroll
            for (int r = 0; r < 4; ++r) ss[r] += __shfl_xor(ss[r], msk);
        f32x4 ri;
        #pragma unroll
        for (int r = 0; r < 4; ++r) {
            ri[r] = rsqrtf(ss[r] * (1.0f / 64.f) + 1.1920929e-07f);
            if (type == 0) ri[r] *= 0.18033688011112042f;  // 0.125 * log2(e)
        }
        #pragma unroll
        for (int ni = 0; ni < 4; ++ni)
            #pragma unroll
            for (int r = 0; r < 4; ++r) acc[mi][ni][r] *= ri[r] * wn[ni];
    }
    __syncthreads();  // other waves done reading As/Bs
    unsigned short* stg = (unsigned short*)SMEM;  // [128][136]
    #pragma unroll
    for (int mi = 0; mi < 4; ++mi)
        #pragma unroll
        for (int ni = 0; ni < 4; ++ni) {
            int colL = wc * 64 + ni * 16 + ll;
            int rowL = wr * 64 + mi * 16 + 4 * lg;
            #pragma unroll
            for (int r = 0; r < 4; ++r)
                stg[(rowL + r) * 136 + colL] = f2bf(acc[mi][ni][r]);
        }
    __syncthreads();
    int rowO = tid >> 1, half = tid & 1;
    int rowG = m0 + rowO;
    if (COND == 1 && rowG >= M) return;
    int ch0 = n0 + half * 64;
    int b, t;
    if (COND == 0) { b = rowG >> 10; t = rowG & 1023; }
    else { b = rowG / 77; t = 1024 + (rowG - b * 77); }
    unsigned short* dst;
    if (type == 0) dst = qb + ((size_t)(b * 8 + (ch0 >> 6)) * HWN + t) * 64;
    else dst = kb + ((size_t)(b * 8 + ((ch0 - 512) >> 6)) * TTOT + t) * 64;
    #pragma unroll
    for (int i = 0; i < 8; ++i)
        *(bhalf8*)&dst[i * 8] = *(const bhalf8*)&stg[rowO * 136 + half * 64 + i * 8];
}

// -------- swapped-QK flash attention v5: Qtile=64 (16 q/wave), KVBLK=128 --------
// LDS 48KB: [0,16K) K [key128][128B]; [16K,32K) V^T two halves [d64][128B];
//           [32K,48K) per-wave P 4KB = two halves [q16][128B].
__global__ __launch_bounds__(256) void k_attn_v5(const unsigned short* __restrict__ qb,
        const unsigned short* __restrict__ kbuf, const unsigned short* __restrict__ vT,
        unsigned short* __restrict__ ob) {
    __shared__ __align__(1024) char smc[49152];
    int bh = blockIdx.y;
    int q0 = blockIdx.x * 64;
    int tid = threadIdx.x;
    int w = tid >> 6, l = tid & 63, lg = l >> 4, ll = l & 15;
    int r8 = l >> 3, c16 = (l & 7) * 16;
    bhalf8 qf[2];
    {
        const unsigned short* qbase = qb + ((size_t)bh * HWN + q0 + w * 16) * 64;
        #pragma unroll
        for (int ks = 0; ks < 2; ++ks)
            qf[ks] = *(const bhalf8*)&qbase[ll * 64 + ks * 32 + lg * 8];
    }
    f32x4 accO[4] = {};
    float Mx = -1e30f, Lx = 0.f;
    const char* kgl = (const char*)kbuf + (size_t)bh * TTOT * 128;
    const char* vgl = (const char*)vT + (size_t)bh * 64 * (VSTRIDE * 2);
    char* pbase = smc + 32768 + w * 4096;
    for (int kt = 0; kt < 9; ++kt) {
        __syncthreads();
        #pragma unroll
        for (int i = 0; i < 8; ++i) {
            int c = w * 8 + i;
            if (c < 16) {  // K: rows = keys 0..127
                int row = c * 8 + r8;
                int t = kt * 128 + row;
                if (t > TTOT - 1) t = TTOT - 1;
                gload16(kgl + (size_t)t * 128 + (c16 ^ ((row & 7) << 4)), smc + c * 1024);
            } else {       // V^T: two 64-key halves, rows = d 0..63
                int c2 = c - 16;
                int half = c2 >> 3;
                int drow = (c2 & 7) * 8 + r8;
                gload16(vgl + (size_t)drow * (VSTRIDE * 2) + (size_t)(kt * 128 + half * 64) * 2
                            + (c16 ^ ((drow & 7) << 4)),
                        smc + 16384 + half * 8192 + (c2 & 7) * 1024);
            }
        }
        __syncthreads();
        // S^T = K x Q
        f32x4 s[8] = {};
        __builtin_amdgcn_s_setprio(1);
        #pragma unroll
        for (int ks = 0; ks < 2; ++ks)
            #pragma unroll
            for (int k4 = 0; k4 < 8; ++k4) {
                bhalf8 kf = *(const bhalf8*)(smc + swz((k4 * 16 + ll) * 128 + ks * 64 + lg * 16));
                s[k4] = __builtin_amdgcn_mfma_f32_16x16x32_bf16(kf, qf[ks], s[k4], 0, 0, 0);
            }
        __builtin_amdgcn_s_setprio(0);
        if (kt == 8) {  // mask tail keys (key = k4*16 + 4lg + r; valid < 77 past 1024)
            int kb0 = 4 * lg;
            #pragma unroll
            for (int k4 = 0; k4 < 8; ++k4)
                #pragma unroll
                for (int r = 0; r < 4; ++r)
                    if (1024 + k4 * 16 + kb0 + r >= TTOT) s[k4][r] = -1e30f;
        }
        // online softmax (q lane-local; reduce over lg groups: shfl 16,32)
        float ml = s[0][0];
        #pragma unroll
        for (int k4 = 0; k4 < 8; ++k4)
            #pragma unroll
            for (int r = 0; r < 4; ++r) ml = fmaxf(ml, s[k4][r]);
        ml = fmaxf(ml, __shfl_xor(ml, 16));
        ml = fmaxf(ml, __shfl_xor(ml, 32));
        if (__any(ml > Mx)) {
            float mnew = fmaxf(Mx, ml);
            float alpha = exp2f(Mx - mnew);
            Mx = mnew;
            Lx *= alpha;
            #pragma unroll
            for (int d4 = 0; d4 < 4; ++d4)
                #pragma unroll
                for (int r = 0; r < 4; ++r) accO[d4][r] *= alpha;
        }
        float sum = 0.f;
        #pragma unroll
        for (int k4 = 0; k4 < 8; ++k4) {
            float p0 = exp2f(s[k4][0] - Mx), p1 = exp2f(s[k4][1] - Mx);
            float p2 = exp2f(s[k4][2] - Mx), p3 = exp2f(s[k4][3] - Mx);
            sum += (p0 + p1) + (p2 + p3);
            uint2 pk = {cvtpk(p0, p1), cvtpk(p2, p3)};
            *(uint2*)(pbase + (k4 >> 2) * 2048 + swz(ll * 128 + (k4 & 3) * 32 + lg * 8)) = pk;
        }
        sum += __shfl_xor(sum, 16);
        sum += __shfl_xor(sum, 32);
        Lx += sum;
        // O^T += V^T x P (P wave-private)
        __builtin_amdgcn_s_setprio(1);
        #pragma unroll
        for (int ks = 0; ks < 4; ++ks) {
            int vh = ks >> 1, ko = (ks & 1) * 64 + lg * 16;
            bhalf8 pf = *(const bhalf8*)(pbase + vh * 2048 + swz(ll * 128 + ko));
            #pragma unroll
            for (int d4 = 0; d4 < 4; ++d4) {
                bhalf8 vf = *(const bhalf8*)(smc + 16384 + vh * 8192 + swz((d4 * 16 + ll) * 128 + ko));
                accO[d4] = __builtin_amdgcn_mfma_f32_16x16x32_bf16(vf, pf, accO[d4], 0, 0, 0);
            }
        }
        __builtin_amdgcn_s_setprio(0);
    }
    // epilogue: /L, transpose O^T -> [q][d] via LDS, coalesced stores
    __syncthreads();
    {
        float inv = 1.0f / Lx;
        int orow = w * 16 + ll;
        char* po = smc + orow * 128;
        int oswz = (orow & 7) << 4;
        #pragma unroll
        for (int d4 = 0; d4 < 4; ++d4) {
            uint2 pk = {cvtpk(accO[d4][0] * inv, accO[d4][1] * inv),
                        cvtpk(accO[d4][2] * inv, accO[d4][3] * inv)};
            *(uint2*)(po + ((d4 * 32 + lg * 8) ^ oswz)) = pk;
        }
    }
    __syncthreads();
    int b = bh >> 3, h = bh & 7;
    int row = tid >> 2, seg = tid & 3;
    bhalf8 v0 = *(const bhalf8*)(smc + swz(row * 128 + seg * 32));
    bhalf8 v1 = *(const bhalf8*)(smc + swz(row * 128 + seg * 32 + 16));
    unsigned short* dst = ob + ((size_t)(b * HWN + q0 + row)) * CH + h * 64 + seg * 16;
    *(bhalf8*)&dst[0] = v0;
    *(bhalf8*)&dst[8] = v1;
}

extern "C" void kernel_launch(void* const* d_in, const int* in_sizes, int n_in,
                              void* d_out, int out_size, void* d_ws, size_t ws_size,
                              hipStream_t stream) {
    const float* x     = (const float*)d_in[0];
    const float* cond  = (const float*)d_in[1];
    const float* femb  = (const float*)d_in[2];
    const float* mod_w = (const float*)d_in[3];
    const float* mod_b = (const float*)d_in[4];
    const float* n1s   = (const float*)d_in[5];
    const float* n2s   = (const float*)d_in[6];
    const float* qkvsw = (const float*)d_in[7];
    const float* qkvcw = (const float*)d_in[8];
    const float* ropef = (const float*)d_in[9];
    const float* qn    = (const float*)d_in[10];
    const float* kn    = (const float*)d_in[11];
    const float* outw  = (const float*)d_in[12];
    const float* outb  = (const float*)d_in[13];
    const float* w1    = (const float*)d_in[14];
    const float* b1    = (const float*)d_in[15];
    const float* w2    = (const float*)d_in[16];
    const float* b2    = (const float*)d_in[17];
    float* out = (float*)d_out;
    char* W = (char*)d_ws;

    // byte layout (~95.5 MB peak)
    unsigned short* wqs_b = (unsigned short*)(W + 0);         // 1536x512
    unsigned short* wqc_b = (unsigned short*)(W + 1572864);   // 1536x768
    unsigned short* wo_b  = (unsigned short*)(W + 3932160);   // 512x512
    unsigned short* w1_b  = (unsigned short*)(W + 4456448);   // 2048x512
    unsigned short* w2_b  = (unsigned short*)(W + 6553600);   // 512x2048
    unsigned short* condb = (unsigned short*)(W + 8650752);   // 616x768
    float* mod            = (float*)(W + 9596928);            // 8x3072
    float* ct             = (float*)(W + 9695232);            // 1101x32 float2
    unsigned short* hmod  = (unsigned short*)(W + 9977088);   // 8192x512 bf16
    unsigned short* obuf  = hmod;                             // overlays hmod (dead post-qkv)
    unsigned short* qbuf  = (unsigned short*)(W + 18365696);  // 64x1024x64 bf16
    unsigned short* kbuf  = (unsigned short*)(W + 26754304);  // 64x1101x64 bf16
    unsigned short* vTb   = (unsigned short*)(W + 35772672);  // 64x64x1152 bf16
    unsigned short* h2    = vTb;                              // overlays vT (dead post-attn)
    unsigned short* mbuf  = (unsigned short*)(W + 45209856);  // 8192x2048 bf16
    float* x1             = (float*)(W + 78764288);           // 8x512x1024 f32

    CvtArgs ca;
    ca.src[0] = qkvsw; ca.dst[0] = wqs_b; ca.n[0] = 1536 * 512;
    ca.src[1] = qkvcw; ca.dst[1] = wqc_b; ca.n[1] = 1536 * 768;
    ca.src[2] = outw;  ca.dst[2] = wo_b;  ca.n[2] = 512 * 512;
    ca.src[3] = w1;    ca.dst[3] = w1_b;  ca.n[3] = 2048 * 512;
    ca.src[4] = w2;    ca.dst[4] = w2_b;  ca.n[4] = 512 * 2048;
    ca.src[5] = cond;  ca.dst[5] = condb; ca.n[5] = 616 * 768;
    k_cvt_all<<<dim3(1152, 6), 256, 0, stream>>>(ca);
    k_rope_table<<<dim3(138), 256, 0, stream>>>(ropef, ct);

    k_modulation<<<dim3(12, BATCH), 256, 0, stream>>>(femb, mod_w, mod_b, mod);
    k_rms2d_mod_t<<<dim3(16, BATCH), 256, 0, stream>>>(x, n1s, mod, 0, 512, hmod);
    // qkv (spatial): fused RoPE/RMS/V^T epilogue
    k_gemm_qkv<0><<<dim3(12, 64), 256, 0, stream>>>(hmod, wqs_b, 8192, 512, 0,
                                                    ct, qn, kn, qbuf, kbuf, vTb);
    // qkv (cond): k/v tiles only (nOff=512)
    k_gemm_qkv<1><<<dim3(8, 5), 256, 0, stream>>>(condb, wqc_b, 616, 768, 512,
                                                  ct, qn, kn, qbuf, kbuf, vTb);
    k_attn_v5<<<dim3(16, 64), 256, 0, stream>>>(qbuf, kbuf, vTb, obuf);
    // out-proj: x1 = x + g1*(obuf @ Wo^T + outb)  (channel-major f32)
    k_gemm_mfma<1, 64, 64><<<dim3(8, 128), 256, 0, stream>>>(
        obuf, wo_b, x1, 8192, 512, 512, outb, mod + 2 * 512, x);
    k_rms2d_mod_t<<<dim3(16, BATCH), 256, 0, stream>>>(x1, n2s, mod, 3 * 512, 4 * 512, h2);
    // MLP1 + gelu -> bf16 [8192,2048]
    k_gemm_mfma<2, 128, 128><<<dim3(16, 64), 256, 0, stream>>>(
        h2, w1_b, mbuf, 8192, 2048, 512, b1, nullptr, nullptr);
    // MLP2 + gate + residual -> d_out (channel-major f32)
    k_gemm_mfma<1, 64, 64><<<dim3(8, 128), 256, 0, stream>>>(
        mbuf, w2_b, out, 8192, 512, 2048, b2, mod + 5 * 512, x1);
}

// Round 6
// 302.861 us; speedup vs baseline: 4.8651x; 1.0186x over previous
//
#include <hip/hip_runtime.h>

// FluxUNet fused block — round 6: attn revert to KVBLK=64 (+setprio, XCD swizzle),
// 128x64 tiles for out-proj/MLP2, merged prep kernel.
// B=8, C=512, HW=1024, S=77, E=768, NH=8, HD=64, HID=2048, T=1101.
constexpr int BATCH = 8, CH = 512, HWN = 1024, SEQ = 77, EMB = 768;
constexpr int NHEAD = 8, HDIM = 64, HIDDEN = 2048, TTOT = 1101;
constexpr int VSTRIDE = 1152;  // padded t-stride for transposed V

typedef short bhalf8 __attribute__((ext_vector_type(8)));
typedef float f32x4 __attribute__((ext_vector_type(4)));

__device__ __forceinline__ unsigned short f2bf(float f) {
    unsigned u = __builtin_bit_cast(unsigned, f);
    unsigned r = (u + 0x7fffu + ((u >> 16) & 1u)) >> 16;
    return (unsigned short)r;
}
__device__ __forceinline__ unsigned cvtpk(float a, float b) {
    unsigned r;
    asm("v_cvt_pk_bf16_f32 %0, %1, %2" : "=v"(r) : "v"(a), "v"(b));
    return r;
}
__device__ __forceinline__ float gelu_tanh(float v) {
    float c = v * v * v;
    float t = tanhf(0.7978845608028654f * (v + 0.044715f * c));
    return 0.5f * v * (1.0f + t);
}
// XOR-swizzle on a 128B-row-stride LDS tile (region base must be 1024B-aligned).
__device__ __forceinline__ int swz(int b) { return b ^ ((b >> 3) & 0x70); }

// async global->LDS 16B: LDS dest = wave-uniform base + lane*16.
__device__ __forceinline__ void gload16(const void* g, void* l) {
    __builtin_amdgcn_global_load_lds(
        (const __attribute__((address_space(1))) unsigned int*)g,
        (__attribute__((address_space(3))) unsigned int*)l, 16, 0, 0);
}

// ---------- merged prep: f32->bf16 casts (y<6), RoPE table (y==6), modulation (y==7) ----------
struct PrepArgs {
    const float* src[6];
    unsigned short* dst[6];
    int n[6];
    const float* freqs;
    float* ct;
    const float* emb;
    const float* mw;
    const float* mb;
    float* mod;
};
__global__ void k_prep(PrepArgs a) {
    int y = blockIdx.y;
    int bx = blockIdx.x;
    int tid = threadIdx.x;
    if (y < 6) {
        int i = (bx * 256 + tid) * 4;
        if (i >= a.n[y]) return;
        float4 v = *(const float4*)&a.src[y][i];
        ushort4 o = {f2bf(v.x), f2bf(v.y), f2bf(v.z), f2bf(v.w)};
        *(ushort4*)&a.dst[y][i] = o;
    } else if (y == 6) {
        int i = bx * 256 + tid;
        if (i >= TTOT * 32) return;
        int t = i >> 5, j = i & 31;
        float ang;
        if (t < HWN) {
            ang = (float)(t >> 5) * a.freqs[2 * j] + (float)(t & 31) * a.freqs[2 * j + 1];
        } else {
            float inv = expf(-(float)j * (9.210340371976184f / 32.0f));
            ang = (float)(t - HWN) * inv;
        }
        a.ct[i * 2] = cosf(ang);
        a.ct[i * 2 + 1] = sinf(ang);
    } else {
        if (bx >= 96) return;
        __shared__ float se[EMB];
        int b = bx / 12, jb = bx - b * 12;
        for (int i = tid; i < EMB; i += 256) {
            float v = a.emb[b * EMB + i];
            se[i] = v / (1.0f + expf(-v));
        }
        __syncthreads();
        int j = jb * 256 + tid;
        float acc = 0.0f;
        #pragma unroll 8
        for (int e = 0; e < EMB; ++e) acc = fmaf(se[e], a.mw[e * (6 * CH) + j], acc);
        a.mod[b * (6 * CH) + j] = acc + a.mb[j];
    }
}

// ------- RMSNorm(channel) + adaLN modulate + transpose -> bf16 token-major -------
__global__ __launch_bounds__(256) void k_rms2d_mod_t(const float* __restrict__ xin,
        const float* __restrict__ sw, const float* __restrict__ mod, int shoff, int scoff,
        unsigned short* __restrict__ outp) {
    __shared__ float part[4][64];
    __shared__ float rinv[64];
    int b = blockIdx.y;
    int n0 = blockIdx.x * 64;
    int tid = threadIdx.x;
    const float* xb = xin + (size_t)b * CH * HWN;
    {
        int n = n0 + (tid & 63);
        int cg = tid >> 6;
        float ss = 0.f;
        #pragma unroll 8
        for (int c = cg * 128; c < cg * 128 + 128; ++c) {
            float v = xb[(size_t)c * HWN + n];
            ss = fmaf(v, v, ss);
        }
        part[cg][tid & 63] = ss;
    }
    __syncthreads();
    if (tid < 64) {
        float s = part[0][tid] + part[1][tid] + part[2][tid] + part[3][tid];
        rinv[tid] = rsqrtf(s * (1.0f / CH) + 1e-6f);
    }
    __syncthreads();
    int n = n0 + (tid >> 2);
    int cq = tid & 3;
    float r = rinv[tid >> 2];
    const float* mb = mod + b * (6 * CH);
    unsigned short* orow = outp + ((size_t)(b * HWN + n)) * CH;
    for (int jc = 0; jc < 16; ++jc) {
        int c = cq * 128 + jc * 8;
        bhalf8 o;
        #pragma unroll
        for (int u = 0; u < 8; ++u) {
            int cc = c + u;
            float v = xb[(size_t)cc * HWN + n];
            float y = v * r * sw[cc] * (1.0f + mb[scoff + cc]) + mb[shoff + cc];
            o[u] = (short)f2bf(y);
        }
        *(bhalf8*)&orow[c] = o;
    }
}

// ---------------- generic bf16 MFMA GEMM ----------------
// A [M][K], Bt [N][K] bf16 row-major. K%64==0, N%BN==0, M row-clamped.
// EPI=1: f32 channel-major residual+gate.  EPI=2: bf16 gelu token-major.
template <int EPI, int BM, int BN>
__global__ __launch_bounds__(256) void k_gemm_mfma(
        const unsigned short* __restrict__ A, const unsigned short* __restrict__ Bt,
        void* __restrict__ OutV, int M, int N, int K,
        const float* __restrict__ bias, const float* __restrict__ gate,
        const float* __restrict__ res) {
    constexpr int WM = BM / 2, WN = BN / 2;
    constexpr int MI = WM / 16, NI = WN / 16;
    constexpr int CA = BM / 8, CB = BN / 8, CW = (CA + CB) / 4;
    __shared__ __align__(1024) unsigned short As[BM * 64];
    __shared__ __align__(1024) unsigned short Bs[BN * 64];
    int tid = threadIdx.x;
    int w = tid >> 6, l = tid & 63, lg = l >> 4, ll = l & 15;
    int wr = w >> 1, wc = w & 1;
    int m0 = blockIdx.y * BM, n0 = blockIdx.x * BN;
    int r8 = l >> 3, c16 = (l & 7) * 16;
    f32x4 acc[MI][NI] = {};
    const char* Ac = (const char*)A;
    const char* Bc = (const char*)Bt;
    size_t rowBytes = (size_t)K * 2;
    for (int k0 = 0; k0 < K; k0 += 64) {
        __syncthreads();
        #pragma unroll
        for (int i = 0; i < CW; ++i) {
            int c = w * CW + i;
            if (c < CA) {
                int row = c * 8 + r8;
                int off = c16 ^ ((row & 7) << 4);
                int ar = m0 + row;
                if (ar > M - 1) ar = M - 1;
                gload16(Ac + (size_t)ar * rowBytes + k0 * 2 + off, (char*)As + c * 1024);
            } else {
                int cc = c - CA;
                int row = cc * 8 + r8;
                int off = c16 ^ ((row & 7) << 4);
                gload16(Bc + (size_t)(n0 + row) * rowBytes + k0 * 2 + off, (char*)Bs + cc * 1024);
            }
        }
        __syncthreads();
        #pragma unroll
        for (int ks = 0; ks < 2; ++ks) {
            bhalf8 af[MI], bf[NI];
            #pragma unroll
            for (int mi = 0; mi < MI; ++mi)
                af[mi] = *(const bhalf8*)((char*)As + swz((wr * WM + mi * 16 + ll) * 128 + ks * 64 + lg * 16));
            #pragma unroll
            for (int ni = 0; ni < NI; ++ni)
                bf[ni] = *(const bhalf8*)((char*)Bs + swz((wc * WN + ni * 16 + ll) * 128 + ks * 64 + lg * 16));
            __builtin_amdgcn_s_setprio(1);
            #pragma unroll
            for (int mi = 0; mi < MI; ++mi)
                #pragma unroll
                for (int ni = 0; ni < NI; ++ni)
                    acc[mi][ni] = __builtin_amdgcn_mfma_f32_16x16x32_bf16(af[mi], bf[ni], acc[mi][ni], 0, 0, 0);
            __builtin_amdgcn_s_setprio(0);
        }
    }
    if (EPI == 2) {
        unsigned short* Out = (unsigned short*)OutV;
        #pragma unroll
        for (int mi = 0; mi < MI; ++mi)
            #pragma unroll
            for (int ni = 0; ni < NI; ++ni) {
                int col = n0 + wc * WN + ni * 16 + ll;
                float bv = bias[col];
                #pragma unroll
                for (int r = 0; r < 4; ++r) {
                    int mrow = m0 + wr * WM + mi * 16 + 4 * lg + r;
                    Out[(size_t)mrow * N + col] = f2bf(gelu_tanh(acc[mi][ni][r] + bv));
                }
            }
    } else {
        float* Out = (float*)OutV;
        int bidx = m0 >> 10;
        int hw0 = m0 & 1023;
        const float* resb = res + (size_t)bidx * N * HWN;
        float* outb_ = Out + (size_t)bidx * N * HWN;
        #pragma unroll
        for (int ni = 0; ni < NI; ++ni) {
            int ch = n0 + wc * WN + ni * 16 + ll;
            float g = gate[bidx * (6 * CH) + ch];
            float bv = bias[ch];
            #pragma unroll
            for (int mi = 0; mi < MI; ++mi) {
                int t = hw0 + wr * WM + mi * 16 + 4 * lg;
                float4 r4 = *(const float4*)&resb[(size_t)ch * HWN + t];
                f32x4 a = acc[mi][ni];
                float4 o;
                o.x = r4.x + g * (a[0] + bv);
                o.y = r4.y + g * (a[1] + bv);
                o.z = r4.z + g * (a[2] + bv);
                o.w = r4.w + g * (a[3] + bv);
                *(float4*)&outb_[(size_t)ch * HWN + t] = o;
            }
        }
    }
}

// ------- qkv GEMM with fused RoPE + qk-RMSNorm + head-split + V-transpose -------
// A [M][K] bf16 (tokens), Bt [1536][K] bf16. 128x128 tiles, n0 = nOff + bx*128.
// Tile type by n0: <512 q, <1024 k, else v.
// COND=0: rows = b*1024 + hw (M=8192).  COND=1: rows = b*77 + s (M=616), t = 1024+s.
// Outputs: qb[bh][1024][64] (q * 0.125*log2e), kb[bh][1101][64], vT[bh][64][1152].
template <int COND>
__global__ __launch_bounds__(256) void k_gemm_qkv(
        const unsigned short* __restrict__ A, const unsigned short* __restrict__ Bt,
        int M, int K, int nOff, const float* __restrict__ ct,
        const float* __restrict__ qn, const float* __restrict__ kn,
        unsigned short* __restrict__ qb, unsigned short* __restrict__ kb,
        unsigned short* __restrict__ vT) {
    __shared__ __align__(1024) char SMEM[34816];  // loop: As/Bs 16K+16K; epi: stage[128][136]
    unsigned short* As = (unsigned short*)SMEM;
    unsigned short* Bs = (unsigned short*)(SMEM + 16384);
    int tid = threadIdx.x;
    int w = tid >> 6, l = tid & 63, lg = l >> 4, ll = l & 15;
    int wr = w >> 1, wc = w & 1;
    int m0 = blockIdx.y * 128, n0 = nOff + blockIdx.x * 128;
    int r8 = l >> 3, c16 = (l & 7) * 16;
    f32x4 acc[4][4] = {};
    const char* Ac = (const char*)A;
    const char* Bc = (const char*)Bt;
    size_t rowBytes = (size_t)K * 2;
    for (int k0 = 0; k0 < K; k0 += 64) {
        __syncthreads();
        #pragma unroll
        for (int i = 0; i < 8; ++i) {
            int c = w * 8 + i;
            if (c < 16) {
                int row = c * 8 + r8;
                int off = c16 ^ ((row & 7) << 4);
                int ar = m0 + row;
                if (ar > M - 1) ar = M - 1;
                gload16(Ac + (size_t)ar * rowBytes + k0 * 2 + off, (char*)As + c * 1024);
            } else {
                int cc = c - 16;
                int row = cc * 8 + r8;
                int off = c16 ^ ((row & 7) << 4);
                gload16(Bc + (size_t)(n0 + row) * rowBytes + k0 * 2 + off, (char*)Bs + cc * 1024);
            }
        }
        __syncthreads();
        #pragma unroll
        for (int ks = 0; ks < 2; ++ks) {
            bhalf8 af[4], bf[4];
            #pragma unroll
            for (int mi = 0; mi < 4; ++mi)
                af[mi] = *(const bhalf8*)((char*)As + swz((wr * 64 + mi * 16 + ll) * 128 + ks * 64 + lg * 16));
            #pragma unroll
            for (int ni = 0; ni < 4; ++ni)
                bf[ni] = *(const bhalf8*)((char*)Bs + swz((wc * 64 + ni * 16 + ll) * 128 + ks * 64 + lg * 16));
            __builtin_amdgcn_s_setprio(1);
            #pragma unroll
            for (int mi = 0; mi < 4; ++mi)
                #pragma unroll
                for (int ni = 0; ni < 4; ++ni)
                    acc[mi][ni] = __builtin_amdgcn_mfma_f32_16x16x32_bf16(af[mi], bf[ni], acc[mi][ni], 0, 0, 0);
            __builtin_amdgcn_s_setprio(0);
        }
    }
    int type = n0 >> 9;  // 0 q, 1 k, >=2 v
    const float2* ct2 = (const float2*)ct;

    if (type >= 2) {  // ---- V: direct transposed bf16 writes ----
        int hd = (n0 - 1024 + wc * 64) >> 6;
        #pragma unroll
        for (int ni = 0; ni < 4; ++ni) {
            int d = ni * 16 + ll;
            #pragma unroll
            for (int mi = 0; mi < 4; ++mi) {
                int rowL = m0 + wr * 64 + mi * 16 + 4 * lg;
                if (COND == 0) {
                    int b = rowL >> 10, t = rowL & 1023;
                    uint2 pk = {cvtpk(acc[mi][ni][0], acc[mi][ni][1]),
                                cvtpk(acc[mi][ni][2], acc[mi][ni][3])};
                    *(uint2*)&vT[((size_t)(b * 8 + hd) * 64 + d) * VSTRIDE + t] = pk;
                } else {
                    #pragma unroll
                    for (int r = 0; r < 4; ++r) {
                        int row = rowL + r;
                        if (row < M) {
                            int b = row / 77, s = row - b * 77;
                            vT[((size_t)(b * 8 + hd) * 64 + d) * VSTRIDE + 1024 + s] =
                                f2bf(acc[mi][ni][r]);
                        }
                    }
                }
            }
        }
        return;
    }
    // ---- Q/K: RoPE + RMSNorm + scale, then LDS-transpose for coalesced stores ----
    const float* wnt = (type == 0) ? qn : kn;
    float wn[4];
    int jj[4];
    #pragma unroll
    for (int ni = 0; ni < 4; ++ni) {
        wn[ni] = wnt[ni * 16 + ll];
        jj[ni] = (ni * 16 + ll) >> 1;
    }
    float sgn = (ll & 1) ? 1.f : -1.f;
    #pragma unroll
    for (int mi = 0; mi < 4; ++mi) {
        int rowL = m0 + wr * 64 + mi * 16 + 4 * lg;
        int tt[4];
        #pragma unroll
        for (int r = 0; r < 4; ++r) {
            if (COND == 0) tt[r] = (rowL + r) & 1023;
            else {
                int row = rowL + r;
                if (row > M - 1) row = M - 1;
                int b = row / 77;
                tt[r] = 1024 + (row - b * 77);
            }
        }
        // RoPE (partner lane = ll^1 holds d^1)
        #pragma unroll
        for (int ni = 0; ni < 4; ++ni) {
            f32x4 a = acc[mi][ni], p;
            #pragma unroll
            for (int r = 0; r < 4; ++r) p[r] = __shfl_xor(a[r], 1);
            #pragma unroll
            for (int r = 0; r < 4; ++r) {
                float2 cs = ct2[tt[r] * 32 + jj[ni]];
                a[r] = fmaf(sgn * p[r], cs.y, a[r] * cs.x);
            }
            acc[mi][ni] = a;
        }
        // RMSNorm over head dim (4 local + 4 shfl over ll)
        f32x4 ss = {};
        #pragma unroll
        for (int ni = 0; ni < 4; ++ni)
            #pragma unroll
            for (int r = 0; r < 4; ++r) ss[r] = fmaf(acc[mi][ni][r], acc[mi][ni][r], ss[r]);
        #pragma unroll
        for (int msk = 1; msk < 16; msk <<= 1)
            #pragma unroll
            for (int r = 0; r < 4; ++r) ss[r] += __shfl_xor(ss[r], msk);
        f32x4 ri;
        #pragma unroll
        for (int r = 0; r < 4; ++r) {
            ri[r] = rsqrtf(ss[r] * (1.0f / 64.f) + 1.1920929e-07f);
            if (type == 0) ri[r] *= 0.18033688011112042f;  // 0.125 * log2(e)
        }
        #pragma unroll
        for (int ni = 0; ni < 4; ++ni)
            #pragma unroll
            for (int r = 0; r < 4; ++r) acc[mi][ni][r] *= ri[r] * wn[ni];
    }
    __syncthreads();  // other waves done reading As/Bs
    unsigned short* stg = (unsigned short*)SMEM;  // [128][136]
    #pragma unroll
    for (int mi = 0; mi < 4; ++mi)
        #pragma unroll
        for (int ni = 0; ni < 4; ++ni) {
            int colL = wc * 64 + ni * 16 + ll;
            int rowL = wr * 64 + mi * 16 + 4 * lg;
            #pragma unroll
            for (int r = 0; r < 4; ++r)
                stg[(rowL + r) * 136 + colL] = f2bf(acc[mi][ni][r]);
        }
    __syncthreads();
    int rowO = tid >> 1, half = tid & 1;
    int rowG = m0 + rowO;
    if (COND == 1 && rowG >= M) return;
    int ch0 = n0 + half * 64;
    int b, t;
    if (COND == 0) { b = rowG >> 10; t = rowG & 1023; }
    else { b = rowG / 77; t = 1024 + (rowG - b * 77); }
    unsigned short* dst;
    if (type == 0) dst = qb + ((size_t)(b * 8 + (ch0 >> 6)) * HWN + t) * 64;
    else dst = kb + ((size_t)(b * 8 + ((ch0 - 512) >> 6)) * TTOT + t) * 64;
    #pragma unroll
    for (int i = 0; i < 8; ++i)
        *(bhalf8*)&dst[i * 8] = *(const bhalf8*)&stg[rowO * 136 + half * 64 + i * 8];
}

// -------- swapped-QK flash attention v6: Qtile=64 (16 q/wave), KVBLK=64, XCD swizzle --------
// LDS 24KB: [0,8K) K [key64][128B]; [8K,16K) V^T [d64][128B]; [16K,24K) per-wave P (2KB).
// Flat grid 1024; decode so 16 q-blocks of one bh land on one XCD (bh%8==XCD).
__global__ __launch_bounds__(256) void k_attn_v6(const unsigned short* __restrict__ qb,
        const unsigned short* __restrict__ kbuf, const unsigned short* __restrict__ vT,
        unsigned short* __restrict__ ob) {
    __shared__ __align__(1024) char smc[24576];
    int f = blockIdx.x;
    int xcd = f & 7, n = f >> 3;
    int q0 = (n & 15) * 64;
    int bh = ((n >> 4) << 3) | xcd;
    int tid = threadIdx.x;
    int w = tid >> 6, l = tid & 63, lg = l >> 4, ll = l & 15;
    int r8 = l >> 3, c16 = (l & 7) * 16;
    bhalf8 qf[2];
    {
        const unsigned short* qbase = qb + ((size_t)bh * HWN + q0 + w * 16) * 64;
        #pragma unroll
        for (int ks = 0; ks < 2; ++ks)
            qf[ks] = *(const bhalf8*)&qbase[ll * 64 + ks * 32 + lg * 8];
    }
    f32x4 accO[4] = {};  // O^T[d=d4*16+4lg+r][q=ll]
    float Mx = -1e30f, Lx = 0.f;
    const char* kgl = (const char*)kbuf + (size_t)bh * TTOT * 128;
    const char* vgl = (const char*)vT + (size_t)bh * 64 * (VSTRIDE * 2);
    char* pw = smc + 16384 + w * 2048 + ll * 128;
    int pswz = (ll & 7) << 4;
    for (int kt = 0; kt < 18; ++kt) {
        __syncthreads();  // previous tile fully consumed
        #pragma unroll
        for (int i = 0; i < 4; ++i) {
            int c = w * 4 + i;
            if (c < 8) {  // K chunk: rows = keys
                int row = c * 8 + r8;
                int t = kt * 64 + row;
                if (t > TTOT - 1) t = TTOT - 1;  // clamped rows are softmax-masked
                gload16(kgl + (size_t)t * 128 + (c16 ^ ((row & 7) << 4)), smc + c * 1024);
            } else {      // V^T chunk: rows = d
                int row = (c - 8) * 8 + r8;
                gload16(vgl + (size_t)row * (VSTRIDE * 2) + kt * 128 + (c16 ^ ((row & 7) << 4)),
                        smc + 8192 + (c - 8) * 1024);
            }
        }
        __syncthreads();
        // S^T = K x Q : A=K rows=key, B=Q cols=q
        f32x4 s[4] = {};
        __builtin_amdgcn_s_setprio(1);
        #pragma unroll
        for (int ks = 0; ks < 2; ++ks) {
            bhalf8 kf[4];
            #pragma unroll
            for (int k4 = 0; k4 < 4; ++k4)
                kf[k4] = *(const bhalf8*)(smc + swz((k4 * 16 + ll) * 128 + ks * 64 + lg * 16));
            #pragma unroll
            for (int k4 = 0; k4 < 4; ++k4)
                s[k4] = __builtin_amdgcn_mfma_f32_16x16x32_bf16(kf[k4], qf[ks], s[k4], 0, 0, 0);
        }
        __builtin_amdgcn_s_setprio(0);
        if (kt == 17) {  // mask tail keys (key index lane-local: k4*16 + 4lg + r)
            int kb0 = kt * 64 + 4 * lg;
            #pragma unroll
            for (int k4 = 0; k4 < 4; ++k4)
                #pragma unroll
                for (int r = 0; r < 4; ++r)
                    if (kb0 + k4 * 16 + r >= TTOT) s[k4][r] = -1e30f;
        }
        // online softmax: q lane-local (ll); reduce 16 local + 2 shfl across lg groups
        float ml = s[0][0];
        #pragma unroll
        for (int k4 = 0; k4 < 4; ++k4)
            #pragma unroll
            for (int r = 0; r < 4; ++r) ml = fmaxf(ml, s[k4][r]);
        ml = fmaxf(ml, __shfl_xor(ml, 16));
        ml = fmaxf(ml, __shfl_xor(ml, 32));
        if (__any(ml > Mx)) {  // exact defer: alpha==1 for all lanes when skipped
            float mnew = fmaxf(Mx, ml);
            float alpha = exp2f(Mx - mnew);
            Mx = mnew;
            Lx *= alpha;
            #pragma unroll
            for (int d4 = 0; d4 < 4; ++d4)
                #pragma unroll
                for (int r = 0; r < 4; ++r) accO[d4][r] *= alpha;
        }
        float sum = 0.f;
        #pragma unroll
        for (int k4 = 0; k4 < 4; ++k4) {
            float p0 = exp2f(s[k4][0] - Mx), p1 = exp2f(s[k4][1] - Mx);
            float p2 = exp2f(s[k4][2] - Mx), p3 = exp2f(s[k4][3] - Mx);
            sum += (p0 + p1) + (p2 + p3);
            uint2 pk = {cvtpk(p0, p1), cvtpk(p2, p3)};
            *(uint2*)(pw + ((k4 * 32 + lg * 8) ^ pswz)) = pk;
        }
        sum += __shfl_xor(sum, 16);
        sum += __shfl_xor(sum, 32);
        Lx += sum;
        // O^T += V^T x P (P wave-private: no barrier between write and read)
        __builtin_amdgcn_s_setprio(1);
        #pragma unroll
        for (int ks = 0; ks < 2; ++ks) {
            bhalf8 vf[4];
            #pragma unroll
            for (int d4 = 0; d4 < 4; ++d4)
                vf[d4] = *(const bhalf8*)(smc + 8192 + swz((d4 * 16 + ll) * 128 + ks * 64 + lg * 16));
            bhalf8 pf = *(const bhalf8*)(smc + 16384 + w * 2048 + swz(ll * 128 + ks * 64 + lg * 16));
            #pragma unroll
            for (int d4 = 0; d4 < 4; ++d4)
                accO[d4] = __builtin_amdgcn_mfma_f32_16x16x32_bf16(vf[d4], pf, accO[d4], 0, 0, 0);
        }
        __builtin_amdgcn_s_setprio(0);
    }
    // epilogue: /L (lane-local), transpose O^T -> [q][d] via LDS, coalesced stores
    __syncthreads();
    {
        float inv = 1.0f / Lx;
        int orow = w * 16 + ll;
        char* po = smc + orow * 128;
        int oswz = (orow & 7) << 4;
        #pragma unroll
        for (int d4 = 0; d4 < 4; ++d4) {
            uint2 pk = {cvtpk(accO[d4][0] * inv, accO[d4][1] * inv),
                        cvtpk(accO[d4][2] * inv, accO[d4][3] * inv)};
            *(uint2*)(po + ((d4 * 32 + lg * 8) ^ oswz)) = pk;
        }
    }
    __syncthreads();
    int b = bh >> 3, h = bh & 7;
    int row = tid >> 2, seg = tid & 3;
    bhalf8 v0 = *(const bhalf8*)(smc + swz(row * 128 + seg * 32));
    bhalf8 v1 = *(const bhalf8*)(smc + swz(row * 128 + seg * 32 + 16));
    unsigned short* dst = ob + ((size_t)(b * HWN + q0 + row)) * CH + h * 64 + seg * 16;
    *(bhalf8*)&dst[0] = v0;
    *(bhalf8*)&dst[8] = v1;
}

extern "C" void kernel_launch(void* const* d_in, const int* in_sizes, int n_in,
                              void* d_out, int out_size, void* d_ws, size_t ws_size,
                              hipStream_t stream) {
    const float* x     = (const float*)d_in[0];
    const float* cond  = (const float*)d_in[1];
    const float* femb  = (const float*)d_in[2];
    const float* mod_w = (const float*)d_in[3];
    const float* mod_b = (const float*)d_in[4];
    const float* n1s   = (const float*)d_in[5];
    const float* n2s   = (const float*)d_in[6];
    const float* qkvsw = (const float*)d_in[7];
    const float* qkvcw = (const float*)d_in[8];
    const float* ropef = (const float*)d_in[9];
    const float* qn    = (const float*)d_in[10];
    const float* kn    = (const float*)d_in[11];
    const float* outw  = (const float*)d_in[12];
    const float* outb  = (const float*)d_in[13];
    const float* w1    = (const float*)d_in[14];
    const float* b1    = (const float*)d_in[15];
    const float* w2    = (const float*)d_in[16];
    const float* b2    = (const float*)d_in[17];
    float* out = (float*)d_out;
    char* W = (char*)d_ws;

    // byte layout (~95.5 MB peak)
    unsigned short* wqs_b = (unsigned short*)(W + 0);         // 1536x512
    unsigned short* wqc_b = (unsigned short*)(W + 1572864);   // 1536x768
    unsigned short* wo_b  = (unsigned short*)(W + 3932160);   // 512x512
    unsigned short* w1_b  = (unsigned short*)(W + 4456448);   // 2048x512
    unsigned short* w2_b  = (unsigned short*)(W + 6553600);   // 512x2048
    unsigned short* condb = (unsigned short*)(W + 8650752);   // 616x768
    float* mod            = (float*)(W + 9596928);            // 8x3072
    float* ct             = (float*)(W + 9695232);            // 1101x32 float2
    unsigned short* hmod  = (unsigned short*)(W + 9977088);   // 8192x512 bf16
    unsigned short* obuf  = hmod;                             // overlays hmod (dead post-qkv)
    unsigned short* qbuf  = (unsigned short*)(W + 18365696);  // 64x1024x64 bf16
    unsigned short* kbuf  = (unsigned short*)(W + 26754304);  // 64x1101x64 bf16
    unsigned short* vTb   = (unsigned short*)(W + 35772672);  // 64x64x1152 bf16
    unsigned short* h2    = vTb;                              // overlays vT (dead post-attn)
    unsigned short* mbuf  = (unsigned short*)(W + 45209856);  // 8192x2048 bf16
    float* x1             = (float*)(W + 78764288);           // 8x512x1024 f32

    PrepArgs pa;
    pa.src[0] = qkvsw; pa.dst[0] = wqs_b; pa.n[0] = 1536 * 512;
    pa.src[1] = qkvcw; pa.dst[1] = wqc_b; pa.n[1] = 1536 * 768;
    pa.src[2] = outw;  pa.dst[2] = wo_b;  pa.n[2] = 512 * 512;
    pa.src[3] = w1;    pa.dst[3] = w1_b;  pa.n[3] = 2048 * 512;
    pa.src[4] = w2;    pa.dst[4] = w2_b;  pa.n[4] = 512 * 2048;
    pa.src[5] = cond;  pa.dst[5] = condb; pa.n[5] = 616 * 768;
    pa.freqs = ropef; pa.ct = ct;
    pa.emb = femb; pa.mw = mod_w; pa.mb = mod_b; pa.mod = mod;
    k_prep<<<dim3(1152, 8), 256, 0, stream>>>(pa);

    k_rms2d_mod_t<<<dim3(16, BATCH), 256, 0, stream>>>(x, n1s, mod, 0, 512, hmod);
    // qkv (spatial): fused RoPE/RMS/V^T epilogue
    k_gemm_qkv<0><<<dim3(12, 64), 256, 0, stream>>>(hmod, wqs_b, 8192, 512, 0,
                                                    ct, qn, kn, qbuf, kbuf, vTb);
    // qkv (cond): k/v tiles only (nOff=512)
    k_gemm_qkv<1><<<dim3(8, 5), 256, 0, stream>>>(condb, wqc_b, 616, 768, 512,
                                                  ct, qn, kn, qbuf, kbuf, vTb);
    k_attn_v6<<<dim3(1024), 256, 0, stream>>>(qbuf, kbuf, vTb, obuf);
    // out-proj: x1 = x + g1*(obuf @ Wo^T + outb)  (channel-major f32), 128x64 tiles
    k_gemm_mfma<1, 128, 64><<<dim3(8, 64), 256, 0, stream>>>(
        obuf, wo_b, x1, 8192, 512, 512, outb, mod + 2 * 512, x);
    k_rms2d_mod_t<<<dim3(16, BATCH), 256, 0, stream>>>(x1, n2s, mod, 3 * 512, 4 * 512, h2);
    // MLP1 + gelu -> bf16 [8192,2048]
    k_gemm_mfma<2, 128, 128><<<dim3(16, 64), 256, 0, stream>>>(
        h2, w1_b, mbuf, 8192, 2048, 512, b1, nullptr, nullptr);
    // MLP2 + gate + residual -> d_out (channel-major f32), 128x64 tiles
    k_gemm_mfma<1, 128, 64><<<dim3(8, 64), 256, 0, stream>>>(
        mbuf, w2_b, out, 8192, 512, 2048, b2, mod + 5 * 512, x1);
}

// Round 7
// 270.659 us; speedup vs baseline: 5.4440x; 1.1190x over previous
//
#include <hip/hip_runtime.h>

// FluxUNet fused block — round 7: parallel modulation (atomic e-split), attn v7
// (static-max softmax + single-barrier double-buffered staging).
// B=8, C=512, HW=1024, S=77, E=768, NH=8, HD=64, HID=2048, T=1101.
constexpr int BATCH = 8, CH = 512, HWN = 1024, SEQ = 77, EMB = 768;
constexpr int NHEAD = 8, HDIM = 64, HIDDEN = 2048, TTOT = 1101;
constexpr int VSTRIDE = 1152;  // padded t-stride for transposed V

typedef short bhalf8 __attribute__((ext_vector_type(8)));
typedef float f32x4 __attribute__((ext_vector_type(4)));

__device__ __forceinline__ unsigned short f2bf(float f) {
    unsigned u = __builtin_bit_cast(unsigned, f);
    unsigned r = (u + 0x7fffu + ((u >> 16) & 1u)) >> 16;
    return (unsigned short)r;
}
__device__ __forceinline__ unsigned cvtpk(float a, float b) {
    unsigned r;
    asm("v_cvt_pk_bf16_f32 %0, %1, %2" : "=v"(r) : "v"(a), "v"(b));
    return r;
}
__device__ __forceinline__ float gelu_tanh(float v) {
    float c = v * v * v;
    float t = tanhf(0.7978845608028654f * (v + 0.044715f * c));
    return 0.5f * v * (1.0f + t);
}
// XOR-swizzle on a 128B-row-stride LDS tile (region base must be 1024B-aligned).
__device__ __forceinline__ int swz(int b) { return b ^ ((b >> 3) & 0x70); }

// async global->LDS 16B: LDS dest = wave-uniform base + lane*16.
__device__ __forceinline__ void gload16(const void* g, void* l) {
    __builtin_amdgcn_global_load_lds(
        (const __attribute__((address_space(1))) unsigned int*)g,
        (__attribute__((address_space(3))) unsigned int*)l, 16, 0, 0);
}

// ---------- merged prep: casts (y<6), rope table (y==6),
// ----------             y==7: mod bias-init / softmax bound / silu(emb) ----------
struct PrepArgs {
    const float* src[6];
    unsigned short* dst[6];
    int n[6];
    const float* freqs;
    float* ct;
    const float* emb;
    const float* mbias;
    float* mod;
    float* se;       // silu(emb) [8][768]
    const float* qn;
    const float* kn;
    float* mbound;   // scalar softmax upper bound (exp2 domain)
};
__global__ void k_prep(PrepArgs a) {
    int y = blockIdx.y;
    int bx = blockIdx.x;
    int tid = threadIdx.x;
    if (y < 6) {
        int i = (bx * 256 + tid) * 4;
        if (i >= a.n[y]) return;
        float4 v = *(const float4*)&a.src[y][i];
        ushort4 o = {f2bf(v.x), f2bf(v.y), f2bf(v.z), f2bf(v.w)};
        *(ushort4*)&a.dst[y][i] = o;
    } else if (y == 6) {
        int i = bx * 256 + tid;
        if (i >= TTOT * 32) return;
        int t = i >> 5, j = i & 31;
        float ang;
        if (t < HWN) {
            ang = (float)(t >> 5) * a.freqs[2 * j] + (float)(t & 31) * a.freqs[2 * j + 1];
        } else {
            float inv = expf(-(float)j * (9.210340371976184f / 32.0f));
            ang = (float)(t - HWN) * inv;
        }
        a.ct[i * 2] = cosf(ang);
        a.ct[i * 2 + 1] = sinf(ang);
    } else {
        if (bx < 24) {            // mod = bias (atomic partials land on top)
            int i = bx * 1024 + tid * 4;           // i = b*3072 + j, j%4==0
            int j = i - (i / (6 * CH)) * (6 * CH);
            *(float4*)&a.mod[i] = *(const float4*)&a.mbias[j];
        } else if (bx == 24) {    // softmax bound: |S*log2e| <= 64*max|qn|*max|kn|*0.125*log2e
            if (tid < 64) {
                float mq = fabsf(a.qn[tid]), mk = fabsf(a.kn[tid]);
                #pragma unroll
                for (int o = 1; o < 64; o <<= 1) {
                    mq = fmaxf(mq, __shfl_xor(mq, o));
                    mk = fmaxf(mk, __shfl_xor(mk, o));
                }
                if (tid == 0) a.mbound[0] = 64.0f * mq * mk * 0.18033688011112042f + 1.0f;
            }
        } else if (bx >= 32 && bx < 38) {  // silu(final_emb) -> se [6144 floats]
            int i = (bx - 32) * 1024 + tid * 4;
            float4 v = *(const float4*)&a.emb[i];
            float4 o;
            o.x = v.x / (1.0f + expf(-v.x));
            o.y = v.y / (1.0f + expf(-v.y));
            o.z = v.z / (1.0f + expf(-v.z));
            o.w = v.w / (1.0f + expf(-v.w));
            *(float4*)&a.se[i] = o;
        }
    }
}

// ---------- modulation partials: mod[b][j] += sum_{e in chunk} se[b][e] * w[e][j] ----------
__global__ __launch_bounds__(256) void k_mod(const float* __restrict__ se,
        const float* __restrict__ w, float* __restrict__ mod) {
    int jb = blockIdx.x, b = blockIdx.y, ec = blockIdx.z;
    int j = jb * 256 + threadIdx.x;
    const float* sb = se + b * EMB + ec * 96;
    const float* wb = w + (size_t)(ec * 96) * (6 * CH) + j;
    float acc = 0.f;
    #pragma unroll 8
    for (int e = 0; e < 96; ++e) acc = fmaf(sb[e], wb[(size_t)e * (6 * CH)], acc);
    atomicAdd(&mod[b * (6 * CH) + j], acc);
}

// ------- RMSNorm(channel) + adaLN modulate + transpose -> bf16 token-major -------
__global__ __launch_bounds__(256) void k_rms2d_mod_t(const float* __restrict__ xin,
        const float* __restrict__ sw, const float* __restrict__ mod, int shoff, int scoff,
        unsigned short* __restrict__ outp) {
    __shared__ float part[4][64];
    __shared__ float rinv[64];
    int b = blockIdx.y;
    int n0 = blockIdx.x * 64;
    int tid = threadIdx.x;
    const float* xb = xin + (size_t)b * CH * HWN;
    {
        int n = n0 + (tid & 63);
        int cg = tid >> 6;
        float ss = 0.f;
        #pragma unroll 8
        for (int c = cg * 128; c < cg * 128 + 128; ++c) {
            float v = xb[(size_t)c * HWN + n];
            ss = fmaf(v, v, ss);
        }
        part[cg][tid & 63] = ss;
    }
    __syncthreads();
    if (tid < 64) {
        float s = part[0][tid] + part[1][tid] + part[2][tid] + part[3][tid];
        rinv[tid] = rsqrtf(s * (1.0f / CH) + 1e-6f);
    }
    __syncthreads();
    int n = n0 + (tid >> 2);
    int cq = tid & 3;
    float r = rinv[tid >> 2];
    const float* mb = mod + b * (6 * CH);
    unsigned short* orow = outp + ((size_t)(b * HWN + n)) * CH;
    for (int jc = 0; jc < 16; ++jc) {
        int c = cq * 128 + jc * 8;
        bhalf8 o;
        #pragma unroll
        for (int u = 0; u < 8; ++u) {
            int cc = c + u;
            float v = xb[(size_t)cc * HWN + n];
            float y = v * r * sw[cc] * (1.0f + mb[scoff + cc]) + mb[shoff + cc];
            o[u] = (short)f2bf(y);
        }
        *(bhalf8*)&orow[c] = o;
    }
}

// ---------------- generic bf16 MFMA GEMM ----------------
template <int EPI, int BM, int BN>
__global__ __launch_bounds__(256) void k_gemm_mfma(
        const unsigned short* __restrict__ A, const unsigned short* __restrict__ Bt,
        void* __restrict__ OutV, int M, int N, int K,
        const float* __restrict__ bias, const float* __restrict__ gate,
        const float* __restrict__ res) {
    constexpr int WM = BM / 2, WN = BN / 2;
    constexpr int MI = WM / 16, NI = WN / 16;
    constexpr int CA = BM / 8, CB = BN / 8, CW = (CA + CB) / 4;
    __shared__ __align__(1024) unsigned short As[BM * 64];
    __shared__ __align__(1024) unsigned short Bs[BN * 64];
    int tid = threadIdx.x;
    int w = tid >> 6, l = tid & 63, lg = l >> 4, ll = l & 15;
    int wr = w >> 1, wc = w & 1;
    int m0 = blockIdx.y * BM, n0 = blockIdx.x * BN;
    int r8 = l >> 3, c16 = (l & 7) * 16;
    f32x4 acc[MI][NI] = {};
    const char* Ac = (const char*)A;
    const char* Bc = (const char*)Bt;
    size_t rowBytes = (size_t)K * 2;
    for (int k0 = 0; k0 < K; k0 += 64) {
        __syncthreads();
        #pragma unroll
        for (int i = 0; i < CW; ++i) {
            int c = w * CW + i;
            if (c < CA) {
                int row = c * 8 + r8;
                int off = c16 ^ ((row & 7) << 4);
                int ar = m0 + row;
                if (ar > M - 1) ar = M - 1;
                gload16(Ac + (size_t)ar * rowBytes + k0 * 2 + off, (char*)As + c * 1024);
            } else {
                int cc = c - CA;
                int row = cc * 8 + r8;
                int off = c16 ^ ((row & 7) << 4);
                gload16(Bc + (size_t)(n0 + row) * rowBytes + k0 * 2 + off, (char*)Bs + cc * 1024);
            }
        }
        __syncthreads();
        #pragma unroll
        for (int ks = 0; ks < 2; ++ks) {
            bhalf8 af[MI], bf[NI];
            #pragma unroll
            for (int mi = 0; mi < MI; ++mi)
                af[mi] = *(const bhalf8*)((char*)As + swz((wr * WM + mi * 16 + ll) * 128 + ks * 64 + lg * 16));
            #pragma unroll
            for (int ni = 0; ni < NI; ++ni)
                bf[ni] = *(const bhalf8*)((char*)Bs + swz((wc * WN + ni * 16 + ll) * 128 + ks * 64 + lg * 16));
            __builtin_amdgcn_s_setprio(1);
            #pragma unroll
            for (int mi = 0; mi < MI; ++mi)
                #pragma unroll
                for (int ni = 0; ni < NI; ++ni)
                    acc[mi][ni] = __builtin_amdgcn_mfma_f32_16x16x32_bf16(af[mi], bf[ni], acc[mi][ni], 0, 0, 0);
            __builtin_amdgcn_s_setprio(0);
        }
    }
    if (EPI == 2) {
        unsigned short* Out = (unsigned short*)OutV;
        #pragma unroll
        for (int mi = 0; mi < MI; ++mi)
            #pragma unroll
            for (int ni = 0; ni < NI; ++ni) {
                int col = n0 + wc * WN + ni * 16 + ll;
                float bv = bias[col];
                #pragma unroll
                for (int r = 0; r < 4; ++r) {
                    int mrow = m0 + wr * WM + mi * 16 + 4 * lg + r;
                    Out[(size_t)mrow * N + col] = f2bf(gelu_tanh(acc[mi][ni][r] + bv));
                }
            }
    } else {
        float* Out = (float*)OutV;
        int bidx = m0 >> 10;
        int hw0 = m0 & 1023;
        const float* resb = res + (size_t)bidx * N * HWN;
        float* outb_ = Out + (size_t)bidx * N * HWN;
        #pragma unroll
        for (int ni = 0; ni < NI; ++ni) {
            int ch = n0 + wc * WN + ni * 16 + ll;
            float g = gate[bidx * (6 * CH) + ch];
            float bv = bias[ch];
            #pragma unroll
            for (int mi = 0; mi < MI; ++mi) {
                int t = hw0 + wr * WM + mi * 16 + 4 * lg;
                float4 r4 = *(const float4*)&resb[(size_t)ch * HWN + t];
                f32x4 a = acc[mi][ni];
                float4 o;
                o.x = r4.x + g * (a[0] + bv);
                o.y = r4.y + g * (a[1] + bv);
                o.z = r4.z + g * (a[2] + bv);
                o.w = r4.w + g * (a[3] + bv);
                *(float4*)&outb_[(size_t)ch * HWN + t] = o;
            }
        }
    }
}

// ------- qkv GEMM with fused RoPE + qk-RMSNorm + head-split + V-transpose -------
template <int COND>
__global__ __launch_bounds__(256) void k_gemm_qkv(
        const unsigned short* __restrict__ A, const unsigned short* __restrict__ Bt,
        int M, int K, int nOff, const float* __restrict__ ct,
        const float* __restrict__ qn, const float* __restrict__ kn,
        unsigned short* __restrict__ qb, unsigned short* __restrict__ kb,
        unsigned short* __restrict__ vT) {
    __shared__ __align__(1024) char SMEM[34816];  // loop: As/Bs 16K+16K; epi: stage[128][136]
    unsigned short* As = (unsigned short*)SMEM;
    unsigned short* Bs = (unsigned short*)(SMEM + 16384);
    int tid = threadIdx.x;
    int w = tid >> 6, l = tid & 63, lg = l >> 4, ll = l & 15;
    int wr = w >> 1, wc = w & 1;
    int m0 = blockIdx.y * 128, n0 = nOff + blockIdx.x * 128;
    int r8 = l >> 3, c16 = (l & 7) * 16;
    f32x4 acc[4][4] = {};
    const char* Ac = (const char*)A;
    const char* Bc = (const char*)Bt;
    size_t rowBytes = (size_t)K * 2;
    for (int k0 = 0; k0 < K; k0 += 64) {
        __syncthreads();
        #pragma unroll
        for (int i = 0; i < 8; ++i) {
            int c = w * 8 + i;
            if (c < 16) {
                int row = c * 8 + r8;
                int off = c16 ^ ((row & 7) << 4);
                int ar = m0 + row;
                if (ar > M - 1) ar = M - 1;
                gload16(Ac + (size_t)ar * rowBytes + k0 * 2 + off, (char*)As + c * 1024);
            } else {
                int cc = c - 16;
                int row = cc * 8 + r8;
                int off = c16 ^ ((row & 7) << 4);
                gload16(Bc + (size_t)(n0 + row) * rowBytes + k0 * 2 + off, (char*)Bs + cc * 1024);
            }
        }
        __syncthreads();
        #pragma unroll
        for (int ks = 0; ks < 2; ++ks) {
            bhalf8 af[4], bf[4];
            #pragma unroll
            for (int mi = 0; mi < 4; ++mi)
                af[mi] = *(const bhalf8*)((char*)As + swz((wr * 64 + mi * 16 + ll) * 128 + ks * 64 + lg * 16));
            #pragma unroll
            for (int ni = 0; ni < 4; ++ni)
                bf[ni] = *(const bhalf8*)((char*)Bs + swz((wc * 64 + ni * 16 + ll) * 128 + ks * 64 + lg * 16));
            __builtin_amdgcn_s_setprio(1);
            #pragma unroll
            for (int mi = 0; mi < 4; ++mi)
                #pragma unroll
                for (int ni = 0; ni < 4; ++ni)
                    acc[mi][ni] = __builtin_amdgcn_mfma_f32_16x16x32_bf16(af[mi], bf[ni], acc[mi][ni], 0, 0, 0);
            __builtin_amdgcn_s_setprio(0);
        }
    }
    int type = n0 >> 9;  // 0 q, 1 k, >=2 v
    const float2* ct2 = (const float2*)ct;

    if (type >= 2) {  // ---- V: direct transposed bf16 writes ----
        int hd = (n0 - 1024 + wc * 64) >> 6;
        #pragma unroll
        for (int ni = 0; ni < 4; ++ni) {
            int d = ni * 16 + ll;
            #pragma unroll
            for (int mi = 0; mi < 4; ++mi) {
                int rowL = m0 + wr * 64 + mi * 16 + 4 * lg;
                if (COND == 0) {
                    int b = rowL >> 10, t = rowL & 1023;
                    uint2 pk = {cvtpk(acc[mi][ni][0], acc[mi][ni][1]),
                                cvtpk(acc[mi][ni][2], acc[mi][ni][3])};
                    *(uint2*)&vT[((size_t)(b * 8 + hd) * 64 + d) * VSTRIDE + t] = pk;
                } else {
                    #pragma unroll
                    for (int r = 0; r < 4; ++r) {
                        int row = rowL + r;
                        if (row < M) {
                            int b = row / 77, s = row - b * 77;
                            vT[((size_t)(b * 8 + hd) * 64 + d) * VSTRIDE + 1024 + s] =
                                f2bf(acc[mi][ni][r]);
                        }
                    }
                }
            }
        }
        return;
    }
    // ---- Q/K: RoPE + RMSNorm + scale, then LDS-transpose for coalesced stores ----
    const float* wnt = (type == 0) ? qn : kn;
    float wn[4];
    int jj[4];
    #pragma unroll
    for (int ni = 0; ni < 4; ++ni) {
        wn[ni] = wnt[ni * 16 + ll];
        jj[ni] = (ni * 16 + ll) >> 1;
    }
    float sgn = (ll & 1) ? 1.f : -1.f;
    #pragma unroll
    for (int mi = 0; mi < 4; ++mi) {
        int rowL = m0 + wr * 64 + mi * 16 + 4 * lg;
        int tt[4];
        #pragma unroll
        for (int r = 0; r < 4; ++r) {
            if (COND == 0) tt[r] = (rowL + r) & 1023;
            else {
                int row = rowL + r;
                if (row > M - 1) row = M - 1;
                int b = row / 77;
                tt[r] = 1024 + (row - b * 77);
            }
        }
        #pragma unroll
        for (int ni = 0; ni < 4; ++ni) {
            f32x4 a = acc[mi][ni], p;
            #pragma unroll
            for (int r = 0; r < 4; ++r) p[r] = __shfl_xor(a[r], 1);
            #pragma unroll
            for (int r = 0; r < 4; ++r) {
                float2 cs = ct2[tt[r] * 32 + jj[ni]];
                a[r] = fmaf(sgn * p[r], cs.y, a[r] * cs.x);
            }
            acc[mi][ni] = a;
        }
        f32x4 ss = {};
        #pragma unroll
        for (int ni = 0; ni < 4; ++ni)
            #pragma unroll
            for (int r = 0; r < 4; ++r) ss[r] = fmaf(acc[mi][ni][r], acc[mi][ni][r], ss[r]);
        #pragma unroll
        for (int msk = 1; msk < 16; msk <<= 1)
            #pragma unroll
            for (int r = 0; r < 4; ++r) ss[r] += __shfl_xor(ss[r], msk);
        f32x4 ri;
        #pragma unroll
        for (int r = 0; r < 4; ++r) {
            ri[r] = rsqrtf(ss[r] * (1.0f / 64.f) + 1.1920929e-07f);
            if (type == 0) ri[r] *= 0.18033688011112042f;  // 0.125 * log2(e)
        }
        #pragma unroll
        for (int ni = 0; ni < 4; ++ni)
            #pragma unroll
            for (int r = 0; r < 4; ++r) acc[mi][ni][r] *= ri[r] * wn[ni];
    }
    __syncthreads();
    unsigned short* stg = (unsigned short*)SMEM;  // [128][136]
    #pragma unroll
    for (int mi = 0; mi < 4; ++mi)
        #pragma unroll
        for (int ni = 0; ni < 4; ++ni) {
            int colL = wc * 64 + ni * 16 + ll;
            int rowL = wr * 64 + mi * 16 + 4 * lg;
            #pragma unroll
            for (int r = 0; r < 4; ++r)
                stg[(rowL + r) * 136 + colL] = f2bf(acc[mi][ni][r]);
        }
    __syncthreads();
    int rowO = tid >> 1, half = tid & 1;
    int rowG = m0 + rowO;
    if (COND == 1 && rowG >= M) return;
    int ch0 = n0 + half * 64;
    int b, t;
    if (COND == 0) { b = rowG >> 10; t = rowG & 1023; }
    else { b = rowG / 77; t = 1024 + (rowG - b * 77); }
    unsigned short* dst;
    if (type == 0) dst = qb + ((size_t)(b * 8 + (ch0 >> 6)) * HWN + t) * 64;
    else dst = kb + ((size_t)(b * 8 + ((ch0 - 512) >> 6)) * TTOT + t) * 64;
    #pragma unroll
    for (int i = 0; i < 8; ++i)
        *(bhalf8*)&dst[i * 8] = *(const bhalf8*)&stg[rowO * 136 + half * 64 + i * 8];
}

// -------- attn v7: static-max softmax, double-buffered K/V, 1 barrier/tile --------
// LDS 40KB: buf0 K[0,8K) V[8K,16K); buf1 K[16K,24K) V[24K,32K); P [32K,40K).
__global__ __launch_bounds__(256) void k_attn_v7(const unsigned short* __restrict__ qb,
        const unsigned short* __restrict__ kbuf, const unsigned short* __restrict__ vT,
        unsigned short* __restrict__ ob, const float* __restrict__ mbp) {
    __shared__ __align__(1024) char smc[40960];
    int f = blockIdx.x;
    int xcd = f & 7, n = f >> 3;
    int q0 = (n & 15) * 64;
    int bh = ((n >> 4) << 3) | xcd;
    int tid = threadIdx.x;
    int w = tid >> 6, l = tid & 63, lg = l >> 4, ll = l & 15;
    int r8 = l >> 3, c16 = (l & 7) * 16;
    float Mb = mbp[0];
    bhalf8 qf[2];
    {
        const unsigned short* qbase = qb + ((size_t)bh * HWN + q0 + w * 16) * 64;
        #pragma unroll
        for (int ks = 0; ks < 2; ++ks)
            qf[ks] = *(const bhalf8*)&qbase[ll * 64 + ks * 32 + lg * 8];
    }
    f32x4 accO[4] = {};  // O^T[d=d4*16+4lg+r][q=ll]
    float Lx = 0.f;
    const char* kgl = (const char*)kbuf + (size_t)bh * TTOT * 128;
    const char* vgl = (const char*)vT + (size_t)bh * 64 * (VSTRIDE * 2);
    char* pw = smc + 32768 + w * 2048 + ll * 128;
    int pswz = (ll & 7) << 4;

    auto stage = [&](int kt, int bsel) {
        char* base = smc + bsel * 16384;
        #pragma unroll
        for (int i = 0; i < 4; ++i) {
            int c = w * 4 + i;
            if (c < 8) {  // K chunk: rows = keys
                int row = c * 8 + r8;
                int t = kt * 64 + row;
                if (t > TTOT - 1) t = TTOT - 1;  // clamped rows are softmax-masked
                gload16(kgl + (size_t)t * 128 + (c16 ^ ((row & 7) << 4)), base + c * 1024);
            } else {      // V^T chunk: rows = d
                int row = (c - 8) * 8 + r8;
                gload16(vgl + (size_t)row * (VSTRIDE * 2) + kt * 128 + (c16 ^ ((row & 7) << 4)),
                        base + 8192 + (c - 8) * 1024);
            }
        }
    };
    stage(0, 0);
    __syncthreads();  // tile 0 landed
    for (int kt = 0; kt < 18; ++kt) {
        int cur = kt & 1;
        if (kt < 17) stage(kt + 1, cur ^ 1);  // issue next tile; latency hides under compute
        char* kl = smc + cur * 16384;
        char* vl = kl + 8192;
        // S^T = K x Q
        f32x4 s[4] = {};
        __builtin_amdgcn_s_setprio(1);
        #pragma unroll
        for (int ks = 0; ks < 2; ++ks) {
            bhalf8 kf[4];
            #pragma unroll
            for (int k4 = 0; k4 < 4; ++k4)
                kf[k4] = *(const bhalf8*)(kl + swz((k4 * 16 + ll) * 128 + ks * 64 + lg * 16));
            #pragma unroll
            for (int k4 = 0; k4 < 4; ++k4)
                s[k4] = __builtin_amdgcn_mfma_f32_16x16x32_bf16(kf[k4], qf[ks], s[k4], 0, 0, 0);
        }
        __builtin_amdgcn_s_setprio(0);
        if (kt == 17) {  // mask tail keys (key index lane-local: k4*16 + 4lg + r)
            int kb0 = kt * 64 + 4 * lg;
            #pragma unroll
            for (int k4 = 0; k4 < 4; ++k4)
                #pragma unroll
                for (int r = 0; r < 4; ++r)
                    if (kb0 + k4 * 16 + r >= TTOT) s[k4][r] = -1e30f;
        }
        // softmax with static max (shift-invariant => exact); no reduce, no rescale
        float sum = 0.f;
        #pragma unroll
        for (int k4 = 0; k4 < 4; ++k4) {
            float p0 = exp2f(s[k4][0] - Mb), p1 = exp2f(s[k4][1] - Mb);
            float p2 = exp2f(s[k4][2] - Mb), p3 = exp2f(s[k4][3] - Mb);
            sum += (p0 + p1) + (p2 + p3);
            uint2 pk = {cvtpk(p0, p1), cvtpk(p2, p3)};
            *(uint2*)(pw + ((k4 * 32 + lg * 8) ^ pswz)) = pk;
        }
        sum += __shfl_xor(sum, 16);
        sum += __shfl_xor(sum, 32);
        Lx += sum;
        // O^T += V^T x P (P wave-private)
        __builtin_amdgcn_s_setprio(1);
        #pragma unroll
        for (int ks = 0; ks < 2; ++ks) {
            bhalf8 vf[4];
            #pragma unroll
            for (int d4 = 0; d4 < 4; ++d4)
                vf[d4] = *(const bhalf8*)(vl + swz((d4 * 16 + ll) * 128 + ks * 64 + lg * 16));
            bhalf8 pf = *(const bhalf8*)(smc + 32768 + w * 2048 + swz(ll * 128 + ks * 64 + lg * 16));
            #pragma unroll
            for (int d4 = 0; d4 < 4; ++d4)
                accO[d4] = __builtin_amdgcn_mfma_f32_16x16x32_bf16(vf[d4], pf, accO[d4], 0, 0, 0);
        }
        __builtin_amdgcn_s_setprio(0);
        __syncthreads();  // next-tile loads landed; all waves done with cur buffers
    }
    // epilogue: /L, transpose O^T -> [q][d] via LDS, coalesced stores
    {
        float inv = 1.0f / Lx;
        int orow = w * 16 + ll;
        char* po = smc + orow * 128;
        int oswz = (orow & 7) << 4;
        #pragma unroll
        for (int d4 = 0; d4 < 4; ++d4) {
            uint2 pk = {cvtpk(accO[d4][0] * inv, accO[d4][1] * inv),
                        cvtpk(accO[d4][2] * inv, accO[d4][3] * inv)};
            *(uint2*)(po + ((d4 * 32 + lg * 8) ^ oswz)) = pk;
        }
    }
    __syncthreads();
    int b = bh >> 3, h = bh & 7;
    int row = tid >> 2, seg = tid & 3;
    bhalf8 v0 = *(const bhalf8*)(smc + swz(row * 128 + seg * 32));
    bhalf8 v1 = *(const bhalf8*)(smc + swz(row * 128 + seg * 32 + 16));
    unsigned short* dst = ob + ((size_t)(b * HWN + q0 + row)) * CH + h * 64 + seg * 16;
    *(bhalf8*)&dst[0] = v0;
    *(bhalf8*)&dst[8] = v1;
}

extern "C" void kernel_launch(void* const* d_in, const int* in_sizes, int n_in,
                              void* d_out, int out_size, void* d_ws, size_t ws_size,
                              hipStream_t stream) {
    const float* x     = (const float*)d_in[0];
    const float* cond  = (const float*)d_in[1];
    const float* femb  = (const float*)d_in[2];
    const float* mod_w = (const float*)d_in[3];
    const float* mod_b = (const float*)d_in[4];
    const float* n1s   = (const float*)d_in[5];
    const float* n2s   = (const float*)d_in[6];
    const float* qkvsw = (const float*)d_in[7];
    const float* qkvcw = (const float*)d_in[8];
    const float* ropef = (const float*)d_in[9];
    const float* qn    = (const float*)d_in[10];
    const float* kn    = (const float*)d_in[11];
    const float* outw  = (const float*)d_in[12];
    const float* outb  = (const float*)d_in[13];
    const float* w1    = (const float*)d_in[14];
    const float* b1    = (const float*)d_in[15];
    const float* w2    = (const float*)d_in[16];
    const float* b2    = (const float*)d_in[17];
    float* out = (float*)d_out;
    char* W = (char*)d_ws;

    // byte layout (~95.5 MB peak)
    unsigned short* wqs_b = (unsigned short*)(W + 0);         // 1536x512
    unsigned short* wqc_b = (unsigned short*)(W + 1572864);   // 1536x768
    unsigned short* wo_b  = (unsigned short*)(W + 3932160);   // 512x512
    unsigned short* w1_b  = (unsigned short*)(W + 4456448);   // 2048x512
    unsigned short* w2_b  = (unsigned short*)(W + 6553600);   // 512x2048
    unsigned short* condb = (unsigned short*)(W + 8650752);   // 616x768
    float* mod            = (float*)(W + 9596928);            // 8x3072
    float* ct             = (float*)(W + 9695232);            // 1101x32 float2
    unsigned short* hmod  = (unsigned short*)(W + 9977088);   // 8192x512 bf16
    unsigned short* obuf  = hmod;                             // overlays hmod (dead post-qkv)
    unsigned short* qbuf  = (unsigned short*)(W + 18365696);  // 64x1024x64 bf16
    unsigned short* kbuf  = (unsigned short*)(W + 26754304);  // 64x1101x64 bf16
    unsigned short* vTb   = (unsigned short*)(W + 35772672);  // 64x64x1152 bf16
    unsigned short* h2    = vTb;                              // overlays vT (dead post-attn)
    unsigned short* mbuf  = (unsigned short*)(W + 45209856);  // 8192x2048 bf16
    float* x1             = (float*)(W + 78764288);           // 8x512x1024 f32
    // mbound + se live in the (not-yet-live) mbuf region: mbound read by attn,
    // se read by k_mod — both dead before MLP1 writes mbuf.
    float* mbound         = (float*)(W + 45209856);
    float* sebuf          = (float*)(W + 45209920);           // 8x768 f32

    PrepArgs pa;
    pa.src[0] = qkvsw; pa.dst[0] = wqs_b; pa.n[0] = 1536 * 512;
    pa.src[1] = qkvcw; pa.dst[1] = wqc_b; pa.n[1] = 1536 * 768;
    pa.src[2] = outw;  pa.dst[2] = wo_b;  pa.n[2] = 512 * 512;
    pa.src[3] = w1;    pa.dst[3] = w1_b;  pa.n[3] = 2048 * 512;
    pa.src[4] = w2;    pa.dst[4] = w2_b;  pa.n[4] = 512 * 2048;
    pa.src[5] = cond;  pa.dst[5] = condb; pa.n[5] = 616 * 768;
    pa.freqs = ropef; pa.ct = ct;
    pa.emb = femb; pa.mbias = mod_b; pa.mod = mod; pa.se = sebuf;
    pa.qn = qn; pa.kn = kn; pa.mbound = mbound;
    k_prep<<<dim3(1152, 8), 256, 0, stream>>>(pa);
    k_mod<<<dim3(12, 8, 8), 256, 0, stream>>>(sebuf, mod_w, mod);

    k_rms2d_mod_t<<<dim3(16, BATCH), 256, 0, stream>>>(x, n1s, mod, 0, 512, hmod);
    // qkv (spatial): fused RoPE/RMS/V^T epilogue
    k_gemm_qkv<0><<<dim3(12, 64), 256, 0, stream>>>(hmod, wqs_b, 8192, 512, 0,
                                                    ct, qn, kn, qbuf, kbuf, vTb);
    // qkv (cond): k/v tiles only (nOff=512)
    k_gemm_qkv<1><<<dim3(8, 5), 256, 0, stream>>>(condb, wqc_b, 616, 768, 512,
                                                  ct, qn, kn, qbuf, kbuf, vTb);
    k_attn_v7<<<dim3(1024), 256, 0, stream>>>(qbuf, kbuf, vTb, obuf, mbound);
    // out-proj: x1 = x + g1*(obuf @ Wo^T + outb)  (channel-major f32), 128x64 tiles
    k_gemm_mfma<1, 128, 64><<<dim3(8, 64), 256, 0, stream>>>(
        obuf, wo_b, x1, 8192, 512, 512, outb, mod + 2 * 512, x);
    k_rms2d_mod_t<<<dim3(16, BATCH), 256, 0, stream>>>(x1, n2s, mod, 3 * 512, 4 * 512, h2);
    // MLP1 + gelu -> bf16 [8192,2048]
    k_gemm_mfma<2, 128, 128><<<dim3(16, 64), 256, 0, stream>>>(
        h2, w1_b, mbuf, 8192, 2048, 512, b1, nullptr, nullptr);
    // MLP2 + gate + residual -> d_out (channel-major f32), 128x64 tiles
    k_gemm_mfma<1, 128, 64><<<dim3(8, 64), 256, 0, stream>>>(
        mbuf, w2_b, out, 8192, 512, 2048, b2, mod + 5 * 512, x1);
}

// Round 8
// 269.340 us; speedup vs baseline: 5.4707x; 1.0049x over previous
//
#include <hip/hip_runtime.h>

// FluxUNet fused block — round 8: 2-phase double-buffered GEMM (prefetch before
// compute, one barrier per K-step); attn v7 + parallel modulation kept.
// B=8, C=512, HW=1024, S=77, E=768, NH=8, HD=64, HID=2048, T=1101.
constexpr int BATCH = 8, CH = 512, HWN = 1024, SEQ = 77, EMB = 768;
constexpr int NHEAD = 8, HDIM = 64, HIDDEN = 2048, TTOT = 1101;
constexpr int VSTRIDE = 1152;  // padded t-stride for transposed V

typedef short bhalf8 __attribute__((ext_vector_type(8)));
typedef float f32x4 __attribute__((ext_vector_type(4)));

__device__ __forceinline__ unsigned short f2bf(float f) {
    unsigned u = __builtin_bit_cast(unsigned, f);
    unsigned r = (u + 0x7fffu + ((u >> 16) & 1u)) >> 16;
    return (unsigned short)r;
}
__device__ __forceinline__ unsigned cvtpk(float a, float b) {
    unsigned r;
    asm("v_cvt_pk_bf16_f32 %0, %1, %2" : "=v"(r) : "v"(a), "v"(b));
    return r;
}
__device__ __forceinline__ float gelu_tanh(float v) {
    float c = v * v * v;
    float t = tanhf(0.7978845608028654f * (v + 0.044715f * c));
    return 0.5f * v * (1.0f + t);
}
// XOR-swizzle on a 128B-row-stride LDS tile (region base must be 1024B-aligned).
__device__ __forceinline__ int swz(int b) { return b ^ ((b >> 3) & 0x70); }

// async global->LDS 16B: LDS dest = wave-uniform base + lane*16.
__device__ __forceinline__ void gload16(const void* g, void* l) {
    __builtin_amdgcn_global_load_lds(
        (const __attribute__((address_space(1))) unsigned int*)g,
        (__attribute__((address_space(3))) unsigned int*)l, 16, 0, 0);
}

// ---------- merged prep: casts (y<6), rope table (y==6),
// ----------             y==7: mod bias-init / softmax bound / silu(emb) ----------
struct PrepArgs {
    const float* src[6];
    unsigned short* dst[6];
    int n[6];
    const float* freqs;
    float* ct;
    const float* emb;
    const float* mbias;
    float* mod;
    float* se;       // silu(emb) [8][768]
    const float* qn;
    const float* kn;
    float* mbound;   // scalar softmax upper bound (exp2 domain)
};
__global__ void k_prep(PrepArgs a) {
    int y = blockIdx.y;
    int bx = blockIdx.x;
    int tid = threadIdx.x;
    if (y < 6) {
        int i = (bx * 256 + tid) * 4;
        if (i >= a.n[y]) return;
        float4 v = *(const float4*)&a.src[y][i];
        ushort4 o = {f2bf(v.x), f2bf(v.y), f2bf(v.z), f2bf(v.w)};
        *(ushort4*)&a.dst[y][i] = o;
    } else if (y == 6) {
        int i = bx * 256 + tid;
        if (i >= TTOT * 32) return;
        int t = i >> 5, j = i & 31;
        float ang;
        if (t < HWN) {
            ang = (float)(t >> 5) * a.freqs[2 * j] + (float)(t & 31) * a.freqs[2 * j + 1];
        } else {
            float inv = expf(-(float)j * (9.210340371976184f / 32.0f));
            ang = (float)(t - HWN) * inv;
        }
        a.ct[i * 2] = cosf(ang);
        a.ct[i * 2 + 1] = sinf(ang);
    } else {
        if (bx < 24) {            // mod = bias (atomic partials land on top)
            int i = bx * 1024 + tid * 4;           // i = b*3072 + j, j%4==0
            int j = i - (i / (6 * CH)) * (6 * CH);
            *(float4*)&a.mod[i] = *(const float4*)&a.mbias[j];
        } else if (bx == 24) {    // softmax bound: |S*log2e| <= 64*max|qn|*max|kn|*0.125*log2e
            if (tid < 64) {
                float mq = fabsf(a.qn[tid]), mk = fabsf(a.kn[tid]);
                #pragma unroll
                for (int o = 1; o < 64; o <<= 1) {
                    mq = fmaxf(mq, __shfl_xor(mq, o));
                    mk = fmaxf(mk, __shfl_xor(mk, o));
                }
                if (tid == 0) a.mbound[0] = 64.0f * mq * mk * 0.18033688011112042f + 1.0f;
            }
        } else if (bx >= 32 && bx < 38) {  // silu(final_emb) -> se [6144 floats]
            int i = (bx - 32) * 1024 + tid * 4;
            float4 v = *(const float4*)&a.emb[i];
            float4 o;
            o.x = v.x / (1.0f + expf(-v.x));
            o.y = v.y / (1.0f + expf(-v.y));
            o.z = v.z / (1.0f + expf(-v.z));
            o.w = v.w / (1.0f + expf(-v.w));
            *(float4*)&a.se[i] = o;
        }
    }
}

// ---------- modulation partials: mod[b][j] += sum_{e in chunk} se[b][e] * w[e][j] ----------
__global__ __launch_bounds__(256) void k_mod(const float* __restrict__ se,
        const float* __restrict__ w, float* __restrict__ mod) {
    int jb = blockIdx.x, b = blockIdx.y, ec = blockIdx.z;
    int j = jb * 256 + threadIdx.x;
    const float* sb = se + b * EMB + ec * 96;
    const float* wb = w + (size_t)(ec * 96) * (6 * CH) + j;
    float acc = 0.f;
    #pragma unroll 8
    for (int e = 0; e < 96; ++e) acc = fmaf(sb[e], wb[(size_t)e * (6 * CH)], acc);
    atomicAdd(&mod[b * (6 * CH) + j], acc);
}

// ------- RMSNorm(channel) + adaLN modulate + transpose -> bf16 token-major -------
__global__ __launch_bounds__(256) void k_rms2d_mod_t(const float* __restrict__ xin,
        const float* __restrict__ sw, const float* __restrict__ mod, int shoff, int scoff,
        unsigned short* __restrict__ outp) {
    __shared__ float part[4][64];
    __shared__ float rinv[64];
    int b = blockIdx.y;
    int n0 = blockIdx.x * 64;
    int tid = threadIdx.x;
    const float* xb = xin + (size_t)b * CH * HWN;
    {
        int n = n0 + (tid & 63);
        int cg = tid >> 6;
        float ss = 0.f;
        #pragma unroll 8
        for (int c = cg * 128; c < cg * 128 + 128; ++c) {
            float v = xb[(size_t)c * HWN + n];
            ss = fmaf(v, v, ss);
        }
        part[cg][tid & 63] = ss;
    }
    __syncthreads();
    if (tid < 64) {
        float s = part[0][tid] + part[1][tid] + part[2][tid] + part[3][tid];
        rinv[tid] = rsqrtf(s * (1.0f / CH) + 1e-6f);
    }
    __syncthreads();
    int n = n0 + (tid >> 2);
    int cq = tid & 3;
    float r = rinv[tid >> 2];
    const float* mb = mod + b * (6 * CH);
    unsigned short* orow = outp + ((size_t)(b * HWN + n)) * CH;
    for (int jc = 0; jc < 16; ++jc) {
        int c = cq * 128 + jc * 8;
        bhalf8 o;
        #pragma unroll
        for (int u = 0; u < 8; ++u) {
            int cc = c + u;
            float v = xb[(size_t)cc * HWN + n];
            float y = v * r * sw[cc] * (1.0f + mb[scoff + cc]) + mb[shoff + cc];
            o[u] = (short)f2bf(y);
        }
        *(bhalf8*)&orow[c] = o;
    }
}

// ------- bf16 MFMA GEMM, 2-phase double-buffered (prefetch t+1 before compute t) -------
// A [M][K], Bt [N][K] bf16 row-major. K%64==0, N%BN==0, M row-clamped.
// LDS = 2 x (BM+BN)*128 bytes; keep (BM+BN) <= 192 for 48KB (3 blocks/CU).
// EPI=1: f32 channel-major residual+gate (BM=128 assumed).  EPI=2: bf16 gelu token-major.
template <int EPI, int BM, int BN>
__global__ __launch_bounds__(256) void k_gemm_mfma(
        const unsigned short* __restrict__ A, const unsigned short* __restrict__ Bt,
        void* __restrict__ OutV, int M, int N, int K,
        const float* __restrict__ bias, const float* __restrict__ gate,
        const float* __restrict__ res) {
    constexpr int WM = BM / 2, WN = BN / 2;
    constexpr int MI = WM / 16, NI = WN / 16;
    constexpr int CA = BM / 8, CB = BN / 8, CW = (CA + CB) / 4;
    constexpr int BUF = (BM + BN) * 128;
    __shared__ __align__(1024) char SM[2 * BUF];
    int tid = threadIdx.x;
    int w = tid >> 6, l = tid & 63, lg = l >> 4, ll = l & 15;
    int wr = w >> 1, wc = w & 1;
    int m0 = blockIdx.y * BM, n0 = blockIdx.x * BN;
    int r8 = l >> 3, c16 = (l & 7) * 16;
    f32x4 acc[MI][NI] = {};
    const char* Ac = (const char*)A;
    const char* Bc = (const char*)Bt;
    size_t rowBytes = (size_t)K * 2;
    int nt = K >> 6;

    auto stage = [&](int t, int bsel) {
        char* As = SM + bsel * BUF;
        char* Bs = As + BM * 128;
        int k0 = t * 64;
        #pragma unroll
        for (int i = 0; i < CW; ++i) {
            int c = w * CW + i;
            if (c < CA) {
                int row = c * 8 + r8;
                int off = c16 ^ ((row & 7) << 4);
                int ar = m0 + row;
                if (ar > M - 1) ar = M - 1;
                gload16(Ac + (size_t)ar * rowBytes + k0 * 2 + off, As + c * 1024);
            } else {
                int cc = c - CA;
                int row = cc * 8 + r8;
                int off = c16 ^ ((row & 7) << 4);
                gload16(Bc + (size_t)(n0 + row) * rowBytes + k0 * 2 + off, Bs + cc * 1024);
            }
        }
    };
    stage(0, 0);
    __syncthreads();  // tile 0 landed (syncthreads drains vmcnt)
    for (int t = 0; t < nt; ++t) {
        int cur = t & 1;
        if (t + 1 < nt) stage(t + 1, cur ^ 1);  // latency hides under compute of tile t
        char* As = SM + cur * BUF;
        char* Bs = As + BM * 128;
        #pragma unroll
        for (int ks = 0; ks < 2; ++ks) {
            bhalf8 af[MI], bf[NI];
            #pragma unroll
            for (int mi = 0; mi < MI; ++mi)
                af[mi] = *(const bhalf8*)(As + swz((wr * WM + mi * 16 + ll) * 128 + ks * 64 + lg * 16));
            #pragma unroll
            for (int ni = 0; ni < NI; ++ni)
                bf[ni] = *(const bhalf8*)(Bs + swz((wc * WN + ni * 16 + ll) * 128 + ks * 64 + lg * 16));
            __builtin_amdgcn_s_setprio(1);
            #pragma unroll
            for (int mi = 0; mi < MI; ++mi)
                #pragma unroll
                for (int ni = 0; ni < NI; ++ni)
                    acc[mi][ni] = __builtin_amdgcn_mfma_f32_16x16x32_bf16(af[mi], bf[ni], acc[mi][ni], 0, 0, 0);
            __builtin_amdgcn_s_setprio(0);
        }
        __syncthreads();  // next tile landed; all waves done with cur buffers
    }
    if (EPI == 2) {
        unsigned short* Out = (unsigned short*)OutV;
        #pragma unroll
        for (int mi = 0; mi < MI; ++mi)
            #pragma unroll
            for (int ni = 0; ni < NI; ++ni) {
                int col = n0 + wc * WN + ni * 16 + ll;
                float bv = bias[col];
                #pragma unroll
                for (int r = 0; r < 4; ++r) {
                    int mrow = m0 + wr * WM + mi * 16 + 4 * lg + r;
                    Out[(size_t)mrow * N + col] = f2bf(gelu_tanh(acc[mi][ni][r] + bv));
                }
            }
    } else {
        float* Out = (float*)OutV;
        int bidx = m0 >> 10;
        int hw0 = m0 & 1023;
        const float* resb = res + (size_t)bidx * N * HWN;
        float* outb_ = Out + (size_t)bidx * N * HWN;
        #pragma unroll
        for (int ni = 0; ni < NI; ++ni) {
            int ch = n0 + wc * WN + ni * 16 + ll;
            float g = gate[bidx * (6 * CH) + ch];
            float bv = bias[ch];
            #pragma unroll
            for (int mi = 0; mi < MI; ++mi) {
                int t = hw0 + wr * WM + mi * 16 + 4 * lg;
                float4 r4 = *(const float4*)&resb[(size_t)ch * HWN + t];
                f32x4 a = acc[mi][ni];
                float4 o;
                o.x = r4.x + g * (a[0] + bv);
                o.y = r4.y + g * (a[1] + bv);
                o.z = r4.z + g * (a[2] + bv);
                o.w = r4.w + g * (a[3] + bv);
                *(float4*)&outb_[(size_t)ch * HWN + t] = o;
            }
        }
    }
}

// ------- qkv GEMM with fused RoPE + qk-RMSNorm + head-split + V-transpose -------
template <int COND>
__global__ __launch_bounds__(256) void k_gemm_qkv(
        const unsigned short* __restrict__ A, const unsigned short* __restrict__ Bt,
        int M, int K, int nOff, const float* __restrict__ ct,
        const float* __restrict__ qn, const float* __restrict__ kn,
        unsigned short* __restrict__ qb, unsigned short* __restrict__ kb,
        unsigned short* __restrict__ vT) {
    __shared__ __align__(1024) char SMEM[34816];  // loop: As/Bs 16K+16K; epi: stage[128][136]
    unsigned short* As = (unsigned short*)SMEM;
    unsigned short* Bs = (unsigned short*)(SMEM + 16384);
    int tid = threadIdx.x;
    int w = tid >> 6, l = tid & 63, lg = l >> 4, ll = l & 15;
    int wr = w >> 1, wc = w & 1;
    int m0 = blockIdx.y * 128, n0 = nOff + blockIdx.x * 128;
    int r8 = l >> 3, c16 = (l & 7) * 16;
    f32x4 acc[4][4] = {};
    const char* Ac = (const char*)A;
    const char* Bc = (const char*)Bt;
    size_t rowBytes = (size_t)K * 2;
    for (int k0 = 0; k0 < K; k0 += 64) {
        __syncthreads();
        #pragma unroll
        for (int i = 0; i < 8; ++i) {
            int c = w * 8 + i;
            if (c < 16) {
                int row = c * 8 + r8;
                int off = c16 ^ ((row & 7) << 4);
                int ar = m0 + row;
                if (ar > M - 1) ar = M - 1;
                gload16(Ac + (size_t)ar * rowBytes + k0 * 2 + off, (char*)As + c * 1024);
            } else {
                int cc = c - 16;
                int row = cc * 8 + r8;
                int off = c16 ^ ((row & 7) << 4);
                gload16(Bc + (size_t)(n0 + row) * rowBytes + k0 * 2 + off, (char*)Bs + cc * 1024);
            }
        }
        __syncthreads();
        #pragma unroll
        for (int ks = 0; ks < 2; ++ks) {
            bhalf8 af[4], bf[4];
            #pragma unroll
            for (int mi = 0; mi < 4; ++mi)
                af[mi] = *(const bhalf8*)((char*)As + swz((wr * 64 + mi * 16 + ll) * 128 + ks * 64 + lg * 16));
            #pragma unroll
            for (int ni = 0; ni < 4; ++ni)
                bf[ni] = *(const bhalf8*)((char*)Bs + swz((wc * 64 + ni * 16 + ll) * 128 + ks * 64 + lg * 16));
            __builtin_amdgcn_s_setprio(1);
            #pragma unroll
            for (int mi = 0; mi < 4; ++mi)
                #pragma unroll
                for (int ni = 0; ni < 4; ++ni)
                    acc[mi][ni] = __builtin_amdgcn_mfma_f32_16x16x32_bf16(af[mi], bf[ni], acc[mi][ni], 0, 0, 0);
            __builtin_amdgcn_s_setprio(0);
        }
    }
    int type = n0 >> 9;  // 0 q, 1 k, >=2 v
    const float2* ct2 = (const float2*)ct;

    if (type >= 2) {  // ---- V: direct transposed bf16 writes ----
        int hd = (n0 - 1024 + wc * 64) >> 6;
        #pragma unroll
        for (int ni = 0; ni < 4; ++ni) {
            int d = ni * 16 + ll;
            #pragma unroll
            for (int mi = 0; mi < 4; ++mi) {
                int rowL = m0 + wr * 64 + mi * 16 + 4 * lg;
                if (COND == 0) {
                    int b = rowL >> 10, t = rowL & 1023;
                    uint2 pk = {cvtpk(acc[mi][ni][0], acc[mi][ni][1]),
                                cvtpk(acc[mi][ni][2], acc[mi][ni][3])};
                    *(uint2*)&vT[((size_t)(b * 8 + hd) * 64 + d) * VSTRIDE + t] = pk;
                } else {
                    #pragma unroll
                    for (int r = 0; r < 4; ++r) {
                        int row = rowL + r;
                        if (row < M) {
                            int b = row / 77, s = row - b * 77;
                            vT[((size_t)(b * 8 + hd) * 64 + d) * VSTRIDE + 1024 + s] =
                                f2bf(acc[mi][ni][r]);
                        }
                    }
                }
            }
        }
        return;
    }
    // ---- Q/K: RoPE + RMSNorm + scale, then LDS-transpose for coalesced stores ----
    const float* wnt = (type == 0) ? qn : kn;
    float wn[4];
    int jj[4];
    #pragma unroll
    for (int ni = 0; ni < 4; ++ni) {
        wn[ni] = wnt[ni * 16 + ll];
        jj[ni] = (ni * 16 + ll) >> 1;
    }
    float sgn = (ll & 1) ? 1.f : -1.f;
    #pragma unroll
    for (int mi = 0; mi < 4; ++mi) {
        int rowL = m0 + wr * 64 + mi * 16 + 4 * lg;
        int tt[4];
        #pragma unroll
        for (int r = 0; r < 4; ++r) {
            if (COND == 0) tt[r] = (rowL + r) & 1023;
            else {
                int row = rowL + r;
                if (row > M - 1) row = M - 1;
                int b = row / 77;
                tt[r] = 1024 + (row - b * 77);
            }
        }
        #pragma unroll
        for (int ni = 0; ni < 4; ++ni) {
            f32x4 a = acc[mi][ni], p;
            #pragma unroll
            for (int r = 0; r < 4; ++r) p[r] = __shfl_xor(a[r], 1);
            #pragma unroll
            for (int r = 0; r < 4; ++r) {
                float2 cs = ct2[tt[r] * 32 + jj[ni]];
                a[r] = fmaf(sgn * p[r], cs.y, a[r] * cs.x);
            }
            acc[mi][ni] = a;
        }
        f32x4 ss = {};
        #pragma unroll
        for (int ni = 0; ni < 4; ++ni)
            #pragma unroll
            for (int r = 0; r < 4; ++r) ss[r] = fmaf(acc[mi][ni][r], acc[mi][ni][r], ss[r]);
        #pragma unroll
        for (int msk = 1; msk < 16; msk <<= 1)
            #pragma unroll
            for (int r = 0; r < 4; ++r) ss[r] += __shfl_xor(ss[r], msk);
        f32x4 ri;
        #pragma unroll
        for (int r = 0; r < 4; ++r) {
            ri[r] = rsqrtf(ss[r] * (1.0f / 64.f) + 1.1920929e-07f);
            if (type == 0) ri[r] *= 0.18033688011112042f;  // 0.125 * log2(e)
        }
        #pragma unroll
        for (int ni = 0; ni < 4; ++ni)
            #pragma unroll
            for (int r = 0; r < 4; ++r) acc[mi][ni][r] *= ri[r] * wn[ni];
    }
    __syncthreads();
    unsigned short* stg = (unsigned short*)SMEM;  // [128][136]
    #pragma unroll
    for (int mi = 0; mi < 4; ++mi)
        #pragma unroll
        for (int ni = 0; ni < 4; ++ni) {
            int colL = wc * 64 + ni * 16 + ll;
            int rowL = wr * 64 + mi * 16 + 4 * lg;
            #pragma unroll
            for (int r = 0; r < 4; ++r)
                stg[(rowL + r) * 136 + colL] = f2bf(acc[mi][ni][r]);
        }
    __syncthreads();
    int rowO = tid >> 1, half = tid & 1;
    int rowG = m0 + rowO;
    if (COND == 1 && rowG >= M) return;
    int ch0 = n0 + half * 64;
    int b, t;
    if (COND == 0) { b = rowG >> 10; t = rowG & 1023; }
    else { b = rowG / 77; t = 1024 + (rowG - b * 77); }
    unsigned short* dst;
    if (type == 0) dst = qb + ((size_t)(b * 8 + (ch0 >> 6)) * HWN + t) * 64;
    else dst = kb + ((size_t)(b * 8 + ((ch0 - 512) >> 6)) * TTOT + t) * 64;
    #pragma unroll
    for (int i = 0; i < 8; ++i)
        *(bhalf8*)&dst[i * 8] = *(const bhalf8*)&stg[rowO * 136 + half * 64 + i * 8];
}

// -------- attn v7: static-max softmax, double-buffered K/V, 1 barrier/tile --------
// LDS 40KB: buf0 K[0,8K) V[8K,16K); buf1 K[16K,24K) V[24K,32K); P [32K,40K).
__global__ __launch_bounds__(256) void k_attn_v7(const unsigned short* __restrict__ qb,
        const unsigned short* __restrict__ kbuf, const unsigned short* __restrict__ vT,
        unsigned short* __restrict__ ob, const float* __restrict__ mbp) {
    __shared__ __align__(1024) char smc[40960];
    int f = blockIdx.x;
    int xcd = f & 7, n = f >> 3;
    int q0 = (n & 15) * 64;
    int bh = ((n >> 4) << 3) | xcd;
    int tid = threadIdx.x;
    int w = tid >> 6, l = tid & 63, lg = l >> 4, ll = l & 15;
    int r8 = l >> 3, c16 = (l & 7) * 16;
    float Mb = mbp[0];
    bhalf8 qf[2];
    {
        const unsigned short* qbase = qb + ((size_t)bh * HWN + q0 + w * 16) * 64;
        #pragma unroll
        for (int ks = 0; ks < 2; ++ks)
            qf[ks] = *(const bhalf8*)&qbase[ll * 64 + ks * 32 + lg * 8];
    }
    f32x4 accO[4] = {};  // O^T[d=d4*16+4lg+r][q=ll]
    float Lx = 0.f;
    const char* kgl = (const char*)kbuf + (size_t)bh * TTOT * 128;
    const char* vgl = (const char*)vT + (size_t)bh * 64 * (VSTRIDE * 2);
    char* pw = smc + 32768 + w * 2048 + ll * 128;
    int pswz = (ll & 7) << 4;

    auto stage = [&](int kt, int bsel) {
        char* base = smc + bsel * 16384;
        #pragma unroll
        for (int i = 0; i < 4; ++i) {
            int c = w * 4 + i;
            if (c < 8) {  // K chunk: rows = keys
                int row = c * 8 + r8;
                int t = kt * 64 + row;
                if (t > TTOT - 1) t = TTOT - 1;  // clamped rows are softmax-masked
                gload16(kgl + (size_t)t * 128 + (c16 ^ ((row & 7) << 4)), base + c * 1024);
            } else {      // V^T chunk: rows = d
                int row = (c - 8) * 8 + r8;
                gload16(vgl + (size_t)row * (VSTRIDE * 2) + kt * 128 + (c16 ^ ((row & 7) << 4)),
                        base + 8192 + (c - 8) * 1024);
            }
        }
    };
    stage(0, 0);
    __syncthreads();  // tile 0 landed
    for (int kt = 0; kt < 18; ++kt) {
        int cur = kt & 1;
        if (kt < 17) stage(kt + 1, cur ^ 1);  // issue next tile; latency hides under compute
        char* kl = smc + cur * 16384;
        char* vl = kl + 8192;
        // S^T = K x Q
        f32x4 s[4] = {};
        __builtin_amdgcn_s_setprio(1);
        #pragma unroll
        for (int ks = 0; ks < 2; ++ks) {
            bhalf8 kf[4];
            #pragma unroll
            for (int k4 = 0; k4 < 4; ++k4)
                kf[k4] = *(const bhalf8*)(kl + swz((k4 * 16 + ll) * 128 + ks * 64 + lg * 16));
            #pragma unroll
            for (int k4 = 0; k4 < 4; ++k4)
                s[k4] = __builtin_amdgcn_mfma_f32_16x16x32_bf16(kf[k4], qf[ks], s[k4], 0, 0, 0);
        }
        __builtin_amdgcn_s_setprio(0);
        if (kt == 17) {  // mask tail keys (key index lane-local: k4*16 + 4lg + r)
            int kb0 = kt * 64 + 4 * lg;
            #pragma unroll
            for (int k4 = 0; k4 < 4; ++k4)
                #pragma unroll
                for (int r = 0; r < 4; ++r)
                    if (kb0 + k4 * 16 + r >= TTOT) s[k4][r] = -1e30f;
        }
        // softmax with static max (shift-invariant => exact); no reduce, no rescale
        float sum = 0.f;
        #pragma unroll
        for (int k4 = 0; k4 < 4; ++k4) {
            float p0 = exp2f(s[k4][0] - Mb), p1 = exp2f(s[k4][1] - Mb);
            float p2 = exp2f(s[k4][2] - Mb), p3 = exp2f(s[k4][3] - Mb);
            sum += (p0 + p1) + (p2 + p3);
            uint2 pk = {cvtpk(p0, p1), cvtpk(p2, p3)};
            *(uint2*)(pw + ((k4 * 32 + lg * 8) ^ pswz)) = pk;
        }
        sum += __shfl_xor(sum, 16);
        sum += __shfl_xor(sum, 32);
        Lx += sum;
        // O^T += V^T x P (P wave-private)
        __builtin_amdgcn_s_setprio(1);
        #pragma unroll
        for (int ks = 0; ks < 2; ++ks) {
            bhalf8 vf[4];
            #pragma unroll
            for (int d4 = 0; d4 < 4; ++d4)
                vf[d4] = *(const bhalf8*)(vl + swz((d4 * 16 + ll) * 128 + ks * 64 + lg * 16));
            bhalf8 pf = *(const bhalf8*)(smc + 32768 + w * 2048 + swz(ll * 128 + ks * 64 + lg * 16));
            #pragma unroll
            for (int d4 = 0; d4 < 4; ++d4)
                accO[d4] = __builtin_amdgcn_mfma_f32_16x16x32_bf16(vf[d4], pf, accO[d4], 0, 0, 0);
        }
        __builtin_amdgcn_s_setprio(0);
        __syncthreads();  // next-tile loads landed; all waves done with cur buffers
    }
    // epilogue: /L, transpose O^T -> [q][d] via LDS, coalesced stores
    {
        float inv = 1.0f / Lx;
        int orow = w * 16 + ll;
        char* po = smc + orow * 128;
        int oswz = (orow & 7) << 4;
        #pragma unroll
        for (int d4 = 0; d4 < 4; ++d4) {
            uint2 pk = {cvtpk(accO[d4][0] * inv, accO[d4][1] * inv),
                        cvtpk(accO[d4][2] * inv, accO[d4][3] * inv)};
            *(uint2*)(po + ((d4 * 32 + lg * 8) ^ oswz)) = pk;
        }
    }
    __syncthreads();
    int b = bh >> 3, h = bh & 7;
    int row = tid >> 2, seg = tid & 3;
    bhalf8 v0 = *(const bhalf8*)(smc + swz(row * 128 + seg * 32));
    bhalf8 v1 = *(const bhalf8*)(smc + swz(row * 128 + seg * 32 + 16));
    unsigned short* dst = ob + ((size_t)(b * HWN + q0 + row)) * CH + h * 64 + seg * 16;
    *(bhalf8*)&dst[0] = v0;
    *(bhalf8*)&dst[8] = v1;
}

extern "C" void kernel_launch(void* const* d_in, const int* in_sizes, int n_in,
                              void* d_out, int out_size, void* d_ws, size_t ws_size,
                              hipStream_t stream) {
    const float* x     = (const float*)d_in[0];
    const float* cond  = (const float*)d_in[1];
    const float* femb  = (const float*)d_in[2];
    const float* mod_w = (const float*)d_in[3];
    const float* mod_b = (const float*)d_in[4];
    const float* n1s   = (const float*)d_in[5];
    const float* n2s   = (const float*)d_in[6];
    const float* qkvsw = (const float*)d_in[7];
    const float* qkvcw = (const float*)d_in[8];
    const float* ropef = (const float*)d_in[9];
    const float* qn    = (const float*)d_in[10];
    const float* kn    = (const float*)d_in[11];
    const float* outw  = (const float*)d_in[12];
    const float* outb  = (const float*)d_in[13];
    const float* w1    = (const float*)d_in[14];
    const float* b1    = (const float*)d_in[15];
    const float* w2    = (const float*)d_in[16];
    const float* b2    = (const float*)d_in[17];
    float* out = (float*)d_out;
    char* W = (char*)d_ws;

    // byte layout (~95.5 MB peak)
    unsigned short* wqs_b = (unsigned short*)(W + 0);         // 1536x512
    unsigned short* wqc_b = (unsigned short*)(W + 1572864);   // 1536x768
    unsigned short* wo_b  = (unsigned short*)(W + 3932160);   // 512x512
    unsigned short* w1_b  = (unsigned short*)(W + 4456448);   // 2048x512
    unsigned short* w2_b  = (unsigned short*)(W + 6553600);   // 512x2048
    unsigned short* condb = (unsigned short*)(W + 8650752);   // 616x768
    float* mod            = (float*)(W + 9596928);            // 8x3072
    float* ct             = (float*)(W + 9695232);            // 1101x32 float2
    unsigned short* hmod  = (unsigned short*)(W + 9977088);   // 8192x512 bf16
    unsigned short* obuf  = hmod;                             // overlays hmod (dead post-qkv)
    unsigned short* qbuf  = (unsigned short*)(W + 18365696);  // 64x1024x64 bf16
    unsigned short* kbuf  = (unsigned short*)(W + 26754304);  // 64x1101x64 bf16
    unsigned short* vTb   = (unsigned short*)(W + 35772672);  // 64x64x1152 bf16
    unsigned short* h2    = vTb;                              // overlays vT (dead post-attn)
    unsigned short* mbuf  = (unsigned short*)(W + 45209856);  // 8192x2048 bf16
    float* x1             = (float*)(W + 78764288);           // 8x512x1024 f32
    // mbound + se live in the (not-yet-live) mbuf region.
    float* mbound         = (float*)(W + 45209856);
    float* sebuf          = (float*)(W + 45209920);           // 8x768 f32

    PrepArgs pa;
    pa.src[0] = qkvsw; pa.dst[0] = wqs_b; pa.n[0] = 1536 * 512;
    pa.src[1] = qkvcw; pa.dst[1] = wqc_b; pa.n[1] = 1536 * 768;
    pa.src[2] = outw;  pa.dst[2] = wo_b;  pa.n[2] = 512 * 512;
    pa.src[3] = w1;    pa.dst[3] = w1_b;  pa.n[3] = 2048 * 512;
    pa.src[4] = w2;    pa.dst[4] = w2_b;  pa.n[4] = 512 * 2048;
    pa.src[5] = cond;  pa.dst[5] = condb; pa.n[5] = 616 * 768;
    pa.freqs = ropef; pa.ct = ct;
    pa.emb = femb; pa.mbias = mod_b; pa.mod = mod; pa.se = sebuf;
    pa.qn = qn; pa.kn = kn; pa.mbound = mbound;
    k_prep<<<dim3(1152, 8), 256, 0, stream>>>(pa);
    k_mod<<<dim3(12, 8, 8), 256, 0, stream>>>(sebuf, mod_w, mod);

    k_rms2d_mod_t<<<dim3(16, BATCH), 256, 0, stream>>>(x, n1s, mod, 0, 512, hmod);
    // qkv (spatial): fused RoPE/RMS/V^T epilogue
    k_gemm_qkv<0><<<dim3(12, 64), 256, 0, stream>>>(hmod, wqs_b, 8192, 512, 0,
                                                    ct, qn, kn, qbuf, kbuf, vTb);
    // qkv (cond): k/v tiles only (nOff=512)
    k_gemm_qkv<1><<<dim3(8, 5), 256, 0, stream>>>(condb, wqc_b, 616, 768, 512,
                                                  ct, qn, kn, qbuf, kbuf, vTb);
    k_attn_v7<<<dim3(1024), 256, 0, stream>>>(qbuf, kbuf, vTb, obuf, mbound);
    // out-proj: x1 = x + g1*(obuf @ Wo^T + outb)  (channel-major f32), 128x64 2-phase
    k_gemm_mfma<1, 128, 64><<<dim3(8, 64), 256, 0, stream>>>(
        obuf, wo_b, x1, 8192, 512, 512, outb, mod + 2 * 512, x);
    k_rms2d_mod_t<<<dim3(16, BATCH), 256, 0, stream>>>(x1, n2s, mod, 3 * 512, 4 * 512, h2);
    // MLP1 + gelu -> bf16 [8192,2048], 64x128 2-phase (2048 blocks)
    k_gemm_mfma<2, 64, 128><<<dim3(16, 128), 256, 0, stream>>>(
        h2, w1_b, mbuf, 8192, 2048, 512, b1, nullptr, nullptr);
    // MLP2 + gate + residual -> d_out (channel-major f32), 128x64 2-phase
    k_gemm_mfma<1, 128, 64><<<dim3(8, 64), 256, 0, stream>>>(
        mbuf, w2_b, out, 8192, 512, 2048, b2, mod + 5 * 512, x1);
}